// Round 12
// baseline (1080.497 us; speedup 1.0000x reference)
//
#include <hip/hip_runtime.h>

// Transformer layer, bf16 MFMA compute, fp32 I/O.
// B=2 T=2048 E=2048 H=16 DH=128 FFN=8192. Needs ~256MB workspace.

#define T_SEQ 2048
#define E_DIM 2048
#define N_HEAD 16
#define D_HEAD 128
#define FFN_DIM 8192
#define M_ROWS 4096  // B*T
#define QS (3 * E_DIM)  // fused QKV row stride

typedef unsigned short u16;
typedef short short8 __attribute__((ext_vector_type(8)));
typedef float f32x4 __attribute__((ext_vector_type(4)));

#define DEV __device__ __forceinline__

DEV u16 f2bf(float f) {
  unsigned u = __float_as_uint(f);
  u += 0x7fffu + ((u >> 16) & 1u);
  return (u16)(u >> 16);
}
DEV float bf2f(u16 h) { return __uint_as_float(((unsigned)h) << 16); }

DEV void async16(void* lds, const void* g) {
  __builtin_amdgcn_global_load_lds((const __attribute__((address_space(1))) void*)g,
                                   (__attribute__((address_space(3))) void*)lds, 16, 0, 0);
}

// ---------------- LayerNorm: fp32 [rows][E] -> bf16 -----------------
__global__ __launch_bounds__(256) void ln_kernel(const float* __restrict__ x,
                                                 const float* __restrict__ gw,
                                                 const float* __restrict__ bw,
                                                 u16* __restrict__ out) {
  int row = blockIdx.x;
  int t = threadIdx.x;
  const float4* xr = (const float4*)(x + (size_t)row * E_DIM);
  float4 a = xr[t], c = xr[t + 256];
  float s = a.x + a.y + a.z + a.w + c.x + c.y + c.z + c.w;
  float q = a.x * a.x + a.y * a.y + a.z * a.z + a.w * a.w +
            c.x * c.x + c.y * c.y + c.z * c.z + c.w * c.w;
  for (int off = 32; off > 0; off >>= 1) {
    s += __shfl_down(s, off);
    q += __shfl_down(q, off);
  }
  __shared__ float red[8];
  if ((t & 63) == 0) { red[(t >> 6) * 2] = s; red[(t >> 6) * 2 + 1] = q; }
  __syncthreads();
  s = red[0] + red[2] + red[4] + red[6];
  q = red[1] + red[3] + red[5] + red[7];
  float mu = s * (1.f / E_DIM);
  float rs = rsqrtf(q * (1.f / E_DIM) - mu * mu + 1e-5f);
  const float4* g4 = (const float4*)gw;
  const float4* b4 = (const float4*)bw;
  float4 g0 = g4[t], g1v = g4[t + 256], e0 = b4[t], e1 = b4[t + 256];
  ushort4 o0, o1;
  o0.x = f2bf((a.x - mu) * rs * g0.x + e0.x);
  o0.y = f2bf((a.y - mu) * rs * g0.y + e0.y);
  o0.z = f2bf((a.z - mu) * rs * g0.z + e0.z);
  o0.w = f2bf((a.w - mu) * rs * g0.w + e0.w);
  o1.x = f2bf((c.x - mu) * rs * g1v.x + e1.x);
  o1.y = f2bf((c.y - mu) * rs * g1v.y + e1.y);
  o1.z = f2bf((c.z - mu) * rs * g1v.z + e1.z);
  o1.w = f2bf((c.w - mu) * rs * g1v.w + e1.w);
  ((ushort4*)(out + (size_t)row * E_DIM))[t] = o0;
  ((ushort4*)(out + (size_t)row * E_DIM))[t + 256] = o1;
}

// ------- convert+transpose: fp32 W[K][N] -> bf16 WT[N][K] -----------
__global__ __launch_bounds__(256) void cvt_t_kernel(const float* __restrict__ W,
                                                    u16* __restrict__ WT,
                                                    int Kd, int Nd) {
  __shared__ float tile[32][33];
  int tx = threadIdx.x, ty = threadIdx.y;
  int n0 = blockIdx.x * 32, k0 = blockIdx.y * 32;
#pragma unroll
  for (int i = 0; i < 4; i++)
    tile[ty + i * 8][tx] = W[(size_t)(k0 + ty + i * 8) * Nd + n0 + tx];
  __syncthreads();
#pragma unroll
  for (int i = 0; i < 4; i++)
    WT[(size_t)(n0 + ty + i * 8) * Kd + k0 + tx] = f2bf(tile[tx][ty + i * 8]);
}

// -- transpose V from fused QKV: bf16 [B*T][QS] col 4096+ -> [B][E][T]
__global__ __launch_bounds__(256) void transpose_v_kernel(const u16* __restrict__ qkv,
                                                          u16* __restrict__ vt) {
  __shared__ u16 tile[32][33];
  int tx = threadIdx.x, ty = threadIdx.y;
  int b = blockIdx.z;
  int t0 = blockIdx.x * 32, e0 = blockIdx.y * 32;
#pragma unroll
  for (int i = 0; i < 4; i++)
    tile[ty + i * 8][tx] =
        qkv[(size_t)(b * T_SEQ + t0 + ty + i * 8) * QS + 2 * E_DIM + e0 + tx];
  __syncthreads();
#pragma unroll
  for (int i = 0; i < 4; i++)
    vt[((size_t)b * E_DIM + e0 + ty + i * 8) * T_SEQ + t0 + tx] = tile[tx][ty + i * 8];
}

// ------------- add3: out += P0 + P1 (split-K reduction) -------------
__global__ __launch_bounds__(256) void add3_kernel(float* __restrict__ out,
                                                   const float* __restrict__ pk) {
  const size_t MN4 = (size_t)M_ROWS * E_DIM / 4;  // in float4
  size_t i = (size_t)blockIdx.x * 256 + threadIdx.x;
  const float4* p04 = (const float4*)pk;
  const float4* p14 = (const float4*)(pk + (size_t)M_ROWS * E_DIM);
  float4* o4 = (float4*)out;
#pragma unroll
  for (int k = 0; k < 4; k++) {
    size_t idx = i + (size_t)k * 524288;
    if (idx < MN4) {
      float4 o = o4[idx], a = p04[idx], b = p14[idx];
      o.x += a.x + b.x; o.y += a.y + b.y;
      o.z += a.z + b.z; o.w += a.w + b.w;
      o4[idx] = o;
    }
  }
}

// ==== GEMM 256x256xBK64, 8-phase + 1-phase REGISTER READ-AHEAD ======
// Per phase: {ds_read NEXT phase's frags into alternate reg set;
// stage 1 unit (2 gload_lds); sched_barrier; setprio(1); 16 MFMA on
// CURRENT set; setprio(0); sched_barrier; vmcnt(6); s_barrier}.
// LDS service of phase P+1's reads overlaps phase P's MFMA; the only
// lgkm waits are compiler-counted before each MFMA (operands read one
// phase earlier -> already complete).  ONE barrier/phase.
// Ledger: every read targets stages 4-5 phases old; vmcnt(6) at every
// phase end + barrier forces them complete across all waves.  Last
// iter: 6,6,4,4,0 then none.  Consumption (db,ks,mh) order p0..p7 =
// (000)(001)(010)(011)(100)(101)(110)(111); stagger as round 6.
// MODE 0: bf16 C.  MODE 2: silu(Extra bf16)*acc.  MODE 3: f32 split-K
// partial at Cout + kz*M*N.
template <int MODE>
__global__ __launch_bounds__(512, 1) void gemm8pp(const u16* __restrict__ A,
                                                  const u16* __restrict__ BT,
                                                  void* __restrict__ Cout,
                                                  const void* __restrict__ Extra,
                                                  int N, int K, int lda, int ldb,
                                                  int CX, int CY) {
  constexpr int AUNIT = 8192;  // 256 rows x 32 cols (paired-row units)
  __shared__ u16 Abuf[4 * AUNIT];
  __shared__ u16 Bbuf[4 * AUNIT];
  const int t = threadIdx.x;
  const int w = t >> 6, l = t & 63, g = l >> 4, lq = l & 15;
  const int wm = w >> 2, wn = w & 3;

  // 2-D XCD chunk swizzle (+ kz for split-K): nchx*nchy*gz == 8
  const int bid = (blockIdx.z * gridDim.y + blockIdx.y) * gridDim.x + blockIdx.x;
  const int xcd = bid & 7, slot = bid >> 3;
  const int nchx = gridDim.x / CX;
  const int nchy = gridDim.y / CY;
  const int cpz = nchx * nchy;
  const int kz = xcd / cpz;
  const int cid = xcd % cpz;
  const int bx = (cid % nchx) * CX + (slot % CX);
  const int by = (cid / nchx) * CY + (slot / CX);
  const size_t bm = (size_t)by * 256, bn = (size_t)bx * 256;
  const size_t koff = (size_t)kz * K;

  // staging lane constants (paired-row)
  const int srcrow = ((l >> 3) << 1) | (l & 1);
  const int csrc = ((((l >> 1) & 3) ^ ((l >> 3) & 3)) << 3);
  const u16* aSrc = A + (bm + w * 16 + srcrow) * (size_t)lda + koff + csrc;
  const u16* bSrc = BT + (bn + w * 16 + srcrow) * (size_t)ldb + koff + csrc;
  const int rdoff = (((lq & 1) + 2 * (g ^ ((lq >> 1) & 3))) << 3);

#define STA(DB, KS, TILE)                                                     \
  {                                                                           \
    u16* Ad = Abuf + (DB) * (2 * AUNIT) + (KS)*AUNIT + w * 512;               \
    const u16* as_ = aSrc + (size_t)(TILE)*64 + (KS)*32;                      \
    async16(Ad, as_);                                                         \
    async16(Ad + 4096, as_ + (size_t)128 * lda);                              \
  }
#define STB(DB, KS, TILE)                                                     \
  {                                                                           \
    u16* Bd = Bbuf + (DB) * (2 * AUNIT) + (KS)*AUNIT + w * 512;               \
    const u16* bs_ = bSrc + (size_t)(TILE)*64 + (KS)*32;                      \
    async16(Bd, bs_);                                                         \
    async16(Bd + 4096, bs_ + (size_t)128 * ldb);                              \
  }
#define RDA(DST, DB, KS, MH)                                                  \
  _Pragma("unroll") for (int mm = 0; mm < 4; ++mm)                            \
      DST[mm] = *(const short8*)(Abuf + (DB) * (2 * AUNIT) + (KS)*AUNIT +     \
                                 (wm * 64 + (MH)*32 + mm * 8 + (lq >> 1)) *   \
                                     64 + rdoff);
#define RDB(DST, DB, KS)                                                      \
  _Pragma("unroll") for (int nn = 0; nn < 4; ++nn)                            \
      DST[nn] = *(const short8*)(Bbuf + (DB) * (2 * AUNIT) + (KS)*AUNIT +     \
                                 (wn * 32 + nn * 8 + (lq >> 1)) * 64 + rdoff);
#define MMA(AF, BF, MH)                                                       \
  _Pragma("unroll") for (int mm = 0; mm < 4; ++mm)                            \
      _Pragma("unroll") for (int nn = 0; nn < 4; ++nn)                        \
          acc[(MH)*4 + mm][nn] = __builtin_amdgcn_mfma_f32_16x16x32_bf16(     \
              AF[mm], BF[nn], acc[(MH)*4 + mm][nn], 0, 0, 0);
#define PIN __builtin_amdgcn_sched_barrier(0);
#define SP1 __builtin_amdgcn_s_setprio(1);
#define PH_END(VN_STR)                                                        \
  __builtin_amdgcn_s_setprio(0);                                              \
  __builtin_amdgcn_sched_barrier(0);                                          \
  asm volatile("s_waitcnt vmcnt(" VN_STR ")" ::: "memory");                   \
  __builtin_amdgcn_s_barrier();
#define PH_ENDN                                                               \
  __builtin_amdgcn_s_setprio(0);                                              \
  __builtin_amdgcn_sched_barrier(0);                                          \
  __builtin_amdgcn_s_barrier();

  const int NT = K >> 6, NI = NT >> 1;
  f32x4 acc[8][4] = {};
  short8 af0[4], af1[4], bf0[4], bf1[4];

  // prologue: stage t0 both halves + t1-ks0; complete (0,0); preload
  STA(0, 0, 0); STB(0, 0, 0);
  STA(0, 1, 0); STB(0, 1, 0);
  STA(1, 0, 1); STB(1, 0, 1);
  asm volatile("s_waitcnt vmcnt(8)" ::: "memory");
  __builtin_amdgcn_s_barrier();
  RDA(af0, 0, 0, 0); RDB(bf0, 0, 0);

  for (int j = 0; j < NI; ++j) {
    const int t1 = 2 * j + 1, t2 = 2 * j + 2, t3 = 2 * j + 3;
    const bool s2 = t2 < NT, s3 = t3 < NT, li = (j + 1 == NI);
    // p0: consume (0,0,0); read af1<-(0,0,1); stage A(1,1)<-t1
    RDA(af1, 0, 0, 1);
    STA(1, 1, t1);
    PIN; SP1; MMA(af0, bf0, 0);
    PH_END("6")
    // p1: consume (0,0,1); read af0<-(0,1,0), bf1<-(0,1); stage B(1,1)
    RDA(af0, 0, 1, 0); RDB(bf1, 0, 1);
    STB(1, 1, t1);
    PIN; SP1; MMA(af1, bf0, 1);
    PH_END("6")
    // p2: consume (0,1,0); read af1<-(0,1,1); stage A(0,0)<-t2
    RDA(af1, 0, 1, 1);
    if (s2) STA(0, 0, t2);
    PIN; SP1; MMA(af0, bf1, 0);
    if (li) { PH_END("4") } else { PH_END("6") }
    // p3: consume (0,1,1); read af0<-(1,0,0), bf0<-(1,0); stage B(0,0)
    RDA(af0, 1, 0, 0); RDB(bf0, 1, 0);
    if (s2) STB(0, 0, t2);
    PIN; SP1; MMA(af1, bf1, 1);
    if (li) { PH_END("4") } else { PH_END("6") }
    // p4: consume (1,0,0); read af1<-(1,0,1); stage A(0,1)<-t2
    RDA(af1, 1, 0, 1);
    if (s2) STA(0, 1, t2);
    PIN; SP1; MMA(af0, bf0, 0);
    if (li) { PH_END("0") } else { PH_END("6") }
    // p5: consume (1,0,1); read af0<-(1,1,0), bf1<-(1,1); stage B(0,1)
    RDA(af0, 1, 1, 0); RDB(bf1, 1, 1);
    if (s2) STB(0, 1, t2);
    PIN; SP1; MMA(af1, bf0, 1);
    if (li) { PH_ENDN } else { PH_END("6") }
    // p6: consume (1,1,0); read af1<-(1,1,1); stage A(1,0)<-t3
    RDA(af1, 1, 1, 1);
    if (s3) STA(1, 0, t3);
    PIN; SP1; MMA(af0, bf1, 0);
    if (li) { PH_ENDN } else { PH_END("6") }
    // p7: consume (1,1,1); read af0,bf0<-(0,0) of next pair; stage B(1,0)
    if (!li) { RDA(af0, 0, 0, 0); RDB(bf0, 0, 0); }
    if (s3) STB(1, 0, t3);
    PIN; SP1; MMA(af1, bf1, 1);
    if (li) { PH_ENDN } else { PH_END("6") }
  }
#undef STA
#undef STB
#undef RDA
#undef RDB
#undef MMA
#undef PIN
#undef SP1
#undef PH_END
#undef PH_ENDN

  const size_t mn = (size_t)gridDim.y * 256 * (size_t)N;
#pragma unroll
  for (int m = 0; m < 8; m++) {
    size_t row = bm + wm * 128 + m * 16 + 4 * g;
#pragma unroll
    for (int n = 0; n < 4; n++) {
      size_t col = bn + wn * 64 + n * 16 + lq;
#pragma unroll
      for (int r = 0; r < 4; r++) {
        size_t idx = (row + r) * (size_t)N + col;
        if constexpr (MODE == 0) {
          ((u16*)Cout)[idx] = f2bf(acc[m][n][r]);
        } else if constexpr (MODE == 2) {
          float a = bf2f(((const u16*)Extra)[idx]);
          float sil = a / (1.f + exp2f(-1.4426950408889634f * a));
          ((u16*)Cout)[idx] = f2bf(sil * acc[m][n][r]);
        } else {
          ((float*)Cout)[(size_t)kz * mn + idx] = acc[m][n][r];
        }
      }
    }
  }
}

// ======= GEMM BM_x256xBK64, 8-phase schedule, paired-row LDS ========
// (round-10 structure; only BM_=128 instantiated: QKV and WO)
template <int MODE, int BM_>
__global__ __launch_bounds__(512, 1) void gemm8p(const u16* __restrict__ A,
                                                 const u16* __restrict__ BT,
                                                 void* __restrict__ Cout,
                                                 const void* __restrict__ Extra,
                                                 int N, int K, int lda, int ldb,
                                                 int CX, int CY) {
  constexpr int MM = BM_ / 64;
  constexpr int AUNIT = BM_ * 32;
  __shared__ u16 Abuf[4 * AUNIT];
  __shared__ u16 Bbuf[4 * 8192];
  const int t = threadIdx.x;
  const int w = t >> 6, l = t & 63, g = l >> 4, lq = l & 15;
  const int wm = w >> 2, wn = w & 3;

  const int bid = (blockIdx.z * gridDim.y + blockIdx.y) * gridDim.x + blockIdx.x;
  const int xcd = bid & 7, slot = bid >> 3;
  const int nchx = gridDim.x / CX;
  const int nchy = gridDim.y / CY;
  const int cpz = nchx * nchy;
  const int kz = xcd / cpz;
  const int cid = xcd % cpz;
  const int bx = (cid % nchx) * CX + (slot % CX);
  const int by = (cid / nchx) * CY + (slot / CX);
  const size_t bm = (size_t)by * BM_, bn = (size_t)bx * 256;
  const size_t koff = (size_t)kz * K;

  const int srcrow = ((l >> 3) << 1) | (l & 1);
  const int csrc = ((((l >> 1) & 3) ^ ((l >> 3) & 3)) << 3);
  const u16* aSrc = A + (bm + w * 16 + srcrow) * (size_t)lda + koff + csrc;
  const u16* bSrc = BT + (bn + w * 16 + srcrow) * (size_t)ldb + koff + csrc;
  const int rdoff = (((lq & 1) + 2 * (g ^ ((lq >> 1) & 3))) << 3);

#define STA8(DB, KS, TILE)                                                    \
  {                                                                           \
    u16* Ad = Abuf + (DB) * (2 * AUNIT) + (KS)*AUNIT + w * 512;               \
    const u16* as_ = aSrc + (size_t)(TILE)*64 + (KS)*32;                      \
    async16(Ad, as_);                                                         \
    if constexpr (BM_ == 256) async16(Ad + 4096, as_ + (size_t)128 * lda);    \
  }
#define STB8(DB, KS, TILE)                                                    \
  {                                                                           \
    u16* Bd = Bbuf + (DB)*16384 + (KS)*8192 + w * 512;                        \
    const u16* bs_ = bSrc + (size_t)(TILE)*64 + (KS)*32;                      \
    async16(Bd, bs_);                                                         \
    async16(Bd + 4096, bs_ + (size_t)128 * ldb);                              \
  }
#define RDA8(DB, KS, MH)                                                      \
  _Pragma("unroll") for (int mm = 0; mm < MM; ++mm)                           \
      af[mm] = *(const short8*)(Abuf + (DB) * (2 * AUNIT) + (KS)*AUNIT +      \
                                (wm * (BM_ / 4) + (MH) * (BM_ / 8) + mm * 8 + \
                                 (lq >> 1)) * 64 + rdoff);
#define RDB8(DB, KS)                                                          \
  _Pragma("unroll") for (int nn = 0; nn < 4; ++nn)                            \
      bf[nn] = *(const short8*)(Bbuf + (DB)*16384 + (KS)*8192 +               \
                                (wn * 32 + nn * 8 + (lq >> 1)) * 64 + rdoff);
#define MM168(MH)                                                             \
  _Pragma("unroll") for (int mm = 0; mm < MM; ++mm)                           \
      _Pragma("unroll") for (int nn = 0; nn < 4; ++nn)                        \
          acc[(MH)*MM + mm][nn] = __builtin_amdgcn_mfma_f32_16x16x32_bf16(    \
              af[mm], bf[nn], acc[(MH)*MM + mm][nn], 0, 0, 0);
#define SYNCA                                                                 \
  __builtin_amdgcn_s_barrier();                                               \
  asm volatile("s_waitcnt lgkmcnt(0)" ::: "memory");                          \
  __builtin_amdgcn_sched_barrier(0);                                          \
  __builtin_amdgcn_s_setprio(1);
#define ENDP __builtin_amdgcn_s_setprio(0);
#define BAR2 __builtin_amdgcn_s_barrier();
#define WAITN                                                                 \
  if constexpr (BM_ == 256) asm volatile("s_waitcnt vmcnt(8)" ::: "memory");  \
  else                      asm volatile("s_waitcnt vmcnt(6)" ::: "memory");
#define WAITH                                                                 \
  if constexpr (BM_ == 256) asm volatile("s_waitcnt vmcnt(4)" ::: "memory");  \
  else                      asm volatile("s_waitcnt vmcnt(3)" ::: "memory");

  const int NT = K >> 6, NI = NT >> 1;
  f32x4 acc[2 * MM][4] = {};
  short8 af[MM > 4 ? MM : 4], bf[4];

  STA8(0, 0, 0); STB8(0, 0, 0);
  STA8(0, 1, 0); STB8(0, 1, 0);
  STA8(1, 0, 1); STB8(1, 0, 1);
  WAITN;
  BAR2;

  for (int j = 0; j < NI; ++j) {
    const int t1 = 2 * j + 1, t2 = 2 * j + 2, t3 = 2 * j + 3;
    const bool s2 = t2 < NT, s3 = t3 < NT, lastI = (j + 1 == NI);
    RDB8(0, 0); RDA8(0, 0, 0);
    STA8(1, 1, t1);
    SYNCA; MM168(0); ENDP; BAR2;
    RDA8(0, 0, 1);
    STB8(1, 1, t1);
    SYNCA; MM168(1); ENDP;
    WAITN;
    BAR2;
    RDB8(0, 1); RDA8(0, 1, 0);
    if (s2) STA8(0, 0, t2);
    SYNCA; MM168(0); ENDP; BAR2;
    RDA8(0, 1, 1);
    if (s2) STB8(0, 0, t2);
    SYNCA; MM168(1); ENDP;
    if (lastI) { WAITH; } else { WAITN; }
    BAR2;
    RDB8(1, 0); RDA8(1, 0, 0);
    if (s2) STA8(0, 1, t2);
    SYNCA; MM168(0); ENDP; BAR2;
    RDA8(1, 0, 1);
    if (s2) STB8(0, 1, t2);
    SYNCA; MM168(1); ENDP;
    if (lastI) { asm volatile("s_waitcnt vmcnt(0)" ::: "memory"); } else { WAITN; }
    BAR2;
    RDB8(1, 1); RDA8(1, 1, 0);
    if (s3) STA8(1, 0, t3);
    SYNCA; MM168(0); ENDP; BAR2;
    RDA8(1, 1, 1);
    if (s3) STB8(1, 0, t3);
    SYNCA; MM168(1); ENDP;
    if (!lastI) { WAITN; }
    BAR2;
  }
#undef STA8
#undef STB8
#undef RDA8
#undef RDB8
#undef MM168
#undef SYNCA
#undef ENDP
#undef BAR2
#undef WAITN
#undef WAITH

  const size_t mn = (size_t)gridDim.y * BM_ * (size_t)N;
#pragma unroll
  for (int m = 0; m < 2 * MM; m++) {
    size_t row = bm + wm * (BM_ / 2) + m * 16 + 4 * g;
#pragma unroll
    for (int n = 0; n < 4; n++) {
      size_t col = bn + wn * 64 + n * 16 + lq;
#pragma unroll
      for (int r = 0; r < 4; r++) {
        size_t idx = (row + r) * (size_t)N + col;
        if constexpr (MODE == 0) {
          ((u16*)Cout)[idx] = f2bf(acc[m][n][r]);
        } else if constexpr (MODE == 1) {
          ((float*)Cout)[idx] = ((const float*)Extra)[idx] + acc[m][n][r];
        } else if constexpr (MODE == 2) {
          float a = bf2f(((const u16*)Extra)[idx]);
          float sil = a / (1.f + exp2f(-1.4426950408889634f * a));
          ((u16*)Cout)[idx] = f2bf(sil * acc[m][n][r]);
        } else {
          ((float*)Cout)[(size_t)kz * mn + idx] = acc[m][n][r];
        }
      }
    }
  }
}

// ----------------- causal flash attention (LDS-staged) --------------
// grid (T/128, B*H); 4 waves/block; wave owns 32 q-rows (2 rg of 16).
__global__ __launch_bounds__(256, 2) void attn_kernel(const u16* __restrict__ QKV,
                                                      const u16* __restrict__ VT,
                                                      u16* __restrict__ CTX) {
  __shared__ u16 Ks[64 * 128];
  __shared__ u16 Vs[128 * 64];
  __shared__ u16 P_all[4][32 * 72];
  const int t = threadIdx.x;
  const int w = t >> 6, l = t & 63, g = l >> 4, lq = l & 15;
  u16* P = P_all[w];
  const int q0blk = blockIdx.x * 128;
  const int q0w = q0blk + w * 32;
  const int bh = blockIdx.y, b = bh >> 4, h = bh & 15;
  const u16* qp = QKV + (size_t)b * T_SEQ * QS + h * D_HEAD;
  const u16* kp = QKV + (size_t)b * T_SEQ * QS + E_DIM + h * D_HEAD;
  const u16* vp = VT + ((size_t)b * E_DIM + h * D_HEAD) * T_SEQ;

  short8 qf[2][4];
#pragma unroll
  for (int rg = 0; rg < 2; rg++)
#pragma unroll
    for (int ks = 0; ks < 4; ks++)
      qf[rg][ks] =
          *(const short8*)(qp + (size_t)(q0w + rg * 16 + lq) * QS + ks * 32 + g * 8);

  f32x4 acc[2][8] = {};
  float m2[2][4], ls[2][4];
#pragma unroll
  for (int rg = 0; rg < 2; rg++)
#pragma unroll
    for (int r = 0; r < 4; r++) { m2[rg][r] = -1e30f; ls[rg][r] = 0.f; }
  const float sc = 0.08838834764831845f * 1.4426950408889634f;

  const int kRow0 = 16 * w + (l >> 4);
  const int kChunk = l & 15;
  const int vRow0 = 32 * w + (l >> 3);
  const int vChunk = l & 7;

  for (int kv0 = 0; kv0 < q0blk + 128; kv0 += 64) {
#pragma unroll
    for (int j = 0; j < 4; j++) {
      int R = kRow0 + 4 * j;
      async16(Ks + (16 * w + 4 * j) * 128,
              kp + (size_t)(kv0 + R) * QS + ((kChunk ^ (R & 7)) << 3));
    }
#pragma unroll
    for (int j = 0; j < 4; j++) {
      int D = vRow0 + 8 * j;
      async16(Vs + (32 * w + 8 * j) * 64,
              vp + (size_t)D * T_SEQ + kv0 + ((vChunk ^ (D & 7)) << 3));
    }
    __syncthreads();

#pragma unroll
    for (int rg = 0; rg < 2; rg++) {
      const int rb = q0w + rg * 16;
      if (kv0 > rb + 15) continue;
      f32x4 s[4];
      __builtin_amdgcn_s_setprio(1);
#pragma unroll
      for (int ct = 0; ct < 4; ct++) {
        s[ct] = f32x4{0.f, 0.f, 0.f, 0.f};
#pragma unroll
        for (int ks = 0; ks < 4; ks++) {
          short8 kf = *(const short8*)(Ks + (ct * 16 + lq) * 128 +
                                       (((ks * 4 + g) ^ (lq & 7)) << 3));
          s[ct] = __builtin_amdgcn_mfma_f32_16x16x32_bf16(qf[rg][ks], kf, s[ct], 0, 0, 0);
        }
      }
      __builtin_amdgcn_s_setprio(0);
      float sv[4][4];
#pragma unroll
      for (int ct = 0; ct < 4; ct++)
#pragma unroll
        for (int r = 0; r < 4; r++) sv[ct][r] = s[ct][r] * sc;
      if (kv0 + 64 > rb) {
#pragma unroll
        for (int ct = 0; ct < 4; ct++)
#pragma unroll
          for (int r = 0; r < 4; r++)
            if (kv0 + ct * 16 + lq > rb + 4 * g + r) sv[ct][r] = -1e30f;
      }
      float mx[4];
#pragma unroll
      for (int r = 0; r < 4; r++)
        mx[r] = fmaxf(fmaxf(sv[0][r], sv[1][r]), fmaxf(sv[2][r], sv[3][r]));
#pragma unroll
      for (int off = 1; off < 16; off <<= 1)
#pragma unroll
        for (int r = 0; r < 4; r++) mx[r] = fmaxf(mx[r], __shfl_xor(mx[r], off));
#pragma unroll
      for (int r = 0; r < 4; r++) {
        float mn = fmaxf(m2[rg][r], mx[r]);
        float sca = exp2f(m2[rg][r] - mn);
        m2[rg][r] = mn;
        float sum = 0.f;
#pragma unroll
        for (int ct = 0; ct < 4; ct++) {
          float pv = exp2f(sv[ct][r] - mn);
          sum += pv;
          P[(rg * 16 + 4 * g + r) * 72 + ct * 16 + lq] = f2bf(pv);
        }
        ls[rg][r] = ls[rg][r] * sca + sum;
#pragma unroll
        for (int n = 0; n < 8; n++) acc[rg][n][r] *= sca;
      }
      short8 pa[2];
#pragma unroll
      for (int ks2 = 0; ks2 < 2; ks2++)
        pa[ks2] = *(const short8*)(P + (rg * 16 + lq) * 72 + ks2 * 32 + g * 8);
      __builtin_amdgcn_s_setprio(1);
#pragma unroll
      for (int n = 0; n < 8; n++)
#pragma unroll
        for (int ks2 = 0; ks2 < 2; ks2++) {
          short8 vf = *(const short8*)(Vs + (n * 16 + lq) * 64 +
                                       (((ks2 * 4 + g) ^ (lq & 7)) << 3));
          acc[rg][n] = __builtin_amdgcn_mfma_f32_16x16x32_bf16(pa[ks2], vf, acc[rg][n], 0, 0, 0);
        }
      __builtin_amdgcn_s_setprio(0);
    }
    __syncthreads();
  }

#pragma unroll
  for (int rg = 0; rg < 2; rg++) {
#pragma unroll
    for (int off = 1; off < 16; off <<= 1)
#pragma unroll
      for (int r = 0; r < 4; r++) ls[rg][r] += __shfl_xor(ls[rg][r], off);
  }
  u16* cp = CTX + ((size_t)b * T_SEQ + q0w) * E_DIM + h * D_HEAD;
#pragma unroll
  for (int rg = 0; rg < 2; rg++) {
    float inv[4];
#pragma unroll
    for (int r = 0; r < 4; r++) inv[r] = 1.f / ls[rg][r];
#pragma unroll
    for (int n = 0; n < 8; n++)
#pragma unroll
      for (int r = 0; r < 4; r++)
        cp[(size_t)(rg * 16 + 4 * g + r) * E_DIM + n * 16 + lq] =
            f2bf(acc[rg][n][r] * inv[r]);
  }
}

extern "C" void kernel_launch(void* const* d_in, const int* in_sizes, int n_in,
                              void* d_out, int out_size, void* d_ws, size_t ws_size,
                              hipStream_t stream) {
  (void)in_sizes; (void)n_in; (void)out_size; (void)ws_size;
  const float* x  = (const float*)d_in[0];
  const float* g1 = (const float*)d_in[1];
  const float* b1 = (const float*)d_in[2];
  const float* wq = (const float*)d_in[3];
  const float* wk = (const float*)d_in[4];
  const float* wv = (const float*)d_in[5];
  const float* wo = (const float*)d_in[6];
  const float* g2 = (const float*)d_in[7];
  const float* b2 = (const float*)d_in[8];
  const float* w1 = (const float*)d_in[9];
  const float* w2 = (const float*)d_in[10];
  const float* w3 = (const float*)d_in[11];
  float* out = (float*)d_out;

  const size_t EE2 = (size_t)E_DIM * E_DIM * 2;
  const size_t EF2 = (size_t)E_DIM * FFN_DIM * 2;
  const size_t ME2 = (size_t)M_ROWS * E_DIM * 2;
  char* p = (char*)d_ws;
  u16* wqkvT = (u16*)p; p += 3 * EE2;
  u16* woT = (u16*)p; p += EE2;
  u16* w1T = (u16*)p; p += EF2;
  u16* w2T = (u16*)p; p += EF2;
  u16* w3T = (u16*)p; p += EF2;
  u16* Hb  = (u16*)p; p += ME2;
  u16* QKVb = (u16*)p; p += (size_t)M_ROWS * QS * 2;
  u16* VTb = (u16*)p; p += ME2;
  u16* CTXb = (u16*)p; p += ME2;
  u16* U1b = QKVb;              // u1/gated reuses QKVb+VTb (64MB)
  float* Pk = (float*)wqkvT;    // w3 split-K partials (64MB, dead wqkvT+woT)

  dim3 blk32(32, 8);
  cvt_t_kernel<<<dim3(E_DIM / 32, E_DIM / 32), blk32, 0, stream>>>(wq, wqkvT, E_DIM, E_DIM);
  cvt_t_kernel<<<dim3(E_DIM / 32, E_DIM / 32), blk32, 0, stream>>>(wk, wqkvT + E_DIM * E_DIM, E_DIM, E_DIM);
  cvt_t_kernel<<<dim3(E_DIM / 32, E_DIM / 32), blk32, 0, stream>>>(wv, wqkvT + 2 * E_DIM * E_DIM, E_DIM, E_DIM);
  cvt_t_kernel<<<dim3(E_DIM / 32, E_DIM / 32), blk32, 0, stream>>>(wo, woT, E_DIM, E_DIM);
  cvt_t_kernel<<<dim3(FFN_DIM / 32, E_DIM / 32), blk32, 0, stream>>>(w1, w1T, E_DIM, FFN_DIM);
  cvt_t_kernel<<<dim3(FFN_DIM / 32, E_DIM / 32), blk32, 0, stream>>>(w2, w2T, E_DIM, FFN_DIM);
  cvt_t_kernel<<<dim3(E_DIM / 32, FFN_DIM / 32), blk32, 0, stream>>>(w3, w3T, FFN_DIM, E_DIM);

  // attention block
  ln_kernel<<<M_ROWS, 256, 0, stream>>>(x, g1, b1, Hb);
  gemm8p<0, 128><<<dim3(QS / 256, M_ROWS / 128), 512, 0, stream>>>(
      Hb, wqkvT, QKVb, nullptr, QS, E_DIM, E_DIM, E_DIM, 6, 16);
  transpose_v_kernel<<<dim3(T_SEQ / 32, E_DIM / 32, 2), blk32, 0, stream>>>(QKVb, VTb);
  attn_kernel<<<dim3(T_SEQ / 128, 2 * N_HEAD), 256, 0, stream>>>(QKVb, VTb, CTXb);
  gemm8p<1, 128><<<dim3(E_DIM / 256, M_ROWS / 128), 512, 0, stream>>>(
      CTXb, woT, out, x, E_DIM, E_DIM, E_DIM, E_DIM, 4, 8);

  // SwiGLU MLP block
  ln_kernel<<<M_ROWS, 256, 0, stream>>>(out, g2, b2, Hb);
  gemm8pp<0><<<dim3(FFN_DIM / 256, M_ROWS / 256), 512, 0, stream>>>(
      Hb, w1T, U1b, nullptr, FFN_DIM, E_DIM, E_DIM, E_DIM, 8, 8);
  gemm8pp<2><<<dim3(FFN_DIM / 256, M_ROWS / 256), 512, 0, stream>>>(
      Hb, w2T, U1b, U1b, FFN_DIM, E_DIM, E_DIM, E_DIM, 8, 8);
  // w3: split-K=2, grid (8,16,2) = 256 blocks (nchx*nchy*gz = 2*2*2)
  gemm8pp<3><<<dim3(E_DIM / 256, M_ROWS / 256, 2), 512, 0, stream>>>(
      U1b, w3T, Pk, nullptr, E_DIM, FFN_DIM / 2, FFN_DIM, FFN_DIM, 4, 8);
  add3_kernel<<<2048, 256, 0, stream>>>(out, Pk);
}

// Round 13
// 920.514 us; speedup vs baseline: 1.1738x; 1.1738x over previous
//
#include <hip/hip_runtime.h>

// Transformer layer, bf16 MFMA compute, fp32 I/O.
// B=2 T=2048 E=2048 H=16 DH=128 FFN=8192. Needs ~256MB workspace.

#define T_SEQ 2048
#define E_DIM 2048
#define N_HEAD 16
#define D_HEAD 128
#define FFN_DIM 8192
#define M_ROWS 4096  // B*T
#define QS (3 * E_DIM)  // fused QKV row stride

typedef unsigned short u16;
typedef short short8 __attribute__((ext_vector_type(8)));
typedef float f32x4 __attribute__((ext_vector_type(4)));

#define DEV __device__ __forceinline__

DEV u16 f2bf(float f) {
  unsigned u = __float_as_uint(f);
  u += 0x7fffu + ((u >> 16) & 1u);
  return (u16)(u >> 16);
}
DEV float bf2f(u16 h) { return __uint_as_float(((unsigned)h) << 16); }

DEV void async16(void* lds, const void* g) {
  __builtin_amdgcn_global_load_lds((const __attribute__((address_space(1))) void*)g,
                                   (__attribute__((address_space(3))) void*)lds, 16, 0, 0);
}

// ---------------- LayerNorm: fp32 [rows][E] -> bf16 -----------------
__global__ __launch_bounds__(256) void ln_kernel(const float* __restrict__ x,
                                                 const float* __restrict__ gw,
                                                 const float* __restrict__ bw,
                                                 u16* __restrict__ out) {
  int row = blockIdx.x;
  int t = threadIdx.x;
  const float4* xr = (const float4*)(x + (size_t)row * E_DIM);
  float4 a = xr[t], c = xr[t + 256];
  float s = a.x + a.y + a.z + a.w + c.x + c.y + c.z + c.w;
  float q = a.x * a.x + a.y * a.y + a.z * a.z + a.w * a.w +
            c.x * c.x + c.y * c.y + c.z * c.z + c.w * c.w;
  for (int off = 32; off > 0; off >>= 1) {
    s += __shfl_down(s, off);
    q += __shfl_down(q, off);
  }
  __shared__ float red[8];
  if ((t & 63) == 0) { red[(t >> 6) * 2] = s; red[(t >> 6) * 2 + 1] = q; }
  __syncthreads();
  s = red[0] + red[2] + red[4] + red[6];
  q = red[1] + red[3] + red[5] + red[7];
  float mu = s * (1.f / E_DIM);
  float rs = rsqrtf(q * (1.f / E_DIM) - mu * mu + 1e-5f);
  const float4* g4 = (const float4*)gw;
  const float4* b4 = (const float4*)bw;
  float4 g0 = g4[t], g1v = g4[t + 256], e0 = b4[t], e1 = b4[t + 256];
  ushort4 o0, o1;
  o0.x = f2bf((a.x - mu) * rs * g0.x + e0.x);
  o0.y = f2bf((a.y - mu) * rs * g0.y + e0.y);
  o0.z = f2bf((a.z - mu) * rs * g0.z + e0.z);
  o0.w = f2bf((a.w - mu) * rs * g0.w + e0.w);
  o1.x = f2bf((c.x - mu) * rs * g1v.x + e1.x);
  o1.y = f2bf((c.y - mu) * rs * g1v.y + e1.y);
  o1.z = f2bf((c.z - mu) * rs * g1v.z + e1.z);
  o1.w = f2bf((c.w - mu) * rs * g1v.w + e1.w);
  ((ushort4*)(out + (size_t)row * E_DIM))[t] = o0;
  ((ushort4*)(out + (size_t)row * E_DIM))[t + 256] = o1;
}

// ------- convert+transpose: fp32 W[K][N] -> bf16 WT[N][K] -----------
__global__ __launch_bounds__(256) void cvt_t_kernel(const float* __restrict__ W,
                                                    u16* __restrict__ WT,
                                                    int Kd, int Nd) {
  __shared__ float tile[32][33];
  int tx = threadIdx.x, ty = threadIdx.y;
  int n0 = blockIdx.x * 32, k0 = blockIdx.y * 32;
#pragma unroll
  for (int i = 0; i < 4; i++)
    tile[ty + i * 8][tx] = W[(size_t)(k0 + ty + i * 8) * Nd + n0 + tx];
  __syncthreads();
#pragma unroll
  for (int i = 0; i < 4; i++)
    WT[(size_t)(n0 + ty + i * 8) * Kd + k0 + tx] = f2bf(tile[tx][ty + i * 8]);
}

// -- transpose V from fused QKV: bf16 [B*T][QS] col 4096+ -> [B][E][T]
__global__ __launch_bounds__(256) void transpose_v_kernel(const u16* __restrict__ qkv,
                                                          u16* __restrict__ vt) {
  __shared__ u16 tile[32][33];
  int tx = threadIdx.x, ty = threadIdx.y;
  int b = blockIdx.z;
  int t0 = blockIdx.x * 32, e0 = blockIdx.y * 32;
#pragma unroll
  for (int i = 0; i < 4; i++)
    tile[ty + i * 8][tx] =
        qkv[(size_t)(b * T_SEQ + t0 + ty + i * 8) * QS + 2 * E_DIM + e0 + tx];
  __syncthreads();
#pragma unroll
  for (int i = 0; i < 4; i++)
    vt[((size_t)b * E_DIM + e0 + ty + i * 8) * T_SEQ + t0 + tx] = tile[tx][ty + i * 8];
}

// ------------- add3: out += P0 + P1 (split-K reduction) -------------
__global__ __launch_bounds__(256) void add3_kernel(float* __restrict__ out,
                                                   const float* __restrict__ pk) {
  const size_t MN4 = (size_t)M_ROWS * E_DIM / 4;  // in float4
  size_t i = (size_t)blockIdx.x * 256 + threadIdx.x;
  const float4* p04 = (const float4*)pk;
  const float4* p14 = (const float4*)(pk + (size_t)M_ROWS * E_DIM);
  float4* o4 = (float4*)out;
#pragma unroll
  for (int k = 0; k < 4; k++) {
    size_t idx = i + (size_t)k * 524288;
    if (idx < MN4) {
      float4 o = o4[idx], a = p04[idx], b = p14[idx];
      o.x += a.x + b.x; o.y += a.y + b.y;
      o.z += a.z + b.z; o.w += a.w + b.w;
      o4[idx] = o;
    }
  }
}

// === GEMM 256x256xBK64, 4 MERGED phases / 2 K-tiles (r10 + merge) ===
// Same proven two-barrier bracket as round-10's gemm8p, but mh0+mh1
// merged: each phase = {12 ds_read (8 A-frags + 4 B-frags) + stage one
// A-unit AND B-unit (4 gload_lds); barrier; lgkmcnt(0); setprio(1);
// 32 MFMA; setprio(0); vmcnt(8); barrier}.  Halves barrier/wait
// overhead per K-tile-pair; read->stage hazards identical to r10.
// Ledger: phase P reads the slot staged in phase P-3; at end of P-1
// outstanding <= 12 (phases P-3,P-2,P-1); vmcnt(8) completes P-3's 4.
// Prologue stages 6 units; vmcnt(8) before P0.  Last iter: 8/4/0.
// MODE 0: bf16 C.  MODE 2: silu(Extra bf16)*acc.  MODE 3: f32 split-K
// partial at Cout + kz*M*N.
template <int MODE>
__global__ __launch_bounds__(512, 1) void gemm4m(const u16* __restrict__ A,
                                                 const u16* __restrict__ BT,
                                                 void* __restrict__ Cout,
                                                 const void* __restrict__ Extra,
                                                 int N, int K, int lda, int ldb,
                                                 int CX, int CY) {
  constexpr int AUNIT = 8192;  // 256 rows x 32 cols (paired-row unit)
  __shared__ u16 Abuf[4 * AUNIT];
  __shared__ u16 Bbuf[4 * AUNIT];
  const int t = threadIdx.x;
  const int w = t >> 6, l = t & 63, g = l >> 4, lq = l & 15;
  const int wm = w >> 2, wn = w & 3;

  // 2-D XCD chunk swizzle (+ kz for split-K): nchx*nchy*gz == 8
  const int bid = (blockIdx.z * gridDim.y + blockIdx.y) * gridDim.x + blockIdx.x;
  const int xcd = bid & 7, slot = bid >> 3;
  const int nchx = gridDim.x / CX;
  const int nchy = gridDim.y / CY;
  const int cpz = nchx * nchy;
  const int kz = xcd / cpz;
  const int cid = xcd % cpz;
  const int bx = (cid % nchx) * CX + (slot % CX);
  const int by = (cid / nchx) * CY + (slot / CX);
  const size_t bm = (size_t)by * 256, bn = (size_t)bx * 256;
  const size_t koff = (size_t)kz * K;

  // staging lane constants (paired-row)
  const int srcrow = ((l >> 3) << 1) | (l & 1);
  const int csrc = ((((l >> 1) & 3) ^ ((l >> 3) & 3)) << 3);
  const u16* aSrc = A + (bm + w * 16 + srcrow) * (size_t)lda + koff + csrc;
  const u16* bSrc = BT + (bn + w * 16 + srcrow) * (size_t)ldb + koff + csrc;
  const int rdoff = (((lq & 1) + 2 * (g ^ ((lq >> 1) & 3))) << 3);

#define STA(DB, KS, TILE)                                                     \
  {                                                                           \
    u16* Ad = Abuf + (DB) * (2 * AUNIT) + (KS)*AUNIT + w * 512;               \
    const u16* as_ = aSrc + (size_t)(TILE)*64 + (KS)*32;                      \
    async16(Ad, as_);                                                         \
    async16(Ad + 4096, as_ + (size_t)128 * lda);                              \
  }
#define STB(DB, KS, TILE)                                                     \
  {                                                                           \
    u16* Bd = Bbuf + (DB) * (2 * AUNIT) + (KS)*AUNIT + w * 512;               \
    const u16* bs_ = bSrc + (size_t)(TILE)*64 + (KS)*32;                      \
    async16(Bd, bs_);                                                         \
    async16(Bd + 4096, bs_ + (size_t)128 * ldb);                              \
  }
#define RDA2(DB, KS)                                                          \
  _Pragma("unroll") for (int mm = 0; mm < 8; ++mm)                            \
      af[mm] = *(const short8*)(Abuf + (DB) * (2 * AUNIT) + (KS)*AUNIT +      \
                                (wm * 64 + mm * 8 + (lq >> 1)) * 64 + rdoff);
#define RDB2(DB, KS)                                                          \
  _Pragma("unroll") for (int nn = 0; nn < 4; ++nn)                            \
      bf[nn] = *(const short8*)(Bbuf + (DB) * (2 * AUNIT) + (KS)*AUNIT +      \
                                (wn * 32 + nn * 8 + (lq >> 1)) * 64 + rdoff);
#define MM32                                                                  \
  _Pragma("unroll") for (int mm = 0; mm < 8; ++mm)                            \
      _Pragma("unroll") for (int nn = 0; nn < 4; ++nn)                        \
          acc[mm][nn] = __builtin_amdgcn_mfma_f32_16x16x32_bf16(              \
              af[mm], bf[nn], acc[mm][nn], 0, 0, 0);
#define SYNCA                                                                 \
  __builtin_amdgcn_s_barrier();                                               \
  asm volatile("s_waitcnt lgkmcnt(0)" ::: "memory");                          \
  __builtin_amdgcn_sched_barrier(0);                                          \
  __builtin_amdgcn_s_setprio(1);
#define PH_END(VN_STR)                                                        \
  __builtin_amdgcn_s_setprio(0);                                              \
  asm volatile("s_waitcnt vmcnt(" VN_STR ")" ::: "memory");                   \
  __builtin_amdgcn_s_barrier();

  const int NT = K >> 6, NI = NT >> 1;
  f32x4 acc[8][4] = {};
  short8 af[8], bf[4];

  // prologue: tile0 both K-halves + tile1 K-half0 (6 units, 12 loads)
  STA(0, 0, 0); STB(0, 0, 0);
  STA(0, 1, 0); STB(0, 1, 0);
  STA(1, 0, 1); STB(1, 0, 1);
  asm volatile("s_waitcnt vmcnt(8)" ::: "memory");  // (0,0) A+B resident
  __builtin_amdgcn_s_barrier();

  for (int j = 0; j < NI; ++j) {
    const int t1 = 2 * j + 1, t2 = 2 * j + 2, t3 = 2 * j + 3;
    const bool s2 = t2 < NT, s3 = t3 < NT, li = (j + 1 == NI);
    // P0: consume (0,0); stage (1,1)<-t1
    RDA2(0, 0); RDB2(0, 0);
    STA(1, 1, t1); STB(1, 1, t1);
    SYNCA; MM32;
    PH_END("8")
    // P1: consume (0,1); stage (0,0)<-t2
    RDA2(0, 1); RDB2(0, 1);
    if (s2) { STA(0, 0, t2); STB(0, 0, t2); }
    SYNCA; MM32;
    if (li) { PH_END("4") } else { PH_END("8") }
    // P2: consume (1,0); stage (0,1)<-t2
    RDA2(1, 0); RDB2(1, 0);
    if (s2) { STA(0, 1, t2); STB(0, 1, t2); }
    SYNCA; MM32;
    if (li) { PH_END("0") } else { PH_END("8") }
    // P3: consume (1,1); stage (1,0)<-t3
    RDA2(1, 1); RDB2(1, 1);
    if (s3) { STA(1, 0, t3); STB(1, 0, t3); }
    SYNCA; MM32;
    if (li) {
      __builtin_amdgcn_s_setprio(0);
    } else {
      PH_END("8")
    }
  }
#undef STA
#undef STB
#undef RDA2
#undef RDB2
#undef MM32
#undef SYNCA
#undef PH_END

  const size_t mn = (size_t)gridDim.y * 256 * (size_t)N;
#pragma unroll
  for (int m = 0; m < 8; m++) {
    size_t row = bm + wm * 128 + m * 16 + 4 * g;
#pragma unroll
    for (int n = 0; n < 4; n++) {
      size_t col = bn + wn * 64 + n * 16 + lq;
#pragma unroll
      for (int r = 0; r < 4; r++) {
        size_t idx = (row + r) * (size_t)N + col;
        if constexpr (MODE == 0) {
          ((u16*)Cout)[idx] = f2bf(acc[m][n][r]);
        } else if constexpr (MODE == 2) {
          float a = bf2f(((const u16*)Extra)[idx]);
          float sil = a / (1.f + exp2f(-1.4426950408889634f * a));
          ((u16*)Cout)[idx] = f2bf(sil * acc[m][n][r]);
        } else {
          ((float*)Cout)[(size_t)kz * mn + idx] = acc[m][n][r];
        }
      }
    }
  }
}

// ======= GEMM BM128x256xBK64, 8-phase schedule (round-10 exact) =====
// Used for QKV (MODE 0) and WO (MODE 1).
template <int MODE, int BM_>
__global__ __launch_bounds__(512, 1) void gemm8p(const u16* __restrict__ A,
                                                 const u16* __restrict__ BT,
                                                 void* __restrict__ Cout,
                                                 const void* __restrict__ Extra,
                                                 int N, int K, int lda, int ldb,
                                                 int CX, int CY) {
  constexpr int MM = BM_ / 64;
  constexpr int AUNIT = BM_ * 32;
  __shared__ u16 Abuf[4 * AUNIT];
  __shared__ u16 Bbuf[4 * 8192];
  const int t = threadIdx.x;
  const int w = t >> 6, l = t & 63, g = l >> 4, lq = l & 15;
  const int wm = w >> 2, wn = w & 3;

  const int bid = (blockIdx.z * gridDim.y + blockIdx.y) * gridDim.x + blockIdx.x;
  const int xcd = bid & 7, slot = bid >> 3;
  const int nchx = gridDim.x / CX;
  const int nchy = gridDim.y / CY;
  const int cpz = nchx * nchy;
  const int kz = xcd / cpz;
  const int cid = xcd % cpz;
  const int bx = (cid % nchx) * CX + (slot % CX);
  const int by = (cid / nchx) * CY + (slot / CX);
  const size_t bm = (size_t)by * BM_, bn = (size_t)bx * 256;
  const size_t koff = (size_t)kz * K;

  const int srcrow = ((l >> 3) << 1) | (l & 1);
  const int csrc = ((((l >> 1) & 3) ^ ((l >> 3) & 3)) << 3);
  const u16* aSrc = A + (bm + w * 16 + srcrow) * (size_t)lda + koff + csrc;
  const u16* bSrc = BT + (bn + w * 16 + srcrow) * (size_t)ldb + koff + csrc;
  const int rdoff = (((lq & 1) + 2 * (g ^ ((lq >> 1) & 3))) << 3);

#define STA8(DB, KS, TILE)                                                    \
  {                                                                           \
    u16* Ad = Abuf + (DB) * (2 * AUNIT) + (KS)*AUNIT + w * 512;               \
    const u16* as_ = aSrc + (size_t)(TILE)*64 + (KS)*32;                      \
    async16(Ad, as_);                                                         \
    if constexpr (BM_ == 256) async16(Ad + 4096, as_ + (size_t)128 * lda);    \
  }
#define STB8(DB, KS, TILE)                                                    \
  {                                                                           \
    u16* Bd = Bbuf + (DB)*16384 + (KS)*8192 + w * 512;                        \
    const u16* bs_ = bSrc + (size_t)(TILE)*64 + (KS)*32;                      \
    async16(Bd, bs_);                                                         \
    async16(Bd + 4096, bs_ + (size_t)128 * ldb);                              \
  }
#define RDA8(DB, KS, MH)                                                      \
  _Pragma("unroll") for (int mm = 0; mm < MM; ++mm)                           \
      af[mm] = *(const short8*)(Abuf + (DB) * (2 * AUNIT) + (KS)*AUNIT +      \
                                (wm * (BM_ / 4) + (MH) * (BM_ / 8) + mm * 8 + \
                                 (lq >> 1)) * 64 + rdoff);
#define RDB8(DB, KS)                                                          \
  _Pragma("unroll") for (int nn = 0; nn < 4; ++nn)                            \
      bf[nn] = *(const short8*)(Bbuf + (DB)*16384 + (KS)*8192 +               \
                                (wn * 32 + nn * 8 + (lq >> 1)) * 64 + rdoff);
#define MM168(MH)                                                             \
  _Pragma("unroll") for (int mm = 0; mm < MM; ++mm)                           \
      _Pragma("unroll") for (int nn = 0; nn < 4; ++nn)                        \
          acc[(MH)*MM + mm][nn] = __builtin_amdgcn_mfma_f32_16x16x32_bf16(    \
              af[mm], bf[nn], acc[(MH)*MM + mm][nn], 0, 0, 0);
#define SYNCA                                                                 \
  __builtin_amdgcn_s_barrier();                                               \
  asm volatile("s_waitcnt lgkmcnt(0)" ::: "memory");                          \
  __builtin_amdgcn_sched_barrier(0);                                          \
  __builtin_amdgcn_s_setprio(1);
#define ENDP __builtin_amdgcn_s_setprio(0);
#define BAR2 __builtin_amdgcn_s_barrier();
#define WAITN                                                                 \
  if constexpr (BM_ == 256) asm volatile("s_waitcnt vmcnt(8)" ::: "memory");  \
  else                      asm volatile("s_waitcnt vmcnt(6)" ::: "memory");
#define WAITH                                                                 \
  if constexpr (BM_ == 256) asm volatile("s_waitcnt vmcnt(4)" ::: "memory");  \
  else                      asm volatile("s_waitcnt vmcnt(3)" ::: "memory");

  const int NT = K >> 6, NI = NT >> 1;
  f32x4 acc[2 * MM][4] = {};
  short8 af[MM > 4 ? MM : 4], bf[4];

  STA8(0, 0, 0); STB8(0, 0, 0);
  STA8(0, 1, 0); STB8(0, 1, 0);
  STA8(1, 0, 1); STB8(1, 0, 1);
  WAITN;
  BAR2;

  for (int j = 0; j < NI; ++j) {
    const int t1 = 2 * j + 1, t2 = 2 * j + 2, t3 = 2 * j + 3;
    const bool s2 = t2 < NT, s3 = t3 < NT, lastI = (j + 1 == NI);
    RDB8(0, 0); RDA8(0, 0, 0);
    STA8(1, 1, t1);
    SYNCA; MM168(0); ENDP; BAR2;
    RDA8(0, 0, 1);
    STB8(1, 1, t1);
    SYNCA; MM168(1); ENDP;
    WAITN;
    BAR2;
    RDB8(0, 1); RDA8(0, 1, 0);
    if (s2) STA8(0, 0, t2);
    SYNCA; MM168(0); ENDP; BAR2;
    RDA8(0, 1, 1);
    if (s2) STB8(0, 0, t2);
    SYNCA; MM168(1); ENDP;
    if (lastI) { WAITH; } else { WAITN; }
    BAR2;
    RDB8(1, 0); RDA8(1, 0, 0);
    if (s2) STA8(0, 1, t2);
    SYNCA; MM168(0); ENDP; BAR2;
    RDA8(1, 0, 1);
    if (s2) STB8(0, 1, t2);
    SYNCA; MM168(1); ENDP;
    if (lastI) { asm volatile("s_waitcnt vmcnt(0)" ::: "memory"); } else { WAITN; }
    BAR2;
    RDB8(1, 1); RDA8(1, 1, 0);
    if (s3) STA8(1, 0, t3);
    SYNCA; MM168(0); ENDP; BAR2;
    RDA8(1, 1, 1);
    if (s3) STB8(1, 0, t3);
    SYNCA; MM168(1); ENDP;
    if (!lastI) { WAITN; }
    BAR2;
  }
#undef STA8
#undef STB8
#undef RDA8
#undef RDB8
#undef MM168
#undef SYNCA
#undef ENDP
#undef BAR2
#undef WAITN
#undef WAITH

  const size_t mn = (size_t)gridDim.y * BM_ * (size_t)N;
#pragma unroll
  for (int m = 0; m < 2 * MM; m++) {
    size_t row = bm + wm * (BM_ / 2) + m * 16 + 4 * g;
#pragma unroll
    for (int n = 0; n < 4; n++) {
      size_t col = bn + wn * 64 + n * 16 + lq;
#pragma unroll
      for (int r = 0; r < 4; r++) {
        size_t idx = (row + r) * (size_t)N + col;
        if constexpr (MODE == 0) {
          ((u16*)Cout)[idx] = f2bf(acc[m][n][r]);
        } else if constexpr (MODE == 1) {
          ((float*)Cout)[idx] = ((const float*)Extra)[idx] + acc[m][n][r];
        } else if constexpr (MODE == 2) {
          float a = bf2f(((const u16*)Extra)[idx]);
          float sil = a / (1.f + exp2f(-1.4426950408889634f * a));
          ((u16*)Cout)[idx] = f2bf(sil * acc[m][n][r]);
        } else {
          ((float*)Cout)[(size_t)kz * mn + idx] = acc[m][n][r];
        }
      }
    }
  }
}

// ----------------- causal flash attention (LDS-staged) --------------
// grid (T/128, B*H); 4 waves/block; wave owns 32 q-rows (2 rg of 16).
__global__ __launch_bounds__(256, 2) void attn_kernel(const u16* __restrict__ QKV,
                                                      const u16* __restrict__ VT,
                                                      u16* __restrict__ CTX) {
  __shared__ u16 Ks[64 * 128];
  __shared__ u16 Vs[128 * 64];
  __shared__ u16 P_all[4][32 * 72];
  const int t = threadIdx.x;
  const int w = t >> 6, l = t & 63, g = l >> 4, lq = l & 15;
  u16* P = P_all[w];
  const int q0blk = blockIdx.x * 128;
  const int q0w = q0blk + w * 32;
  const int bh = blockIdx.y, b = bh >> 4, h = bh & 15;
  const u16* qp = QKV + (size_t)b * T_SEQ * QS + h * D_HEAD;
  const u16* kp = QKV + (size_t)b * T_SEQ * QS + E_DIM + h * D_HEAD;
  const u16* vp = VT + ((size_t)b * E_DIM + h * D_HEAD) * T_SEQ;

  short8 qf[2][4];
#pragma unroll
  for (int rg = 0; rg < 2; rg++)
#pragma unroll
    for (int ks = 0; ks < 4; ks++)
      qf[rg][ks] =
          *(const short8*)(qp + (size_t)(q0w + rg * 16 + lq) * QS + ks * 32 + g * 8);

  f32x4 acc[2][8] = {};
  float m2[2][4], ls[2][4];
#pragma unroll
  for (int rg = 0; rg < 2; rg++)
#pragma unroll
    for (int r = 0; r < 4; r++) { m2[rg][r] = -1e30f; ls[rg][r] = 0.f; }
  const float sc = 0.08838834764831845f * 1.4426950408889634f;

  const int kRow0 = 16 * w + (l >> 4);
  const int kChunk = l & 15;
  const int vRow0 = 32 * w + (l >> 3);
  const int vChunk = l & 7;

  for (int kv0 = 0; kv0 < q0blk + 128; kv0 += 64) {
#pragma unroll
    for (int j = 0; j < 4; j++) {
      int R = kRow0 + 4 * j;
      async16(Ks + (16 * w + 4 * j) * 128,
              kp + (size_t)(kv0 + R) * QS + ((kChunk ^ (R & 7)) << 3));
    }
#pragma unroll
    for (int j = 0; j < 4; j++) {
      int D = vRow0 + 8 * j;
      async16(Vs + (32 * w + 8 * j) * 64,
              vp + (size_t)D * T_SEQ + kv0 + ((vChunk ^ (D & 7)) << 3));
    }
    __syncthreads();

#pragma unroll
    for (int rg = 0; rg < 2; rg++) {
      const int rb = q0w + rg * 16;
      if (kv0 > rb + 15) continue;
      f32x4 s[4];
      __builtin_amdgcn_s_setprio(1);
#pragma unroll
      for (int ct = 0; ct < 4; ct++) {
        s[ct] = f32x4{0.f, 0.f, 0.f, 0.f};
#pragma unroll
        for (int ks = 0; ks < 4; ks++) {
          short8 kf = *(const short8*)(Ks + (ct * 16 + lq) * 128 +
                                       (((ks * 4 + g) ^ (lq & 7)) << 3));
          s[ct] = __builtin_amdgcn_mfma_f32_16x16x32_bf16(qf[rg][ks], kf, s[ct], 0, 0, 0);
        }
      }
      __builtin_amdgcn_s_setprio(0);
      float sv[4][4];
#pragma unroll
      for (int ct = 0; ct < 4; ct++)
#pragma unroll
        for (int r = 0; r < 4; r++) sv[ct][r] = s[ct][r] * sc;
      if (kv0 + 64 > rb) {
#pragma unroll
        for (int ct = 0; ct < 4; ct++)
#pragma unroll
          for (int r = 0; r < 4; r++)
            if (kv0 + ct * 16 + lq > rb + 4 * g + r) sv[ct][r] = -1e30f;
      }
      float mx[4];
#pragma unroll
      for (int r = 0; r < 4; r++)
        mx[r] = fmaxf(fmaxf(sv[0][r], sv[1][r]), fmaxf(sv[2][r], sv[3][r]));
#pragma unroll
      for (int off = 1; off < 16; off <<= 1)
#pragma unroll
        for (int r = 0; r < 4; r++) mx[r] = fmaxf(mx[r], __shfl_xor(mx[r], off));
#pragma unroll
      for (int r = 0; r < 4; r++) {
        float mn = fmaxf(m2[rg][r], mx[r]);
        float sca = exp2f(m2[rg][r] - mn);
        m2[rg][r] = mn;
        float sum = 0.f;
#pragma unroll
        for (int ct = 0; ct < 4; ct++) {
          float pv = exp2f(sv[ct][r] - mn);
          sum += pv;
          P[(rg * 16 + 4 * g + r) * 72 + ct * 16 + lq] = f2bf(pv);
        }
        ls[rg][r] = ls[rg][r] * sca + sum;
#pragma unroll
        for (int n = 0; n < 8; n++) acc[rg][n][r] *= sca;
      }
      short8 pa[2];
#pragma unroll
      for (int ks2 = 0; ks2 < 2; ks2++)
        pa[ks2] = *(const short8*)(P + (rg * 16 + lq) * 72 + ks2 * 32 + g * 8);
      __builtin_amdgcn_s_setprio(1);
#pragma unroll
      for (int n = 0; n < 8; n++)
#pragma unroll
        for (int ks2 = 0; ks2 < 2; ks2++) {
          short8 vf = *(const short8*)(Vs + (n * 16 + lq) * 64 +
                                       (((ks2 * 4 + g) ^ (lq & 7)) << 3));
          acc[rg][n] = __builtin_amdgcn_mfma_f32_16x16x32_bf16(pa[ks2], vf, acc[rg][n], 0, 0, 0);
        }
      __builtin_amdgcn_s_setprio(0);
    }
    __syncthreads();
  }

#pragma unroll
  for (int rg = 0; rg < 2; rg++) {
#pragma unroll
    for (int off = 1; off < 16; off <<= 1)
#pragma unroll
      for (int r = 0; r < 4; r++) ls[rg][r] += __shfl_xor(ls[rg][r], off);
  }
  u16* cp = CTX + ((size_t)b * T_SEQ + q0w) * E_DIM + h * D_HEAD;
#pragma unroll
  for (int rg = 0; rg < 2; rg++) {
    float inv[4];
#pragma unroll
    for (int r = 0; r < 4; r++) inv[r] = 1.f / ls[rg][r];
#pragma unroll
    for (int n = 0; n < 8; n++)
#pragma unroll
      for (int r = 0; r < 4; r++)
        cp[(size_t)(rg * 16 + 4 * g + r) * E_DIM + n * 16 + lq] =
            f2bf(acc[rg][n][r] * inv[r]);
  }
}

extern "C" void kernel_launch(void* const* d_in, const int* in_sizes, int n_in,
                              void* d_out, int out_size, void* d_ws, size_t ws_size,
                              hipStream_t stream) {
  (void)in_sizes; (void)n_in; (void)out_size; (void)ws_size;
  const float* x  = (const float*)d_in[0];
  const float* g1 = (const float*)d_in[1];
  const float* b1 = (const float*)d_in[2];
  const float* wq = (const float*)d_in[3];
  const float* wk = (const float*)d_in[4];
  const float* wv = (const float*)d_in[5];
  const float* wo = (const float*)d_in[6];
  const float* g2 = (const float*)d_in[7];
  const float* b2 = (const float*)d_in[8];
  const float* w1 = (const float*)d_in[9];
  const float* w2 = (const float*)d_in[10];
  const float* w3 = (const float*)d_in[11];
  float* out = (float*)d_out;

  const size_t EE2 = (size_t)E_DIM * E_DIM * 2;
  const size_t EF2 = (size_t)E_DIM * FFN_DIM * 2;
  const size_t ME2 = (size_t)M_ROWS * E_DIM * 2;
  char* p = (char*)d_ws;
  u16* wqkvT = (u16*)p; p += 3 * EE2;
  u16* woT = (u16*)p; p += EE2;
  u16* w1T = (u16*)p; p += EF2;
  u16* w2T = (u16*)p; p += EF2;
  u16* w3T = (u16*)p; p += EF2;
  u16* Hb  = (u16*)p; p += ME2;
  u16* QKVb = (u16*)p; p += (size_t)M_ROWS * QS * 2;
  u16* VTb = (u16*)p; p += ME2;
  u16* CTXb = (u16*)p; p += ME2;
  u16* U1b = QKVb;              // u1/gated reuses QKVb+VTb (64MB)
  float* Pk = (float*)wqkvT;    // w3 split-K partials (64MB, dead wqkvT+woT)

  dim3 blk32(32, 8);
  cvt_t_kernel<<<dim3(E_DIM / 32, E_DIM / 32), blk32, 0, stream>>>(wq, wqkvT, E_DIM, E_DIM);
  cvt_t_kernel<<<dim3(E_DIM / 32, E_DIM / 32), blk32, 0, stream>>>(wk, wqkvT + E_DIM * E_DIM, E_DIM, E_DIM);
  cvt_t_kernel<<<dim3(E_DIM / 32, E_DIM / 32), blk32, 0, stream>>>(wv, wqkvT + 2 * E_DIM * E_DIM, E_DIM, E_DIM);
  cvt_t_kernel<<<dim3(E_DIM / 32, E_DIM / 32), blk32, 0, stream>>>(wo, woT, E_DIM, E_DIM);
  cvt_t_kernel<<<dim3(FFN_DIM / 32, E_DIM / 32), blk32, 0, stream>>>(w1, w1T, E_DIM, FFN_DIM);
  cvt_t_kernel<<<dim3(FFN_DIM / 32, E_DIM / 32), blk32, 0, stream>>>(w2, w2T, E_DIM, FFN_DIM);
  cvt_t_kernel<<<dim3(E_DIM / 32, FFN_DIM / 32), blk32, 0, stream>>>(w3, w3T, FFN_DIM, E_DIM);

  // attention block
  ln_kernel<<<M_ROWS, 256, 0, stream>>>(x, g1, b1, Hb);
  gemm8p<0, 128><<<dim3(QS / 256, M_ROWS / 128), 512, 0, stream>>>(
      Hb, wqkvT, QKVb, nullptr, QS, E_DIM, E_DIM, E_DIM, 6, 16);
  transpose_v_kernel<<<dim3(T_SEQ / 32, E_DIM / 32, 2), blk32, 0, stream>>>(QKVb, VTb);
  attn_kernel<<<dim3(T_SEQ / 128, 2 * N_HEAD), 256, 0, stream>>>(QKVb, VTb, CTXb);
  gemm8p<1, 128><<<dim3(E_DIM / 256, M_ROWS / 128), 512, 0, stream>>>(
      CTXb, woT, out, x, E_DIM, E_DIM, E_DIM, E_DIM, 4, 8);

  // SwiGLU MLP block
  ln_kernel<<<M_ROWS, 256, 0, stream>>>(out, g2, b2, Hb);
  gemm4m<0><<<dim3(FFN_DIM / 256, M_ROWS / 256), 512, 0, stream>>>(
      Hb, w1T, U1b, nullptr, FFN_DIM, E_DIM, E_DIM, E_DIM, 8, 8);
  gemm4m<2><<<dim3(FFN_DIM / 256, M_ROWS / 256), 512, 0, stream>>>(
      Hb, w2T, U1b, U1b, FFN_DIM, E_DIM, E_DIM, E_DIM, 8, 8);
  // w3: split-K=2, grid (8,16,2) = 256 blocks (nchx*nchy*gz = 2*2*2)
  gemm4m<3><<<dim3(E_DIM / 256, M_ROWS / 256, 2), 512, 0, stream>>>(
      U1b, w3T, Pk, nullptr, E_DIM, FFN_DIM / 2, FFN_DIM, FFN_DIM, 4, 8);
  add3_kernel<<<2048, 256, 0, stream>>>(out, Pk);
}

// Round 14
// 893.327 us; speedup vs baseline: 1.2095x; 1.0304x over previous
//
#include <hip/hip_runtime.h>

// Transformer layer, bf16 MFMA compute, fp32 I/O.
// B=2 T=2048 E=2048 H=16 DH=128 FFN=8192. Needs ~256MB workspace.

#define T_SEQ 2048
#define E_DIM 2048
#define N_HEAD 16
#define D_HEAD 128
#define FFN_DIM 8192
#define M_ROWS 4096  // B*T
#define QS (3 * E_DIM)  // fused QKV row stride

typedef unsigned short u16;
typedef short short8 __attribute__((ext_vector_type(8)));
typedef float f32x4 __attribute__((ext_vector_type(4)));

#define DEV __device__ __forceinline__

DEV u16 f2bf(float f) {
  unsigned u = __float_as_uint(f);
  u += 0x7fffu + ((u >> 16) & 1u);
  return (u16)(u >> 16);
}
DEV float bf2f(u16 h) { return __uint_as_float(((unsigned)h) << 16); }

DEV void async16(void* lds, const void* g) {
  __builtin_amdgcn_global_load_lds((const __attribute__((address_space(1))) void*)g,
                                   (__attribute__((address_space(3))) void*)lds, 16, 0, 0);
}

// ---------------- LayerNorm: fp32 [rows][E] -> bf16 -----------------
__global__ __launch_bounds__(256) void ln_kernel(const float* __restrict__ x,
                                                 const float* __restrict__ gw,
                                                 const float* __restrict__ bw,
                                                 u16* __restrict__ out) {
  int row = blockIdx.x;
  int t = threadIdx.x;
  const float4* xr = (const float4*)(x + (size_t)row * E_DIM);
  float4 a = xr[t], c = xr[t + 256];
  float s = a.x + a.y + a.z + a.w + c.x + c.y + c.z + c.w;
  float q = a.x * a.x + a.y * a.y + a.z * a.z + a.w * a.w +
            c.x * c.x + c.y * c.y + c.z * c.z + c.w * c.w;
  for (int off = 32; off > 0; off >>= 1) {
    s += __shfl_down(s, off);
    q += __shfl_down(q, off);
  }
  __shared__ float red[8];
  if ((t & 63) == 0) { red[(t >> 6) * 2] = s; red[(t >> 6) * 2 + 1] = q; }
  __syncthreads();
  s = red[0] + red[2] + red[4] + red[6];
  q = red[1] + red[3] + red[5] + red[7];
  float mu = s * (1.f / E_DIM);
  float rs = rsqrtf(q * (1.f / E_DIM) - mu * mu + 1e-5f);
  const float4* g4 = (const float4*)gw;
  const float4* b4 = (const float4*)bw;
  float4 g0 = g4[t], g1v = g4[t + 256], e0 = b4[t], e1 = b4[t + 256];
  ushort4 o0, o1;
  o0.x = f2bf((a.x - mu) * rs * g0.x + e0.x);
  o0.y = f2bf((a.y - mu) * rs * g0.y + e0.y);
  o0.z = f2bf((a.z - mu) * rs * g0.z + e0.z);
  o0.w = f2bf((a.w - mu) * rs * g0.w + e0.w);
  o1.x = f2bf((c.x - mu) * rs * g1v.x + e1.x);
  o1.y = f2bf((c.y - mu) * rs * g1v.y + e1.y);
  o1.z = f2bf((c.z - mu) * rs * g1v.z + e1.z);
  o1.w = f2bf((c.w - mu) * rs * g1v.w + e1.w);
  ((ushort4*)(out + (size_t)row * E_DIM))[t] = o0;
  ((ushort4*)(out + (size_t)row * E_DIM))[t + 256] = o1;
}

// ------- convert+transpose: fp32 W[K][N] -> bf16 WT[N][K] -----------
__global__ __launch_bounds__(256) void cvt_t_kernel(const float* __restrict__ W,
                                                    u16* __restrict__ WT,
                                                    int Kd, int Nd) {
  __shared__ float tile[32][33];
  int tx = threadIdx.x, ty = threadIdx.y;
  int n0 = blockIdx.x * 32, k0 = blockIdx.y * 32;
#pragma unroll
  for (int i = 0; i < 4; i++)
    tile[ty + i * 8][tx] = W[(size_t)(k0 + ty + i * 8) * Nd + n0 + tx];
  __syncthreads();
#pragma unroll
  for (int i = 0; i < 4; i++)
    WT[(size_t)(n0 + ty + i * 8) * Kd + k0 + tx] = f2bf(tile[tx][ty + i * 8]);
}

// -- transpose V from fused QKV: bf16 [B*T][QS] col 4096+ -> [B][E][T]
__global__ __launch_bounds__(256) void transpose_v_kernel(const u16* __restrict__ qkv,
                                                          u16* __restrict__ vt) {
  __shared__ u16 tile[32][33];
  int tx = threadIdx.x, ty = threadIdx.y;
  int b = blockIdx.z;
  int t0 = blockIdx.x * 32, e0 = blockIdx.y * 32;
#pragma unroll
  for (int i = 0; i < 4; i++)
    tile[ty + i * 8][tx] =
        qkv[(size_t)(b * T_SEQ + t0 + ty + i * 8) * QS + 2 * E_DIM + e0 + tx];
  __syncthreads();
#pragma unroll
  for (int i = 0; i < 4; i++)
    vt[((size_t)b * E_DIM + e0 + ty + i * 8) * T_SEQ + t0 + tx] = tile[tx][ty + i * 8];
}

// ------ add3: out += P0 + P1 (bf16 split-K partials, 96MB traffic) --
__global__ __launch_bounds__(256) void add3_kernel(float* __restrict__ out,
                                                   const u16* __restrict__ pk) {
  const size_t MN = (size_t)M_ROWS * E_DIM;
  size_t base = ((size_t)blockIdx.x * 256 + threadIdx.x) * 8;
  short8 a = *(const short8*)(pk + base);
  short8 b = *(const short8*)(pk + MN + base);
  float4 o0 = *(float4*)(out + base), o1 = *(float4*)(out + base + 4);
  o0.x += bf2f((u16)a[0]) + bf2f((u16)b[0]);
  o0.y += bf2f((u16)a[1]) + bf2f((u16)b[1]);
  o0.z += bf2f((u16)a[2]) + bf2f((u16)b[2]);
  o0.w += bf2f((u16)a[3]) + bf2f((u16)b[3]);
  o1.x += bf2f((u16)a[4]) + bf2f((u16)b[4]);
  o1.y += bf2f((u16)a[5]) + bf2f((u16)b[5]);
  o1.z += bf2f((u16)a[6]) + bf2f((u16)b[6]);
  o1.w += bf2f((u16)a[7]) + bf2f((u16)b[7]);
  *(float4*)(out + base) = o0;
  *(float4*)(out + base + 4) = o1;
}

// ======= GEMM BM_x256xBK64, 8-phase schedule, paired-row LDS ========
// Round-10 structure (best verified: 910us).  2-D XCD chunking:
// bid -> xcd=bid&7, slot=bid>>3; bx=(cid%nchx)*CX+slot%CX,
// by=(cid/nchx)*CY+slot/CX; kz = xcd/(nchx*nchy) for split-K
// (nchx*nchy*gridDim.z must == 8).  A/B strides lda/ldb; K loop
// covers [kz*K, kz*K+K).
// MODE 0: bf16 C.  MODE 1: Cout(f32)=Extra(f32)+acc.
// MODE 2: Cout(bf16)=silu(Extra bf16)*acc.
// MODE 3: bf16 split-K partial at Cout + kz*M*N.
template <int MODE, int BM_>
__global__ __launch_bounds__(512, 1) void gemm8p(const u16* __restrict__ A,
                                                 const u16* __restrict__ BT,
                                                 void* __restrict__ Cout,
                                                 const void* __restrict__ Extra,
                                                 int N, int K, int lda, int ldb,
                                                 int CX, int CY) {
  constexpr int MM = BM_ / 64;
  constexpr int AUNIT = BM_ * 32;
  __shared__ u16 Abuf[4 * AUNIT];
  __shared__ u16 Bbuf[4 * 8192];
  const int t = threadIdx.x;
  const int w = t >> 6, l = t & 63, g = l >> 4, lq = l & 15;
  const int wm = w >> 2, wn = w & 3;

  const int bid = (blockIdx.z * gridDim.y + blockIdx.y) * gridDim.x + blockIdx.x;
  const int xcd = bid & 7, slot = bid >> 3;
  const int nchx = gridDim.x / CX;
  const int nchy = gridDim.y / CY;
  const int cpz = nchx * nchy;
  const int kz = xcd / cpz;
  const int cid = xcd % cpz;
  const int bx = (cid % nchx) * CX + (slot % CX);
  const int by = (cid / nchx) * CY + (slot / CX);
  const size_t bm = (size_t)by * BM_, bn = (size_t)bx * 256;
  const size_t koff = (size_t)kz * K;

  // staging lane constants (paired-row): lane l covers
  // row = 2*(l>>3) + (l&1), kchunk = ((l>>1)&3) ^ ((l>>3)&3)
  const int srcrow = ((l >> 3) << 1) | (l & 1);
  const int csrc = ((((l >> 1) & 3) ^ ((l >> 3) & 3)) << 3);
  const u16* aSrc = A + (bm + w * 16 + srcrow) * (size_t)lda + koff + csrc;
  const u16* bSrc = BT + (bn + w * 16 + srcrow) * (size_t)ldb + koff + csrc;
  // read lane constant: ch7 = (lq&1) + 2*(g ^ ((lq>>1)&3))
  const int rdoff = (((lq & 1) + 2 * (g ^ ((lq >> 1) & 3))) << 3);

#define STA8(DB, KS, TILE)                                                    \
  {                                                                           \
    u16* Ad = Abuf + (DB) * (2 * AUNIT) + (KS)*AUNIT + w * 512;               \
    const u16* as_ = aSrc + (size_t)(TILE)*64 + (KS)*32;                      \
    async16(Ad, as_);                                                         \
    if constexpr (BM_ == 256) async16(Ad + 4096, as_ + (size_t)128 * lda);    \
  }
#define STB8(DB, KS, TILE)                                                    \
  {                                                                           \
    u16* Bd = Bbuf + (DB)*16384 + (KS)*8192 + w * 512;                        \
    const u16* bs_ = bSrc + (size_t)(TILE)*64 + (KS)*32;                      \
    async16(Bd, bs_);                                                         \
    async16(Bd + 4096, bs_ + (size_t)128 * ldb);                              \
  }
#define RDA8(DB, KS, MH)                                                      \
  _Pragma("unroll") for (int mm = 0; mm < MM; ++mm)                           \
      af[mm] = *(const short8*)(Abuf + (DB) * (2 * AUNIT) + (KS)*AUNIT +      \
                                (wm * (BM_ / 4) + (MH) * (BM_ / 8) + mm * 8 + \
                                 (lq >> 1)) * 64 + rdoff);
#define RDB8(DB, KS)                                                          \
  _Pragma("unroll") for (int nn = 0; nn < 4; ++nn)                            \
      bf[nn] = *(const short8*)(Bbuf + (DB)*16384 + (KS)*8192 +               \
                                (wn * 32 + nn * 8 + (lq >> 1)) * 64 + rdoff);
#define MM168(MH)                                                             \
  _Pragma("unroll") for (int mm = 0; mm < MM; ++mm)                           \
      _Pragma("unroll") for (int nn = 0; nn < 4; ++nn)                        \
          acc[(MH)*MM + mm][nn] = __builtin_amdgcn_mfma_f32_16x16x32_bf16(    \
              af[mm], bf[nn], acc[(MH)*MM + mm][nn], 0, 0, 0);
#define SYNCA                                                                 \
  __builtin_amdgcn_s_barrier();                                               \
  asm volatile("s_waitcnt lgkmcnt(0)" ::: "memory");                          \
  __builtin_amdgcn_sched_barrier(0);                                          \
  __builtin_amdgcn_s_setprio(1);
#define ENDP __builtin_amdgcn_s_setprio(0);
#define BAR2 __builtin_amdgcn_s_barrier();
#define WAITN                                                                 \
  if constexpr (BM_ == 256) asm volatile("s_waitcnt vmcnt(8)" ::: "memory");  \
  else                      asm volatile("s_waitcnt vmcnt(6)" ::: "memory");
#define WAITH                                                                 \
  if constexpr (BM_ == 256) asm volatile("s_waitcnt vmcnt(4)" ::: "memory");  \
  else                      asm volatile("s_waitcnt vmcnt(3)" ::: "memory");

  const int NT = K >> 6, NI = NT >> 1;
  f32x4 acc[2 * MM][4] = {};
  short8 af[MM > 4 ? MM : 4], bf[4];

  // prologue: tile0 both K-halves + tile1 K-half0
  STA8(0, 0, 0); STB8(0, 0, 0);
  STA8(0, 1, 0); STB8(0, 1, 0);
  STA8(1, 0, 1); STB8(1, 0, 1);
  WAITN;  // completes t0-ks0; rest stays in flight
  BAR2;

  for (int j = 0; j < NI; ++j) {
    const int t1 = 2 * j + 1, t2 = 2 * j + 2, t3 = 2 * j + 3;
    const bool s2 = t2 < NT, s3 = t3 < NT, lastI = (j + 1 == NI);
    // p0: db0 ks0 mh0
    RDB8(0, 0); RDA8(0, 0, 0);
    STA8(1, 1, t1);
    SYNCA; MM168(0); ENDP; BAR2;
    // p1: db0 ks0 mh1
    RDA8(0, 0, 1);
    STB8(1, 1, t1);
    SYNCA; MM168(1); ENDP;
    WAITN;
    BAR2;
    // p2: db0 ks1 mh0
    RDB8(0, 1); RDA8(0, 1, 0);
    if (s2) STA8(0, 0, t2);
    SYNCA; MM168(0); ENDP; BAR2;
    // p3: db0 ks1 mh1
    RDA8(0, 1, 1);
    if (s2) STB8(0, 0, t2);
    SYNCA; MM168(1); ENDP;
    if (lastI) { WAITH; } else { WAITN; }
    BAR2;
    // p4: db1 ks0 mh0
    RDB8(1, 0); RDA8(1, 0, 0);
    if (s2) STA8(0, 1, t2);
    SYNCA; MM168(0); ENDP; BAR2;
    // p5: db1 ks0 mh1
    RDA8(1, 0, 1);
    if (s2) STB8(0, 1, t2);
    SYNCA; MM168(1); ENDP;
    if (lastI) { asm volatile("s_waitcnt vmcnt(0)" ::: "memory"); } else { WAITN; }
    BAR2;
    // p6: db1 ks1 mh0
    RDB8(1, 1); RDA8(1, 1, 0);
    if (s3) STA8(1, 0, t3);
    SYNCA; MM168(0); ENDP; BAR2;
    // p7: db1 ks1 mh1
    RDA8(1, 1, 1);
    if (s3) STB8(1, 0, t3);
    SYNCA; MM168(1); ENDP;
    if (!lastI) { WAITN; }
    BAR2;
  }
#undef STA8
#undef STB8
#undef RDA8
#undef RDB8
#undef MM168
#undef SYNCA
#undef ENDP
#undef BAR2
#undef WAITN
#undef WAITH

  const size_t mn = (size_t)gridDim.y * BM_ * (size_t)N;
#pragma unroll
  for (int m = 0; m < 2 * MM; m++) {
    size_t row = bm + wm * (BM_ / 2) + m * 16 + 4 * g;
#pragma unroll
    for (int n = 0; n < 4; n++) {
      size_t col = bn + wn * 64 + n * 16 + lq;
#pragma unroll
      for (int r = 0; r < 4; r++) {
        size_t idx = (row + r) * (size_t)N + col;
        if constexpr (MODE == 0) {
          ((u16*)Cout)[idx] = f2bf(acc[m][n][r]);
        } else if constexpr (MODE == 1) {
          ((float*)Cout)[idx] = ((const float*)Extra)[idx] + acc[m][n][r];
        } else if constexpr (MODE == 2) {
          float a = bf2f(((const u16*)Extra)[idx]);
          float sil = a / (1.f + exp2f(-1.4426950408889634f * a));
          ((u16*)Cout)[idx] = f2bf(sil * acc[m][n][r]);
        } else {
          ((u16*)Cout)[(size_t)kz * mn + idx] = f2bf(acc[m][n][r]);
        }
      }
    }
  }
}

// ----------------- causal flash attention (LDS-staged) --------------
// grid (T/128, B*H); 4 waves/block; wave owns 32 q-rows (2 rg of 16).
__global__ __launch_bounds__(256, 2) void attn_kernel(const u16* __restrict__ QKV,
                                                      const u16* __restrict__ VT,
                                                      u16* __restrict__ CTX) {
  __shared__ u16 Ks[64 * 128];
  __shared__ u16 Vs[128 * 64];
  __shared__ u16 P_all[4][32 * 72];
  const int t = threadIdx.x;
  const int w = t >> 6, l = t & 63, g = l >> 4, lq = l & 15;
  u16* P = P_all[w];
  const int q0blk = blockIdx.x * 128;
  const int q0w = q0blk + w * 32;
  const int bh = blockIdx.y, b = bh >> 4, h = bh & 15;
  const u16* qp = QKV + (size_t)b * T_SEQ * QS + h * D_HEAD;
  const u16* kp = QKV + (size_t)b * T_SEQ * QS + E_DIM + h * D_HEAD;
  const u16* vp = VT + ((size_t)b * E_DIM + h * D_HEAD) * T_SEQ;

  short8 qf[2][4];
#pragma unroll
  for (int rg = 0; rg < 2; rg++)
#pragma unroll
    for (int ks = 0; ks < 4; ks++)
      qf[rg][ks] =
          *(const short8*)(qp + (size_t)(q0w + rg * 16 + lq) * QS + ks * 32 + g * 8);

  f32x4 acc[2][8] = {};
  float m2[2][4], ls[2][4];
#pragma unroll
  for (int rg = 0; rg < 2; rg++)
#pragma unroll
    for (int r = 0; r < 4; r++) { m2[rg][r] = -1e30f; ls[rg][r] = 0.f; }
  const float sc = 0.08838834764831845f * 1.4426950408889634f;

  const int kRow0 = 16 * w + (l >> 4);
  const int kChunk = l & 15;
  const int vRow0 = 32 * w + (l >> 3);
  const int vChunk = l & 7;

  for (int kv0 = 0; kv0 < q0blk + 128; kv0 += 64) {
#pragma unroll
    for (int j = 0; j < 4; j++) {
      int R = kRow0 + 4 * j;
      async16(Ks + (16 * w + 4 * j) * 128,
              kp + (size_t)(kv0 + R) * QS + ((kChunk ^ (R & 7)) << 3));
    }
#pragma unroll
    for (int j = 0; j < 4; j++) {
      int D = vRow0 + 8 * j;
      async16(Vs + (32 * w + 8 * j) * 64,
              vp + (size_t)D * T_SEQ + kv0 + ((vChunk ^ (D & 7)) << 3));
    }
    __syncthreads();

#pragma unroll
    for (int rg = 0; rg < 2; rg++) {
      const int rb = q0w + rg * 16;
      if (kv0 > rb + 15) continue;
      f32x4 s[4];
      __builtin_amdgcn_s_setprio(1);
#pragma unroll
      for (int ct = 0; ct < 4; ct++) {
        s[ct] = f32x4{0.f, 0.f, 0.f, 0.f};
#pragma unroll
        for (int ks = 0; ks < 4; ks++) {
          short8 kf = *(const short8*)(Ks + (ct * 16 + lq) * 128 +
                                       (((ks * 4 + g) ^ (lq & 7)) << 3));
          s[ct] = __builtin_amdgcn_mfma_f32_16x16x32_bf16(qf[rg][ks], kf, s[ct], 0, 0, 0);
        }
      }
      __builtin_amdgcn_s_setprio(0);
      float sv[4][4];
#pragma unroll
      for (int ct = 0; ct < 4; ct++)
#pragma unroll
        for (int r = 0; r < 4; r++) sv[ct][r] = s[ct][r] * sc;
      if (kv0 + 64 > rb) {
#pragma unroll
        for (int ct = 0; ct < 4; ct++)
#pragma unroll
          for (int r = 0; r < 4; r++)
            if (kv0 + ct * 16 + lq > rb + 4 * g + r) sv[ct][r] = -1e30f;
      }
      float mx[4];
#pragma unroll
      for (int r = 0; r < 4; r++)
        mx[r] = fmaxf(fmaxf(sv[0][r], sv[1][r]), fmaxf(sv[2][r], sv[3][r]));
#pragma unroll
      for (int off = 1; off < 16; off <<= 1)
#pragma unroll
        for (int r = 0; r < 4; r++) mx[r] = fmaxf(mx[r], __shfl_xor(mx[r], off));
#pragma unroll
      for (int r = 0; r < 4; r++) {
        float mn = fmaxf(m2[rg][r], mx[r]);
        float sca = exp2f(m2[rg][r] - mn);
        m2[rg][r] = mn;
        float sum = 0.f;
#pragma unroll
        for (int ct = 0; ct < 4; ct++) {
          float pv = exp2f(sv[ct][r] - mn);
          sum += pv;
          P[(rg * 16 + 4 * g + r) * 72 + ct * 16 + lq] = f2bf(pv);
        }
        ls[rg][r] = ls[rg][r] * sca + sum;
#pragma unroll
        for (int n = 0; n < 8; n++) acc[rg][n][r] *= sca;
      }
      short8 pa[2];
#pragma unroll
      for (int ks2 = 0; ks2 < 2; ks2++)
        pa[ks2] = *(const short8*)(P + (rg * 16 + lq) * 72 + ks2 * 32 + g * 8);
      __builtin_amdgcn_s_setprio(1);
#pragma unroll
      for (int n = 0; n < 8; n++)
#pragma unroll
        for (int ks2 = 0; ks2 < 2; ks2++) {
          short8 vf = *(const short8*)(Vs + (n * 16 + lq) * 64 +
                                       (((ks2 * 4 + g) ^ (lq & 7)) << 3));
          acc[rg][n] = __builtin_amdgcn_mfma_f32_16x16x32_bf16(pa[ks2], vf, acc[rg][n], 0, 0, 0);
        }
      __builtin_amdgcn_s_setprio(0);
    }
    __syncthreads();
  }

#pragma unroll
  for (int rg = 0; rg < 2; rg++) {
#pragma unroll
    for (int off = 1; off < 16; off <<= 1)
#pragma unroll
      for (int r = 0; r < 4; r++) ls[rg][r] += __shfl_xor(ls[rg][r], off);
  }
  u16* cp = CTX + ((size_t)b * T_SEQ + q0w) * E_DIM + h * D_HEAD;
#pragma unroll
  for (int rg = 0; rg < 2; rg++) {
    float inv[4];
#pragma unroll
    for (int r = 0; r < 4; r++) inv[r] = 1.f / ls[rg][r];
#pragma unroll
    for (int n = 0; n < 8; n++)
#pragma unroll
      for (int r = 0; r < 4; r++)
        cp[(size_t)(rg * 16 + 4 * g + r) * E_DIM + n * 16 + lq] =
            f2bf(acc[rg][n][r] * inv[r]);
  }
}

extern "C" void kernel_launch(void* const* d_in, const int* in_sizes, int n_in,
                              void* d_out, int out_size, void* d_ws, size_t ws_size,
                              hipStream_t stream) {
  (void)in_sizes; (void)n_in; (void)out_size; (void)ws_size;
  const float* x  = (const float*)d_in[0];
  const float* g1 = (const float*)d_in[1];
  const float* b1 = (const float*)d_in[2];
  const float* wq = (const float*)d_in[3];
  const float* wk = (const float*)d_in[4];
  const float* wv = (const float*)d_in[5];
  const float* wo = (const float*)d_in[6];
  const float* g2 = (const float*)d_in[7];
  const float* b2 = (const float*)d_in[8];
  const float* w1 = (const float*)d_in[9];
  const float* w2 = (const float*)d_in[10];
  const float* w3 = (const float*)d_in[11];
  float* out = (float*)d_out;

  const size_t EE2 = (size_t)E_DIM * E_DIM * 2;
  const size_t EF2 = (size_t)E_DIM * FFN_DIM * 2;
  const size_t ME2 = (size_t)M_ROWS * E_DIM * 2;
  char* p = (char*)d_ws;
  u16* wqkvT = (u16*)p; p += 3 * EE2;
  u16* woT = (u16*)p; p += EE2;
  u16* w1T = (u16*)p; p += EF2;
  u16* w2T = (u16*)p; p += EF2;
  u16* w3T = (u16*)p; p += EF2;
  u16* Hb  = (u16*)p; p += ME2;
  u16* QKVb = (u16*)p; p += (size_t)M_ROWS * QS * 2;
  u16* VTb = (u16*)p; p += ME2;
  u16* CTXb = (u16*)p; p += ME2;
  u16* U1b = QKVb;            // u1/gated reuses QKVb+VTb (64MB)
  u16* Pk = wqkvT;            // w3 split-K bf16 partials (32MB; wqkvT dead)

  dim3 blk32(32, 8);
  cvt_t_kernel<<<dim3(E_DIM / 32, E_DIM / 32), blk32, 0, stream>>>(wq, wqkvT, E_DIM, E_DIM);
  cvt_t_kernel<<<dim3(E_DIM / 32, E_DIM / 32), blk32, 0, stream>>>(wk, wqkvT + E_DIM * E_DIM, E_DIM, E_DIM);
  cvt_t_kernel<<<dim3(E_DIM / 32, E_DIM / 32), blk32, 0, stream>>>(wv, wqkvT + 2 * E_DIM * E_DIM, E_DIM, E_DIM);
  cvt_t_kernel<<<dim3(E_DIM / 32, E_DIM / 32), blk32, 0, stream>>>(wo, woT, E_DIM, E_DIM);
  cvt_t_kernel<<<dim3(FFN_DIM / 32, E_DIM / 32), blk32, 0, stream>>>(w1, w1T, E_DIM, FFN_DIM);
  cvt_t_kernel<<<dim3(FFN_DIM / 32, E_DIM / 32), blk32, 0, stream>>>(w2, w2T, E_DIM, FFN_DIM);
  cvt_t_kernel<<<dim3(E_DIM / 32, FFN_DIM / 32), blk32, 0, stream>>>(w3, w3T, FFN_DIM, E_DIM);

  // attention block
  ln_kernel<<<M_ROWS, 256, 0, stream>>>(x, g1, b1, Hb);
  // fused QKV GEMM at BM256: grid (24,16) = 384 blocks; chunk 6x8
  // (nchx=4, nchy=2 -> 8 chunks, kz=0)
  gemm8p<0, 256><<<dim3(QS / 256, M_ROWS / 256), 512, 0, stream>>>(
      Hb, wqkvT, QKVb, nullptr, QS, E_DIM, E_DIM, E_DIM, 6, 8);
  transpose_v_kernel<<<dim3(T_SEQ / 32, E_DIM / 32, 2), blk32, 0, stream>>>(QKVb, VTb);
  attn_kernel<<<dim3(T_SEQ / 128, 2 * N_HEAD), 256, 0, stream>>>(QKVb, VTb, CTXb);
  // WO: BM128, grid (8,32); chunk 4x8
  gemm8p<1, 128><<<dim3(E_DIM / 256, M_ROWS / 128), 512, 0, stream>>>(
      CTXb, woT, out, x, E_DIM, E_DIM, E_DIM, E_DIM, 4, 8);

  // SwiGLU MLP block
  ln_kernel<<<M_ROWS, 256, 0, stream>>>(out, g2, b2, Hb);
  // FFN: BM256, grid (32,16); chunk 8x8
  gemm8p<0, 256><<<dim3(FFN_DIM / 256, M_ROWS / 256), 512, 0, stream>>>(
      Hb, w1T, U1b, nullptr, FFN_DIM, E_DIM, E_DIM, E_DIM, 8, 8);
  gemm8p<2, 256><<<dim3(FFN_DIM / 256, M_ROWS / 256), 512, 0, stream>>>(
      Hb, w2T, U1b, U1b, FFN_DIM, E_DIM, E_DIM, E_DIM, 8, 8);
  // w3: BM256 split-K=2: grid (8,16,2) = 256 blocks; chunk 4x8 per kz
  gemm8p<3, 256><<<dim3(E_DIM / 256, M_ROWS / 256, 2), 512, 0, stream>>>(
      U1b, w3T, Pk, nullptr, E_DIM, FFN_DIM / 2, FFN_DIM, FFN_DIM, 4, 8);
  add3_kernel<<<4096, 256, 0, stream>>>(out, Pk);
}

// Round 15
// 892.266 us; speedup vs baseline: 1.2110x; 1.0012x over previous
//
#include <hip/hip_runtime.h>

// Transformer layer, bf16 MFMA compute, fp32 I/O.
// B=2 T=2048 E=2048 H=16 DH=128 FFN=8192. Needs ~256MB workspace.

#define T_SEQ 2048
#define E_DIM 2048
#define N_HEAD 16
#define D_HEAD 128
#define FFN_DIM 8192
#define M_ROWS 4096  // B*T
#define QS (3 * E_DIM)  // fused QKV row stride

typedef unsigned short u16;
typedef short short8 __attribute__((ext_vector_type(8)));
typedef float f32x4 __attribute__((ext_vector_type(4)));

#define DEV __device__ __forceinline__

DEV u16 f2bf(float f) {
  unsigned u = __float_as_uint(f);
  u += 0x7fffu + ((u >> 16) & 1u);
  return (u16)(u >> 16);
}
DEV float bf2f(u16 h) { return __uint_as_float(((unsigned)h) << 16); }

DEV void async16(void* lds, const void* g) {
  __builtin_amdgcn_global_load_lds((const __attribute__((address_space(1))) void*)g,
                                   (__attribute__((address_space(3))) void*)lds, 16, 0, 0);
}

// ---------------- LayerNorm: fp32 [rows][E] -> bf16 -----------------
__global__ __launch_bounds__(256) void ln_kernel(const float* __restrict__ x,
                                                 const float* __restrict__ gw,
                                                 const float* __restrict__ bw,
                                                 u16* __restrict__ out) {
  int row = blockIdx.x;
  int t = threadIdx.x;
  const float4* xr = (const float4*)(x + (size_t)row * E_DIM);
  float4 a = xr[t], c = xr[t + 256];
  float s = a.x + a.y + a.z + a.w + c.x + c.y + c.z + c.w;
  float q = a.x * a.x + a.y * a.y + a.z * a.z + a.w * a.w +
            c.x * c.x + c.y * c.y + c.z * c.z + c.w * c.w;
  for (int off = 32; off > 0; off >>= 1) {
    s += __shfl_down(s, off);
    q += __shfl_down(q, off);
  }
  __shared__ float red[8];
  if ((t & 63) == 0) { red[(t >> 6) * 2] = s; red[(t >> 6) * 2 + 1] = q; }
  __syncthreads();
  s = red[0] + red[2] + red[4] + red[6];
  q = red[1] + red[3] + red[5] + red[7];
  float mu = s * (1.f / E_DIM);
  float rs = rsqrtf(q * (1.f / E_DIM) - mu * mu + 1e-5f);
  const float4* g4 = (const float4*)gw;
  const float4* b4 = (const float4*)bw;
  float4 g0 = g4[t], g1v = g4[t + 256], e0 = b4[t], e1 = b4[t + 256];
  ushort4 o0, o1;
  o0.x = f2bf((a.x - mu) * rs * g0.x + e0.x);
  o0.y = f2bf((a.y - mu) * rs * g0.y + e0.y);
  o0.z = f2bf((a.z - mu) * rs * g0.z + e0.z);
  o0.w = f2bf((a.w - mu) * rs * g0.w + e0.w);
  o1.x = f2bf((c.x - mu) * rs * g1v.x + e1.x);
  o1.y = f2bf((c.y - mu) * rs * g1v.y + e1.y);
  o1.z = f2bf((c.z - mu) * rs * g1v.z + e1.z);
  o1.w = f2bf((c.w - mu) * rs * g1v.w + e1.w);
  ((ushort4*)(out + (size_t)row * E_DIM))[t] = o0;
  ((ushort4*)(out + (size_t)row * E_DIM))[t + 256] = o1;
}

// ------- convert+transpose: fp32 W[K][N] -> bf16 WT[N][K] -----------
__global__ __launch_bounds__(256) void cvt_t_kernel(const float* __restrict__ W,
                                                    u16* __restrict__ WT,
                                                    int Kd, int Nd) {
  __shared__ float tile[32][33];
  int tx = threadIdx.x, ty = threadIdx.y;
  int n0 = blockIdx.x * 32, k0 = blockIdx.y * 32;
#pragma unroll
  for (int i = 0; i < 4; i++)
    tile[ty + i * 8][tx] = W[(size_t)(k0 + ty + i * 8) * Nd + n0 + tx];
  __syncthreads();
#pragma unroll
  for (int i = 0; i < 4; i++)
    WT[(size_t)(n0 + ty + i * 8) * Kd + k0 + tx] = f2bf(tile[tx][ty + i * 8]);
}

// -- transpose V from fused QKV: bf16 [B*T][QS] col 4096+ -> [B][E][T]
__global__ __launch_bounds__(256) void transpose_v_kernel(const u16* __restrict__ qkv,
                                                          u16* __restrict__ vt) {
  __shared__ u16 tile[32][33];
  int tx = threadIdx.x, ty = threadIdx.y;
  int b = blockIdx.z;
  int t0 = blockIdx.x * 32, e0 = blockIdx.y * 32;
#pragma unroll
  for (int i = 0; i < 4; i++)
    tile[ty + i * 8][tx] =
        qkv[(size_t)(b * T_SEQ + t0 + ty + i * 8) * QS + 2 * E_DIM + e0 + tx];
  __syncthreads();
#pragma unroll
  for (int i = 0; i < 4; i++)
    vt[((size_t)b * E_DIM + e0 + ty + i * 8) * T_SEQ + t0 + tx] = tile[tx][ty + i * 8];
}

// ------ add3: out += P0 + P1 (bf16 split-K partials, 96MB traffic) --
__global__ __launch_bounds__(256) void add3_kernel(float* __restrict__ out,
                                                   const u16* __restrict__ pk) {
  const size_t MN = (size_t)M_ROWS * E_DIM;
  size_t base = ((size_t)blockIdx.x * 256 + threadIdx.x) * 8;
  short8 a = *(const short8*)(pk + base);
  short8 b = *(const short8*)(pk + MN + base);
  float4 o0 = *(float4*)(out + base), o1 = *(float4*)(out + base + 4);
  o0.x += bf2f((u16)a[0]) + bf2f((u16)b[0]);
  o0.y += bf2f((u16)a[1]) + bf2f((u16)b[1]);
  o0.z += bf2f((u16)a[2]) + bf2f((u16)b[2]);
  o0.w += bf2f((u16)a[3]) + bf2f((u16)b[3]);
  o1.x += bf2f((u16)a[4]) + bf2f((u16)b[4]);
  o1.y += bf2f((u16)a[5]) + bf2f((u16)b[5]);
  o1.z += bf2f((u16)a[6]) + bf2f((u16)b[6]);
  o1.w += bf2f((u16)a[7]) + bf2f((u16)b[7]);
  *(float4*)(out + base) = o0;
  *(float4*)(out + base + 4) = o1;
}

// ======= GEMM BM_x256xBK64, 8-phase schedule, paired-row LDS ========
// Round-10 structure (proven).  2-D XCD chunking; split-K via kz.
// MODE 0: bf16 C.  MODE 1: Cout(f32)=Extra(f32)+acc.
// MODE 2: Cout(bf16)=silu(Extra bf16)*acc.
// MODE 3: bf16 split-K partial at Cout + kz*M*N.
template <int MODE, int BM_>
__global__ __launch_bounds__(512, 1) void gemm8p(const u16* __restrict__ A,
                                                 const u16* __restrict__ BT,
                                                 void* __restrict__ Cout,
                                                 const void* __restrict__ Extra,
                                                 int N, int K, int lda, int ldb,
                                                 int CX, int CY) {
  constexpr int MM = BM_ / 64;
  constexpr int AUNIT = BM_ * 32;
  __shared__ u16 Abuf[4 * AUNIT];
  __shared__ u16 Bbuf[4 * 8192];
  const int t = threadIdx.x;
  const int w = t >> 6, l = t & 63, g = l >> 4, lq = l & 15;
  const int wm = w >> 2, wn = w & 3;

  const int bid = (blockIdx.z * gridDim.y + blockIdx.y) * gridDim.x + blockIdx.x;
  const int xcd = bid & 7, slot = bid >> 3;
  const int nchx = gridDim.x / CX;
  const int nchy = gridDim.y / CY;
  const int cpz = nchx * nchy;
  const int kz = xcd / cpz;
  const int cid = xcd % cpz;
  const int bx = (cid % nchx) * CX + (slot % CX);
  const int by = (cid / nchx) * CY + (slot / CX);
  const size_t bm = (size_t)by * BM_, bn = (size_t)bx * 256;
  const size_t koff = (size_t)kz * K;

  const int srcrow = ((l >> 3) << 1) | (l & 1);
  const int csrc = ((((l >> 1) & 3) ^ ((l >> 3) & 3)) << 3);
  const u16* aSrc = A + (bm + w * 16 + srcrow) * (size_t)lda + koff + csrc;
  const u16* bSrc = BT + (bn + w * 16 + srcrow) * (size_t)ldb + koff + csrc;
  const int rdoff = (((lq & 1) + 2 * (g ^ ((lq >> 1) & 3))) << 3);

#define STA8(DB, KS, TILE)                                                    \
  {                                                                           \
    u16* Ad = Abuf + (DB) * (2 * AUNIT) + (KS)*AUNIT + w * 512;               \
    const u16* as_ = aSrc + (size_t)(TILE)*64 + (KS)*32;                      \
    async16(Ad, as_);                                                         \
    if constexpr (BM_ == 256) async16(Ad + 4096, as_ + (size_t)128 * lda);    \
  }
#define STB8(DB, KS, TILE)                                                    \
  {                                                                           \
    u16* Bd = Bbuf + (DB)*16384 + (KS)*8192 + w * 512;                        \
    const u16* bs_ = bSrc + (size_t)(TILE)*64 + (KS)*32;                      \
    async16(Bd, bs_);                                                         \
    async16(Bd + 4096, bs_ + (size_t)128 * ldb);                              \
  }
#define RDA8(DB, KS, MH)                                                      \
  _Pragma("unroll") for (int mm = 0; mm < MM; ++mm)                           \
      af[mm] = *(const short8*)(Abuf + (DB) * (2 * AUNIT) + (KS)*AUNIT +      \
                                (wm * (BM_ / 4) + (MH) * (BM_ / 8) + mm * 8 + \
                                 (lq >> 1)) * 64 + rdoff);
#define RDB8(DB, KS)                                                          \
  _Pragma("unroll") for (int nn = 0; nn < 4; ++nn)                            \
      bf[nn] = *(const short8*)(Bbuf + (DB)*16384 + (KS)*8192 +               \
                                (wn * 32 + nn * 8 + (lq >> 1)) * 64 + rdoff);
#define MM168(MH)                                                             \
  _Pragma("unroll") for (int mm = 0; mm < MM; ++mm)                           \
      _Pragma("unroll") for (int nn = 0; nn < 4; ++nn)                        \
          acc[(MH)*MM + mm][nn] = __builtin_amdgcn_mfma_f32_16x16x32_bf16(    \
              af[mm], bf[nn], acc[(MH)*MM + mm][nn], 0, 0, 0);
#define SYNCA                                                                 \
  __builtin_amdgcn_s_barrier();                                               \
  asm volatile("s_waitcnt lgkmcnt(0)" ::: "memory");                          \
  __builtin_amdgcn_sched_barrier(0);                                          \
  __builtin_amdgcn_s_setprio(1);
#define ENDP __builtin_amdgcn_s_setprio(0);
#define BAR2 __builtin_amdgcn_s_barrier();
#define WAITN                                                                 \
  if constexpr (BM_ == 256) asm volatile("s_waitcnt vmcnt(8)" ::: "memory");  \
  else                      asm volatile("s_waitcnt vmcnt(6)" ::: "memory");
#define WAITH                                                                 \
  if constexpr (BM_ == 256) asm volatile("s_waitcnt vmcnt(4)" ::: "memory");  \
  else                      asm volatile("s_waitcnt vmcnt(3)" ::: "memory");

  const int NT = K >> 6, NI = NT >> 1;
  f32x4 acc[2 * MM][4] = {};
  short8 af[MM > 4 ? MM : 4], bf[4];

  STA8(0, 0, 0); STB8(0, 0, 0);
  STA8(0, 1, 0); STB8(0, 1, 0);
  STA8(1, 0, 1); STB8(1, 0, 1);
  WAITN;
  BAR2;

  for (int j = 0; j < NI; ++j) {
    const int t1 = 2 * j + 1, t2 = 2 * j + 2, t3 = 2 * j + 3;
    const bool s2 = t2 < NT, s3 = t3 < NT, lastI = (j + 1 == NI);
    RDB8(0, 0); RDA8(0, 0, 0);
    STA8(1, 1, t1);
    SYNCA; MM168(0); ENDP; BAR2;
    RDA8(0, 0, 1);
    STB8(1, 1, t1);
    SYNCA; MM168(1); ENDP;
    WAITN;
    BAR2;
    RDB8(0, 1); RDA8(0, 1, 0);
    if (s2) STA8(0, 0, t2);
    SYNCA; MM168(0); ENDP; BAR2;
    RDA8(0, 1, 1);
    if (s2) STB8(0, 0, t2);
    SYNCA; MM168(1); ENDP;
    if (lastI) { WAITH; } else { WAITN; }
    BAR2;
    RDB8(1, 0); RDA8(1, 0, 0);
    if (s2) STA8(0, 1, t2);
    SYNCA; MM168(0); ENDP; BAR2;
    RDA8(1, 0, 1);
    if (s2) STB8(0, 1, t2);
    SYNCA; MM168(1); ENDP;
    if (lastI) { asm volatile("s_waitcnt vmcnt(0)" ::: "memory"); } else { WAITN; }
    BAR2;
    RDB8(1, 1); RDA8(1, 1, 0);
    if (s3) STA8(1, 0, t3);
    SYNCA; MM168(0); ENDP; BAR2;
    RDA8(1, 1, 1);
    if (s3) STB8(1, 0, t3);
    SYNCA; MM168(1); ENDP;
    if (!lastI) { WAITN; }
    BAR2;
  }
#undef STA8
#undef STB8
#undef RDA8
#undef RDB8
#undef MM168
#undef SYNCA
#undef ENDP
#undef BAR2
#undef WAITN
#undef WAITH

  const size_t mn = (size_t)gridDim.y * BM_ * (size_t)N;
#pragma unroll
  for (int m = 0; m < 2 * MM; m++) {
    size_t row = bm + wm * (BM_ / 2) + m * 16 + 4 * g;
#pragma unroll
    for (int n = 0; n < 4; n++) {
      size_t col = bn + wn * 64 + n * 16 + lq;
#pragma unroll
      for (int r = 0; r < 4; r++) {
        size_t idx = (row + r) * (size_t)N + col;
        if constexpr (MODE == 0) {
          ((u16*)Cout)[idx] = f2bf(acc[m][n][r]);
        } else if constexpr (MODE == 1) {
          ((float*)Cout)[idx] = ((const float*)Extra)[idx] + acc[m][n][r];
        } else if constexpr (MODE == 2) {
          float a = bf2f(((const u16*)Extra)[idx]);
          float sil = a / (1.f + exp2f(-1.4426950408889634f * a));
          ((u16*)Cout)[idx] = f2bf(sil * acc[m][n][r]);
        } else {
          ((u16*)Cout)[(size_t)kz * mn + idx] = f2bf(acc[m][n][r]);
        }
      }
    }
  }
}

// ==== FUSED SwiGLU FFN GEMM: gated = silu(A@w1T^T) * (A@w2T^T) ======
// 256x128 gated cols per block; B-tile rows 0..127 <- w1T[c0..c0+128),
// rows 128..255 <- w2T[c0..c0+128) (same staging shape as gemm8p-256).
// After K-loop: waves wn>=2 hold u2 for the same (row,col) as waves
// wn<2's u1 -> exchange u2 fp32 through the dead LDS buffers
// (pcol ^= (g&1)<<4 -> 2-way bank alias = free), gate in fp32, store
// bf16.  Grid (FFN/128, M/256) = (64,16) = 1024 blocks = 4/CU.
__global__ __launch_bounds__(512, 1) void gemm_ffn(const u16* __restrict__ A,
                                                   const u16* __restrict__ B1T,
                                                   const u16* __restrict__ B2T,
                                                   u16* __restrict__ Cout,
                                                   int N, int K, int lda, int ldb,
                                                   int CX, int CY) {
  constexpr int AUNIT = 8192;
  __shared__ u16 Abuf[4 * AUNIT];
  __shared__ u16 Bbuf[4 * AUNIT];
  const int t = threadIdx.x;
  const int w = t >> 6, l = t & 63, g = l >> 4, lq = l & 15;
  const int wm = w >> 2, wn = w & 3;

  const int bid = blockIdx.y * gridDim.x + blockIdx.x;
  const int xcd = bid & 7, slot = bid >> 3;
  const int nchx = gridDim.x / CX;
  const int cid = xcd;
  const int bx = (cid % nchx) * CX + (slot % CX);
  const int by = (cid / nchx) * CY + (slot / CX);
  const size_t bm = (size_t)by * 256;
  const size_t c0 = (size_t)bx * 128;

  const int srcrow = ((l >> 3) << 1) | (l & 1);
  const int csrc = ((((l >> 1) & 3) ^ ((l >> 3) & 3)) << 3);
  const u16* aSrc = A + (bm + w * 16 + srcrow) * (size_t)lda + csrc;
  const u16* b1Src = B1T + (c0 + w * 16 + srcrow) * (size_t)ldb + csrc;
  const u16* b2Src = B2T + (c0 + w * 16 + srcrow) * (size_t)ldb + csrc;
  const int rdoff = (((lq & 1) + 2 * (g ^ ((lq >> 1) & 3))) << 3);

#define STA8(DB, KS, TILE)                                                    \
  {                                                                           \
    u16* Ad = Abuf + (DB) * (2 * AUNIT) + (KS)*AUNIT + w * 512;               \
    const u16* as_ = aSrc + (size_t)(TILE)*64 + (KS)*32;                      \
    async16(Ad, as_);                                                         \
    async16(Ad + 4096, as_ + (size_t)128 * lda);                              \
  }
#define STB8(DB, KS, TILE)                                                    \
  {                                                                           \
    u16* Bd = Bbuf + (DB) * (2 * AUNIT) + (KS)*AUNIT + w * 512;               \
    size_t off_ = (size_t)(TILE)*64 + (KS)*32;                                \
    async16(Bd, b1Src + off_);                                                \
    async16(Bd + 4096, b2Src + off_);                                         \
  }
#define RDA8(DB, KS, MH)                                                      \
  _Pragma("unroll") for (int mm = 0; mm < 4; ++mm)                            \
      af[mm] = *(const short8*)(Abuf + (DB) * (2 * AUNIT) + (KS)*AUNIT +      \
                                (wm * 64 + (MH)*32 + mm * 8 + (lq >> 1)) *    \
                                    64 + rdoff);
#define RDB8(DB, KS)                                                          \
  _Pragma("unroll") for (int nn = 0; nn < 4; ++nn)                            \
      bf[nn] = *(const short8*)(Bbuf + (DB) * (2 * AUNIT) + (KS)*AUNIT +      \
                                (wn * 32 + nn * 8 + (lq >> 1)) * 64 + rdoff);
#define MM168(MH)                                                             \
  _Pragma("unroll") for (int mm = 0; mm < 4; ++mm)                            \
      _Pragma("unroll") for (int nn = 0; nn < 4; ++nn)                        \
          acc[(MH)*4 + mm][nn] = __builtin_amdgcn_mfma_f32_16x16x32_bf16(     \
              af[mm], bf[nn], acc[(MH)*4 + mm][nn], 0, 0, 0);
#define SYNCA                                                                 \
  __builtin_amdgcn_s_barrier();                                               \
  asm volatile("s_waitcnt lgkmcnt(0)" ::: "memory");                          \
  __builtin_amdgcn_sched_barrier(0);                                          \
  __builtin_amdgcn_s_setprio(1);
#define ENDP __builtin_amdgcn_s_setprio(0);
#define BAR2 __builtin_amdgcn_s_barrier();
#define WAITN asm volatile("s_waitcnt vmcnt(8)" ::: "memory");
#define WAITH asm volatile("s_waitcnt vmcnt(4)" ::: "memory");

  const int NT = K >> 6, NI = NT >> 1;
  f32x4 acc[8][4] = {};
  short8 af[4], bf[4];

  STA8(0, 0, 0); STB8(0, 0, 0);
  STA8(0, 1, 0); STB8(0, 1, 0);
  STA8(1, 0, 1); STB8(1, 0, 1);
  WAITN;
  BAR2;

  for (int j = 0; j < NI; ++j) {
    const int t1 = 2 * j + 1, t2 = 2 * j + 2, t3 = 2 * j + 3;
    const bool s2 = t2 < NT, s3 = t3 < NT, lastI = (j + 1 == NI);
    RDB8(0, 0); RDA8(0, 0, 0);
    STA8(1, 1, t1);
    SYNCA; MM168(0); ENDP; BAR2;
    RDA8(0, 0, 1);
    STB8(1, 1, t1);
    SYNCA; MM168(1); ENDP;
    WAITN;
    BAR2;
    RDB8(0, 1); RDA8(0, 1, 0);
    if (s2) STA8(0, 0, t2);
    SYNCA; MM168(0); ENDP; BAR2;
    RDA8(0, 1, 1);
    if (s2) STB8(0, 0, t2);
    SYNCA; MM168(1); ENDP;
    if (lastI) { WAITH; } else { WAITN; }
    BAR2;
    RDB8(1, 0); RDA8(1, 0, 0);
    if (s2) STA8(0, 1, t2);
    SYNCA; MM168(0); ENDP; BAR2;
    RDA8(1, 0, 1);
    if (s2) STB8(0, 1, t2);
    SYNCA; MM168(1); ENDP;
    if (lastI) { asm volatile("s_waitcnt vmcnt(0)" ::: "memory"); } else { WAITN; }
    BAR2;
    RDB8(1, 1); RDA8(1, 1, 0);
    if (s3) STA8(1, 0, t3);
    SYNCA; MM168(0); ENDP; BAR2;
    RDA8(1, 1, 1);
    if (s3) STB8(1, 0, t3);
    SYNCA; MM168(1); ENDP;
    if (!lastI) { WAITN; }
    BAR2;
  }
#undef STA8
#undef STB8
#undef RDA8
#undef RDB8
#undef MM168
#undef SYNCA
#undef ENDP
#undef BAR2
#undef WAITN
#undef WAITH

  // ---- SwiGLU epilogue: exchange u2 via (dead) LDS, gate, store ----
  const int reg = wm * 2 + ((wn >= 2) ? (wn - 2) : wn);
  float* fb = (float*)((reg < 2 ? Abuf : Bbuf) + (reg & 1) * 16384);
  if (wn >= 2) {
#pragma unroll
    for (int m = 0; m < 8; m++)
#pragma unroll
      for (int n = 0; n < 4; n++)
#pragma unroll
        for (int r = 0; r < 4; r++) {
          int lrow = m * 16 + 4 * g + r;
          int pcol = (n * 16 + lq) ^ ((g & 1) << 4);
          fb[lrow * 64 + pcol] = acc[m][n][r];
        }
  }
  __syncthreads();
  if (wn < 2) {
#pragma unroll
    for (int m = 0; m < 8; m++) {
      size_t row = bm + wm * 128 + m * 16 + 4 * g;
#pragma unroll
      for (int n = 0; n < 4; n++) {
        size_t col = c0 + wn * 64 + n * 16 + lq;
#pragma unroll
        for (int r = 0; r < 4; r++) {
          int lrow = m * 16 + 4 * g + r;
          int pcol = (n * 16 + lq) ^ ((g & 1) << 4);
          float u1 = acc[m][n][r];
          float u2 = fb[lrow * 64 + pcol];
          float sil = u1 / (1.f + exp2f(-1.4426950408889634f * u1));
          Cout[(row + r) * (size_t)N + col] = f2bf(sil * u2);
        }
      }
    }
  }
}

// ----------------- causal flash attention (LDS-staged) --------------
// grid (T/128, B*H); 4 waves/block; wave owns 32 q-rows (2 rg of 16).
__global__ __launch_bounds__(256, 2) void attn_kernel(const u16* __restrict__ QKV,
                                                      const u16* __restrict__ VT,
                                                      u16* __restrict__ CTX) {
  __shared__ u16 Ks[64 * 128];
  __shared__ u16 Vs[128 * 64];
  __shared__ u16 P_all[4][32 * 72];
  const int t = threadIdx.x;
  const int w = t >> 6, l = t & 63, g = l >> 4, lq = l & 15;
  u16* P = P_all[w];
  const int q0blk = blockIdx.x * 128;
  const int q0w = q0blk + w * 32;
  const int bh = blockIdx.y, b = bh >> 4, h = bh & 15;
  const u16* qp = QKV + (size_t)b * T_SEQ * QS + h * D_HEAD;
  const u16* kp = QKV + (size_t)b * T_SEQ * QS + E_DIM + h * D_HEAD;
  const u16* vp = VT + ((size_t)b * E_DIM + h * D_HEAD) * T_SEQ;

  short8 qf[2][4];
#pragma unroll
  for (int rg = 0; rg < 2; rg++)
#pragma unroll
    for (int ks = 0; ks < 4; ks++)
      qf[rg][ks] =
          *(const short8*)(qp + (size_t)(q0w + rg * 16 + lq) * QS + ks * 32 + g * 8);

  f32x4 acc[2][8] = {};
  float m2[2][4], ls[2][4];
#pragma unroll
  for (int rg = 0; rg < 2; rg++)
#pragma unroll
    for (int r = 0; r < 4; r++) { m2[rg][r] = -1e30f; ls[rg][r] = 0.f; }
  const float sc = 0.08838834764831845f * 1.4426950408889634f;

  const int kRow0 = 16 * w + (l >> 4);
  const int kChunk = l & 15;
  const int vRow0 = 32 * w + (l >> 3);
  const int vChunk = l & 7;

  for (int kv0 = 0; kv0 < q0blk + 128; kv0 += 64) {
#pragma unroll
    for (int j = 0; j < 4; j++) {
      int R = kRow0 + 4 * j;
      async16(Ks + (16 * w + 4 * j) * 128,
              kp + (size_t)(kv0 + R) * QS + ((kChunk ^ (R & 7)) << 3));
    }
#pragma unroll
    for (int j = 0; j < 4; j++) {
      int D = vRow0 + 8 * j;
      async16(Vs + (32 * w + 8 * j) * 64,
              vp + (size_t)D * T_SEQ + kv0 + ((vChunk ^ (D & 7)) << 3));
    }
    __syncthreads();

#pragma unroll
    for (int rg = 0; rg < 2; rg++) {
      const int rb = q0w + rg * 16;
      if (kv0 > rb + 15) continue;
      f32x4 s[4];
      __builtin_amdgcn_s_setprio(1);
#pragma unroll
      for (int ct = 0; ct < 4; ct++) {
        s[ct] = f32x4{0.f, 0.f, 0.f, 0.f};
#pragma unroll
        for (int ks = 0; ks < 4; ks++) {
          short8 kf = *(const short8*)(Ks + (ct * 16 + lq) * 128 +
                                       (((ks * 4 + g) ^ (lq & 7)) << 3));
          s[ct] = __builtin_amdgcn_mfma_f32_16x16x32_bf16(qf[rg][ks], kf, s[ct], 0, 0, 0);
        }
      }
      __builtin_amdgcn_s_setprio(0);
      float sv[4][4];
#pragma unroll
      for (int ct = 0; ct < 4; ct++)
#pragma unroll
        for (int r = 0; r < 4; r++) sv[ct][r] = s[ct][r] * sc;
      if (kv0 + 64 > rb) {
#pragma unroll
        for (int ct = 0; ct < 4; ct++)
#pragma unroll
          for (int r = 0; r < 4; r++)
            if (kv0 + ct * 16 + lq > rb + 4 * g + r) sv[ct][r] = -1e30f;
      }
      float mx[4];
#pragma unroll
      for (int r = 0; r < 4; r++)
        mx[r] = fmaxf(fmaxf(sv[0][r], sv[1][r]), fmaxf(sv[2][r], sv[3][r]));
#pragma unroll
      for (int off = 1; off < 16; off <<= 1)
#pragma unroll
        for (int r = 0; r < 4; r++) mx[r] = fmaxf(mx[r], __shfl_xor(mx[r], off));
#pragma unroll
      for (int r = 0; r < 4; r++) {
        float mn = fmaxf(m2[rg][r], mx[r]);
        float sca = exp2f(m2[rg][r] - mn);
        m2[rg][r] = mn;
        float sum = 0.f;
#pragma unroll
        for (int ct = 0; ct < 4; ct++) {
          float pv = exp2f(sv[ct][r] - mn);
          sum += pv;
          P[(rg * 16 + 4 * g + r) * 72 + ct * 16 + lq] = f2bf(pv);
        }
        ls[rg][r] = ls[rg][r] * sca + sum;
#pragma unroll
        for (int n = 0; n < 8; n++) acc[rg][n][r] *= sca;
      }
      short8 pa[2];
#pragma unroll
      for (int ks2 = 0; ks2 < 2; ks2++)
        pa[ks2] = *(const short8*)(P + (rg * 16 + lq) * 72 + ks2 * 32 + g * 8);
      __builtin_amdgcn_s_setprio(1);
#pragma unroll
      for (int n = 0; n < 8; n++)
#pragma unroll
        for (int ks2 = 0; ks2 < 2; ks2++) {
          short8 vf = *(const short8*)(Vs + (n * 16 + lq) * 64 +
                                       (((ks2 * 4 + g) ^ (lq & 7)) << 3));
          acc[rg][n] = __builtin_amdgcn_mfma_f32_16x16x32_bf16(pa[ks2], vf, acc[rg][n], 0, 0, 0);
        }
      __builtin_amdgcn_s_setprio(0);
    }
    __syncthreads();
  }

#pragma unroll
  for (int rg = 0; rg < 2; rg++) {
#pragma unroll
    for (int off = 1; off < 16; off <<= 1)
#pragma unroll
      for (int r = 0; r < 4; r++) ls[rg][r] += __shfl_xor(ls[rg][r], off);
  }
  u16* cp = CTX + ((size_t)b * T_SEQ + q0w) * E_DIM + h * D_HEAD;
#pragma unroll
  for (int rg = 0; rg < 2; rg++) {
    float inv[4];
#pragma unroll
    for (int r = 0; r < 4; r++) inv[r] = 1.f / ls[rg][r];
#pragma unroll
    for (int n = 0; n < 8; n++)
#pragma unroll
      for (int r = 0; r < 4; r++)
        cp[(size_t)(rg * 16 + 4 * g + r) * E_DIM + n * 16 + lq] =
            f2bf(acc[rg][n][r] * inv[r]);
  }
}

extern "C" void kernel_launch(void* const* d_in, const int* in_sizes, int n_in,
                              void* d_out, int out_size, void* d_ws, size_t ws_size,
                              hipStream_t stream) {
  (void)in_sizes; (void)n_in; (void)out_size; (void)ws_size;
  const float* x  = (const float*)d_in[0];
  const float* g1 = (const float*)d_in[1];
  const float* b1 = (const float*)d_in[2];
  const float* wq = (const float*)d_in[3];
  const float* wk = (const float*)d_in[4];
  const float* wv = (const float*)d_in[5];
  const float* wo = (const float*)d_in[6];
  const float* g2 = (const float*)d_in[7];
  const float* b2 = (const float*)d_in[8];
  const float* w1 = (const float*)d_in[9];
  const float* w2 = (const float*)d_in[10];
  const float* w3 = (const float*)d_in[11];
  float* out = (float*)d_out;

  const size_t EE2 = (size_t)E_DIM * E_DIM * 2;
  const size_t EF2 = (size_t)E_DIM * FFN_DIM * 2;
  const size_t ME2 = (size_t)M_ROWS * E_DIM * 2;
  char* p = (char*)d_ws;
  u16* wqkvT = (u16*)p; p += 3 * EE2;
  u16* woT = (u16*)p; p += EE2;
  u16* w1T = (u16*)p; p += EF2;
  u16* w2T = (u16*)p; p += EF2;
  u16* w3T = (u16*)p; p += EF2;
  u16* Hb  = (u16*)p; p += ME2;
  u16* QKVb = (u16*)p; p += (size_t)M_ROWS * QS * 2;
  u16* VTb = (u16*)p; p += ME2;
  u16* CTXb = (u16*)p; p += ME2;
  u16* U1b = QKVb;            // gated reuses QKVb+VTb (64MB)
  u16* Pk = wqkvT;            // w3 split-K bf16 partials (32MB; wqkvT dead)

  dim3 blk32(32, 8);
  cvt_t_kernel<<<dim3(E_DIM / 32, E_DIM / 32), blk32, 0, stream>>>(wq, wqkvT, E_DIM, E_DIM);
  cvt_t_kernel<<<dim3(E_DIM / 32, E_DIM / 32), blk32, 0, stream>>>(wk, wqkvT + E_DIM * E_DIM, E_DIM, E_DIM);
  cvt_t_kernel<<<dim3(E_DIM / 32, E_DIM / 32), blk32, 0, stream>>>(wv, wqkvT + 2 * E_DIM * E_DIM, E_DIM, E_DIM);
  cvt_t_kernel<<<dim3(E_DIM / 32, E_DIM / 32), blk32, 0, stream>>>(wo, woT, E_DIM, E_DIM);
  cvt_t_kernel<<<dim3(FFN_DIM / 32, E_DIM / 32), blk32, 0, stream>>>(w1, w1T, E_DIM, FFN_DIM);
  cvt_t_kernel<<<dim3(FFN_DIM / 32, E_DIM / 32), blk32, 0, stream>>>(w2, w2T, E_DIM, FFN_DIM);
  cvt_t_kernel<<<dim3(E_DIM / 32, FFN_DIM / 32), blk32, 0, stream>>>(w3, w3T, FFN_DIM, E_DIM);

  // attention block
  ln_kernel<<<M_ROWS, 256, 0, stream>>>(x, g1, b1, Hb);
  // fused QKV GEMM at BM256: grid (24,16) = 384 blocks; chunk 6x8
  gemm8p<0, 256><<<dim3(QS / 256, M_ROWS / 256), 512, 0, stream>>>(
      Hb, wqkvT, QKVb, nullptr, QS, E_DIM, E_DIM, E_DIM, 6, 8);
  transpose_v_kernel<<<dim3(T_SEQ / 32, E_DIM / 32, 2), blk32, 0, stream>>>(QKVb, VTb);
  attn_kernel<<<dim3(T_SEQ / 128, 2 * N_HEAD), 256, 0, stream>>>(QKVb, VTb, CTXb);
  // WO: BM128, grid (8,32); chunk 4x8
  gemm8p<1, 128><<<dim3(E_DIM / 256, M_ROWS / 128), 512, 0, stream>>>(
      CTXb, woT, out, x, E_DIM, E_DIM, E_DIM, E_DIM, 4, 8);

  // SwiGLU MLP block
  ln_kernel<<<M_ROWS, 256, 0, stream>>>(out, g2, b2, Hb);
  // fused FFN1+FFN2+silu-gate: grid (64,16) = 1024 blocks; chunk 16x8
  gemm_ffn<<<dim3(FFN_DIM / 128, M_ROWS / 256), 512, 0, stream>>>(
      Hb, w1T, w2T, U1b, FFN_DIM, E_DIM, E_DIM, E_DIM, 16, 8);
  // w3: BM256 split-K=2: grid (8,16,2) = 256 blocks; chunk 4x8 per kz
  gemm8p<3, 256><<<dim3(E_DIM / 256, M_ROWS / 256, 2), 512, 0, stream>>>(
      U1b, w3T, Pk, nullptr, E_DIM, FFN_DIM / 2, FFN_DIM, FFN_DIM, 4, 8);
  add3_kernel<<<4096, 256, 0, stream>>>(out, Pk);
}

// Round 16
// 888.694 us; speedup vs baseline: 1.2158x; 1.0040x over previous
//
#include <hip/hip_runtime.h>

// Transformer layer, bf16 MFMA compute, fp32 I/O.
// B=2 T=2048 E=2048 H=16 DH=128 FFN=8192. Needs ~235MB workspace.

#define T_SEQ 2048
#define E_DIM 2048
#define N_HEAD 16
#define D_HEAD 128
#define FFN_DIM 8192
#define M_ROWS 4096  // B*T
#define QKS (2 * E_DIM)  // fused QK output row stride

typedef unsigned short u16;
typedef short short8 __attribute__((ext_vector_type(8)));
typedef float f32x4 __attribute__((ext_vector_type(4)));

#define DEV __device__ __forceinline__

DEV u16 f2bf(float f) {
  unsigned u = __float_as_uint(f);
  u += 0x7fffu + ((u >> 16) & 1u);
  return (u16)(u >> 16);
}
DEV float bf2f(u16 h) { return __uint_as_float(((unsigned)h) << 16); }

DEV void async16(void* lds, const void* g) {
  __builtin_amdgcn_global_load_lds((const __attribute__((address_space(1))) void*)g,
                                   (__attribute__((address_space(3))) void*)lds, 16, 0, 0);
}

// ---------------- LayerNorm: fp32 [rows][E] -> bf16 -----------------
__global__ __launch_bounds__(256) void ln_kernel(const float* __restrict__ x,
                                                 const float* __restrict__ gw,
                                                 const float* __restrict__ bw,
                                                 u16* __restrict__ out) {
  int row = blockIdx.x;
  int t = threadIdx.x;
  const float4* xr = (const float4*)(x + (size_t)row * E_DIM);
  float4 a = xr[t], c = xr[t + 256];
  float s = a.x + a.y + a.z + a.w + c.x + c.y + c.z + c.w;
  float q = a.x * a.x + a.y * a.y + a.z * a.z + a.w * a.w +
            c.x * c.x + c.y * c.y + c.z * c.z + c.w * c.w;
  for (int off = 32; off > 0; off >>= 1) {
    s += __shfl_down(s, off);
    q += __shfl_down(q, off);
  }
  __shared__ float red[8];
  if ((t & 63) == 0) { red[(t >> 6) * 2] = s; red[(t >> 6) * 2 + 1] = q; }
  __syncthreads();
  s = red[0] + red[2] + red[4] + red[6];
  q = red[1] + red[3] + red[5] + red[7];
  float mu = s * (1.f / E_DIM);
  float rs = rsqrtf(q * (1.f / E_DIM) - mu * mu + 1e-5f);
  const float4* g4 = (const float4*)gw;
  const float4* b4 = (const float4*)bw;
  float4 g0 = g4[t], g1v = g4[t + 256], e0 = b4[t], e1 = b4[t + 256];
  ushort4 o0, o1;
  o0.x = f2bf((a.x - mu) * rs * g0.x + e0.x);
  o0.y = f2bf((a.y - mu) * rs * g0.y + e0.y);
  o0.z = f2bf((a.z - mu) * rs * g0.z + e0.z);
  o0.w = f2bf((a.w - mu) * rs * g0.w + e0.w);
  o1.x = f2bf((c.x - mu) * rs * g1v.x + e1.x);
  o1.y = f2bf((c.y - mu) * rs * g1v.y + e1.y);
  o1.z = f2bf((c.z - mu) * rs * g1v.z + e1.z);
  o1.w = f2bf((c.w - mu) * rs * g1v.w + e1.w);
  ((ushort4*)(out + (size_t)row * E_DIM))[t] = o0;
  ((ushort4*)(out + (size_t)row * E_DIM))[t + 256] = o1;
}

// ------- convert+transpose: fp32 W[K][N] -> bf16 WT[N][K] -----------
__global__ __launch_bounds__(256) void cvt_t_kernel(const float* __restrict__ W,
                                                    u16* __restrict__ WT,
                                                    int Kd, int Nd) {
  __shared__ float tile[32][33];
  int tx = threadIdx.x, ty = threadIdx.y;
  int n0 = blockIdx.x * 32, k0 = blockIdx.y * 32;
#pragma unroll
  for (int i = 0; i < 4; i++)
    tile[ty + i * 8][tx] = W[(size_t)(k0 + ty + i * 8) * Nd + n0 + tx];
  __syncthreads();
#pragma unroll
  for (int i = 0; i < 4; i++)
    WT[(size_t)(n0 + ty + i * 8) * Kd + k0 + tx] = f2bf(tile[tx][ty + i * 8]);
}

// ------- transpose V: bf16 [B*T][E] -> [B][E][T] --------------------
__global__ __launch_bounds__(256) void transpose_v_kernel(const u16* __restrict__ v,
                                                          u16* __restrict__ vt) {
  __shared__ u16 tile[32][33];
  int tx = threadIdx.x, ty = threadIdx.y;
  int b = blockIdx.z;
  int t0 = blockIdx.x * 32, e0 = blockIdx.y * 32;
#pragma unroll
  for (int i = 0; i < 4; i++)
    tile[ty + i * 8][tx] =
        v[(size_t)(b * T_SEQ + t0 + ty + i * 8) * E_DIM + e0 + tx];
  __syncthreads();
#pragma unroll
  for (int i = 0; i < 4; i++)
    vt[((size_t)b * E_DIM + e0 + ty + i * 8) * T_SEQ + t0 + tx] = tile[tx][ty + i * 8];
}

// ------ add3: out += P0 + P1 (bf16 split-K partials, 96MB traffic) --
__global__ __launch_bounds__(256) void add3_kernel(float* __restrict__ out,
                                                   const u16* __restrict__ pk) {
  const size_t MN = (size_t)M_ROWS * E_DIM;
  size_t base = ((size_t)blockIdx.x * 256 + threadIdx.x) * 8;
  short8 a = *(const short8*)(pk + base);
  short8 b = *(const short8*)(pk + MN + base);
  float4 o0 = *(float4*)(out + base), o1 = *(float4*)(out + base + 4);
  o0.x += bf2f((u16)a[0]) + bf2f((u16)b[0]);
  o0.y += bf2f((u16)a[1]) + bf2f((u16)b[1]);
  o0.z += bf2f((u16)a[2]) + bf2f((u16)b[2]);
  o0.w += bf2f((u16)a[3]) + bf2f((u16)b[3]);
  o1.x += bf2f((u16)a[4]) + bf2f((u16)b[4]);
  o1.y += bf2f((u16)a[5]) + bf2f((u16)b[5]);
  o1.z += bf2f((u16)a[6]) + bf2f((u16)b[6]);
  o1.w += bf2f((u16)a[7]) + bf2f((u16)b[7]);
  *(float4*)(out + base) = o0;
  *(float4*)(out + base + 4) = o1;
}

// ======= GEMM BM_x256xBK64, 8-phase schedule, paired-row LDS ========
// Round-10 structure (proven).  2-D XCD chunking; split-K via kz.
// MODE 0: bf16 C.  MODE 1: Cout(f32)=Extra(f32)+acc.
// MODE 2: Cout(bf16)=silu(Extra bf16)*acc.
// MODE 3: bf16 split-K partial at Cout + kz*M*N.
template <int MODE, int BM_>
__global__ __launch_bounds__(512, 1) void gemm8p(const u16* __restrict__ A,
                                                 const u16* __restrict__ BT,
                                                 void* __restrict__ Cout,
                                                 const void* __restrict__ Extra,
                                                 int N, int K, int lda, int ldb,
                                                 int CX, int CY) {
  constexpr int MM = BM_ / 64;
  constexpr int AUNIT = BM_ * 32;
  __shared__ u16 Abuf[4 * AUNIT];
  __shared__ u16 Bbuf[4 * 8192];
  const int t = threadIdx.x;
  const int w = t >> 6, l = t & 63, g = l >> 4, lq = l & 15;
  const int wm = w >> 2, wn = w & 3;

  const int bid = (blockIdx.z * gridDim.y + blockIdx.y) * gridDim.x + blockIdx.x;
  const int xcd = bid & 7, slot = bid >> 3;
  const int nchx = gridDim.x / CX;
  const int nchy = gridDim.y / CY;
  const int cpz = nchx * nchy;
  const int kz = xcd / cpz;
  const int cid = xcd % cpz;
  const int bx = (cid % nchx) * CX + (slot % CX);
  const int by = (cid / nchx) * CY + (slot / CX);
  const size_t bm = (size_t)by * BM_, bn = (size_t)bx * 256;
  const size_t koff = (size_t)kz * K;

  const int srcrow = ((l >> 3) << 1) | (l & 1);
  const int csrc = ((((l >> 1) & 3) ^ ((l >> 3) & 3)) << 3);
  const u16* aSrc = A + (bm + w * 16 + srcrow) * (size_t)lda + koff + csrc;
  const u16* bSrc = BT + (bn + w * 16 + srcrow) * (size_t)ldb + koff + csrc;
  const int rdoff = (((lq & 1) + 2 * (g ^ ((lq >> 1) & 3))) << 3);

#define STA8(DB, KS, TILE)                                                    \
  {                                                                           \
    u16* Ad = Abuf + (DB) * (2 * AUNIT) + (KS)*AUNIT + w * 512;               \
    const u16* as_ = aSrc + (size_t)(TILE)*64 + (KS)*32;                      \
    async16(Ad, as_);                                                         \
    if constexpr (BM_ == 256) async16(Ad + 4096, as_ + (size_t)128 * lda);    \
  }
#define STB8(DB, KS, TILE)                                                    \
  {                                                                           \
    u16* Bd = Bbuf + (DB)*16384 + (KS)*8192 + w * 512;                        \
    const u16* bs_ = bSrc + (size_t)(TILE)*64 + (KS)*32;                      \
    async16(Bd, bs_);                                                         \
    async16(Bd + 4096, bs_ + (size_t)128 * ldb);                              \
  }
#define RDA8(DB, KS, MH)                                                      \
  _Pragma("unroll") for (int mm = 0; mm < MM; ++mm)                           \
      af[mm] = *(const short8*)(Abuf + (DB) * (2 * AUNIT) + (KS)*AUNIT +      \
                                (wm * (BM_ / 4) + (MH) * (BM_ / 8) + mm * 8 + \
                                 (lq >> 1)) * 64 + rdoff);
#define RDB8(DB, KS)                                                          \
  _Pragma("unroll") for (int nn = 0; nn < 4; ++nn)                            \
      bf[nn] = *(const short8*)(Bbuf + (DB)*16384 + (KS)*8192 +               \
                                (wn * 32 + nn * 8 + (lq >> 1)) * 64 + rdoff);
#define MM168(MH)                                                             \
  _Pragma("unroll") for (int mm = 0; mm < MM; ++mm)                           \
      _Pragma("unroll") for (int nn = 0; nn < 4; ++nn)                        \
          acc[(MH)*MM + mm][nn] = __builtin_amdgcn_mfma_f32_16x16x32_bf16(    \
              af[mm], bf[nn], acc[(MH)*MM + mm][nn], 0, 0, 0);
#define SYNCA                                                                 \
  __builtin_amdgcn_s_barrier();                                               \
  asm volatile("s_waitcnt lgkmcnt(0)" ::: "memory");                          \
  __builtin_amdgcn_sched_barrier(0);                                          \
  __builtin_amdgcn_s_setprio(1);
#define ENDP __builtin_amdgcn_s_setprio(0);
#define BAR2 __builtin_amdgcn_s_barrier();
#define WAITN                                                                 \
  if constexpr (BM_ == 256) asm volatile("s_waitcnt vmcnt(8)" ::: "memory");  \
  else                      asm volatile("s_waitcnt vmcnt(6)" ::: "memory");
#define WAITH                                                                 \
  if constexpr (BM_ == 256) asm volatile("s_waitcnt vmcnt(4)" ::: "memory");  \
  else                      asm volatile("s_waitcnt vmcnt(3)" ::: "memory");

  const int NT = K >> 6, NI = NT >> 1;
  f32x4 acc[2 * MM][4] = {};
  short8 af[MM > 4 ? MM : 4], bf[4];

  STA8(0, 0, 0); STB8(0, 0, 0);
  STA8(0, 1, 0); STB8(0, 1, 0);
  STA8(1, 0, 1); STB8(1, 0, 1);
  WAITN;
  BAR2;

  for (int j = 0; j < NI; ++j) {
    const int t1 = 2 * j + 1, t2 = 2 * j + 2, t3 = 2 * j + 3;
    const bool s2 = t2 < NT, s3 = t3 < NT, lastI = (j + 1 == NI);
    RDB8(0, 0); RDA8(0, 0, 0);
    STA8(1, 1, t1);
    SYNCA; MM168(0); ENDP; BAR2;
    RDA8(0, 0, 1);
    STB8(1, 1, t1);
    SYNCA; MM168(1); ENDP;
    WAITN;
    BAR2;
    RDB8(0, 1); RDA8(0, 1, 0);
    if (s2) STA8(0, 0, t2);
    SYNCA; MM168(0); ENDP; BAR2;
    RDA8(0, 1, 1);
    if (s2) STB8(0, 0, t2);
    SYNCA; MM168(1); ENDP;
    if (lastI) { WAITH; } else { WAITN; }
    BAR2;
    RDB8(1, 0); RDA8(1, 0, 0);
    if (s2) STA8(0, 1, t2);
    SYNCA; MM168(0); ENDP; BAR2;
    RDA8(1, 0, 1);
    if (s2) STB8(0, 1, t2);
    SYNCA; MM168(1); ENDP;
    if (lastI) { asm volatile("s_waitcnt vmcnt(0)" ::: "memory"); } else { WAITN; }
    BAR2;
    RDB8(1, 1); RDA8(1, 1, 0);
    if (s3) STA8(1, 0, t3);
    SYNCA; MM168(0); ENDP; BAR2;
    RDA8(1, 1, 1);
    if (s3) STB8(1, 0, t3);
    SYNCA; MM168(1); ENDP;
    if (!lastI) { WAITN; }
    BAR2;
  }
#undef STA8
#undef STB8
#undef RDA8
#undef RDB8
#undef MM168
#undef SYNCA
#undef ENDP
#undef BAR2
#undef WAITN
#undef WAITH

  const size_t mn = (size_t)gridDim.y * BM_ * (size_t)N;
#pragma unroll
  for (int m = 0; m < 2 * MM; m++) {
    size_t row = bm + wm * (BM_ / 2) + m * 16 + 4 * g;
#pragma unroll
    for (int n = 0; n < 4; n++) {
      size_t col = bn + wn * 64 + n * 16 + lq;
#pragma unroll
      for (int r = 0; r < 4; r++) {
        size_t idx = (row + r) * (size_t)N + col;
        if constexpr (MODE == 0) {
          ((u16*)Cout)[idx] = f2bf(acc[m][n][r]);
        } else if constexpr (MODE == 1) {
          ((float*)Cout)[idx] = ((const float*)Extra)[idx] + acc[m][n][r];
        } else if constexpr (MODE == 2) {
          float a = bf2f(((const u16*)Extra)[idx]);
          float sil = a / (1.f + exp2f(-1.4426950408889634f * a));
          ((u16*)Cout)[idx] = f2bf(sil * acc[m][n][r]);
        } else {
          ((u16*)Cout)[(size_t)kz * mn + idx] = f2bf(acc[m][n][r]);
        }
      }
    }
  }
}

// ==== FUSED SwiGLU FFN GEMM: gated = silu(A@w1T^T) * (A@w2T^T) ======
// (round-14 kernel, unchanged)
__global__ __launch_bounds__(512, 1) void gemm_ffn(const u16* __restrict__ A,
                                                   const u16* __restrict__ B1T,
                                                   const u16* __restrict__ B2T,
                                                   u16* __restrict__ Cout,
                                                   int N, int K, int lda, int ldb,
                                                   int CX, int CY) {
  constexpr int AUNIT = 8192;
  __shared__ u16 Abuf[4 * AUNIT];
  __shared__ u16 Bbuf[4 * AUNIT];
  const int t = threadIdx.x;
  const int w = t >> 6, l = t & 63, g = l >> 4, lq = l & 15;
  const int wm = w >> 2, wn = w & 3;

  const int bid = blockIdx.y * gridDim.x + blockIdx.x;
  const int xcd = bid & 7, slot = bid >> 3;
  const int nchx = gridDim.x / CX;
  const int cid = xcd;
  const int bx = (cid % nchx) * CX + (slot % CX);
  const int by = (cid / nchx) * CY + (slot / CX);
  const size_t bm = (size_t)by * 256;
  const size_t c0 = (size_t)bx * 128;

  const int srcrow = ((l >> 3) << 1) | (l & 1);
  const int csrc = ((((l >> 1) & 3) ^ ((l >> 3) & 3)) << 3);
  const u16* aSrc = A + (bm + w * 16 + srcrow) * (size_t)lda + csrc;
  const u16* b1Src = B1T + (c0 + w * 16 + srcrow) * (size_t)ldb + csrc;
  const u16* b2Src = B2T + (c0 + w * 16 + srcrow) * (size_t)ldb + csrc;
  const int rdoff = (((lq & 1) + 2 * (g ^ ((lq >> 1) & 3))) << 3);

#define STA8(DB, KS, TILE)                                                    \
  {                                                                           \
    u16* Ad = Abuf + (DB) * (2 * AUNIT) + (KS)*AUNIT + w * 512;               \
    const u16* as_ = aSrc + (size_t)(TILE)*64 + (KS)*32;                      \
    async16(Ad, as_);                                                         \
    async16(Ad + 4096, as_ + (size_t)128 * lda);                              \
  }
#define STB8(DB, KS, TILE)                                                    \
  {                                                                           \
    u16* Bd = Bbuf + (DB) * (2 * AUNIT) + (KS)*AUNIT + w * 512;               \
    size_t off_ = (size_t)(TILE)*64 + (KS)*32;                                \
    async16(Bd, b1Src + off_);                                                \
    async16(Bd + 4096, b2Src + off_);                                         \
  }
#define RDA8(DB, KS, MH)                                                      \
  _Pragma("unroll") for (int mm = 0; mm < 4; ++mm)                            \
      af[mm] = *(const short8*)(Abuf + (DB) * (2 * AUNIT) + (KS)*AUNIT +      \
                                (wm * 64 + (MH)*32 + mm * 8 + (lq >> 1)) *    \
                                    64 + rdoff);
#define RDB8(DB, KS)                                                          \
  _Pragma("unroll") for (int nn = 0; nn < 4; ++nn)                            \
      bf[nn] = *(const short8*)(Bbuf + (DB) * (2 * AUNIT) + (KS)*AUNIT +      \
                                (wn * 32 + nn * 8 + (lq >> 1)) * 64 + rdoff);
#define MM168(MH)                                                             \
  _Pragma("unroll") for (int mm = 0; mm < 4; ++mm)                            \
      _Pragma("unroll") for (int nn = 0; nn < 4; ++nn)                        \
          acc[(MH)*4 + mm][nn] = __builtin_amdgcn_mfma_f32_16x16x32_bf16(     \
              af[mm], bf[nn], acc[(MH)*4 + mm][nn], 0, 0, 0);
#define SYNCA                                                                 \
  __builtin_amdgcn_s_barrier();                                               \
  asm volatile("s_waitcnt lgkmcnt(0)" ::: "memory");                          \
  __builtin_amdgcn_sched_barrier(0);                                          \
  __builtin_amdgcn_s_setprio(1);
#define ENDP __builtin_amdgcn_s_setprio(0);
#define BAR2 __builtin_amdgcn_s_barrier();
#define WAITN asm volatile("s_waitcnt vmcnt(8)" ::: "memory");
#define WAITH asm volatile("s_waitcnt vmcnt(4)" ::: "memory");

  const int NT = K >> 6, NI = NT >> 1;
  f32x4 acc[8][4] = {};
  short8 af[4], bf[4];

  STA8(0, 0, 0); STB8(0, 0, 0);
  STA8(0, 1, 0); STB8(0, 1, 0);
  STA8(1, 0, 1); STB8(1, 0, 1);
  WAITN;
  BAR2;

  for (int j = 0; j < NI; ++j) {
    const int t1 = 2 * j + 1, t2 = 2 * j + 2, t3 = 2 * j + 3;
    const bool s2 = t2 < NT, s3 = t3 < NT, lastI = (j + 1 == NI);
    RDB8(0, 0); RDA8(0, 0, 0);
    STA8(1, 1, t1);
    SYNCA; MM168(0); ENDP; BAR2;
    RDA8(0, 0, 1);
    STB8(1, 1, t1);
    SYNCA; MM168(1); ENDP;
    WAITN;
    BAR2;
    RDB8(0, 1); RDA8(0, 1, 0);
    if (s2) STA8(0, 0, t2);
    SYNCA; MM168(0); ENDP; BAR2;
    RDA8(0, 1, 1);
    if (s2) STB8(0, 0, t2);
    SYNCA; MM168(1); ENDP;
    if (lastI) { WAITH; } else { WAITN; }
    BAR2;
    RDB8(1, 0); RDA8(1, 0, 0);
    if (s2) STA8(0, 1, t2);
    SYNCA; MM168(0); ENDP; BAR2;
    RDA8(1, 0, 1);
    if (s2) STB8(0, 1, t2);
    SYNCA; MM168(1); ENDP;
    if (lastI) { asm volatile("s_waitcnt vmcnt(0)" ::: "memory"); } else { WAITN; }
    BAR2;
    RDB8(1, 1); RDA8(1, 1, 0);
    if (s3) STA8(1, 0, t3);
    SYNCA; MM168(0); ENDP; BAR2;
    RDA8(1, 1, 1);
    if (s3) STB8(1, 0, t3);
    SYNCA; MM168(1); ENDP;
    if (!lastI) { WAITN; }
    BAR2;
  }
#undef STA8
#undef STB8
#undef RDA8
#undef RDB8
#undef MM168
#undef SYNCA
#undef ENDP
#undef BAR2
#undef WAITN
#undef WAITH

  // ---- SwiGLU epilogue: exchange u2 via (dead) LDS, gate, store ----
  const int reg = wm * 2 + ((wn >= 2) ? (wn - 2) : wn);
  float* fb = (float*)((reg < 2 ? Abuf : Bbuf) + (reg & 1) * 16384);
  if (wn >= 2) {
#pragma unroll
    for (int m = 0; m < 8; m++)
#pragma unroll
      for (int n = 0; n < 4; n++)
#pragma unroll
        for (int r = 0; r < 4; r++) {
          int lrow = m * 16 + 4 * g + r;
          int pcol = (n * 16 + lq) ^ ((g & 1) << 4);
          fb[lrow * 64 + pcol] = acc[m][n][r];
        }
  }
  __syncthreads();
  if (wn < 2) {
#pragma unroll
    for (int m = 0; m < 8; m++) {
      size_t row = bm + wm * 128 + m * 16 + 4 * g;
#pragma unroll
      for (int n = 0; n < 4; n++) {
        size_t col = c0 + wn * 64 + n * 16 + lq;
#pragma unroll
        for (int r = 0; r < 4; r++) {
          int lrow = m * 16 + 4 * g + r;
          int pcol = (n * 16 + lq) ^ ((g & 1) << 4);
          float u1 = acc[m][n][r];
          float u2 = fb[lrow * 64 + pcol];
          float sil = u1 / (1.f + exp2f(-1.4426950408889634f * u1));
          Cout[(row + r) * (size_t)N + col] = f2bf(sil * u2);
        }
      }
    }
  }
}

// ----------------- causal flash attention (LDS-staged) --------------
// grid (T/128, B*H); 4 waves/block; wave owns 32 q-rows (2 rg of 16).
// Q,K from fused QK buffer [B*T][4096] (q cols 0..2047, k cols 2048+).
__global__ __launch_bounds__(256, 2) void attn_kernel(const u16* __restrict__ QK,
                                                      const u16* __restrict__ VT,
                                                      u16* __restrict__ CTX) {
  __shared__ u16 Ks[64 * 128];
  __shared__ u16 Vs[128 * 64];
  __shared__ u16 P_all[4][32 * 72];
  const int t = threadIdx.x;
  const int w = t >> 6, l = t & 63, g = l >> 4, lq = l & 15;
  u16* P = P_all[w];
  const int q0blk = blockIdx.x * 128;
  const int q0w = q0blk + w * 32;
  const int bh = blockIdx.y, b = bh >> 4, h = bh & 15;
  const u16* qp = QK + (size_t)b * T_SEQ * QKS + h * D_HEAD;
  const u16* kp = qp + E_DIM;
  const u16* vp = VT + ((size_t)b * E_DIM + h * D_HEAD) * T_SEQ;

  short8 qf[2][4];
#pragma unroll
  for (int rg = 0; rg < 2; rg++)
#pragma unroll
    for (int ks = 0; ks < 4; ks++)
      qf[rg][ks] =
          *(const short8*)(qp + (size_t)(q0w + rg * 16 + lq) * QKS + ks * 32 + g * 8);

  f32x4 acc[2][8] = {};
  float m2[2][4], ls[2][4];
#pragma unroll
  for (int rg = 0; rg < 2; rg++)
#pragma unroll
    for (int r = 0; r < 4; r++) { m2[rg][r] = -1e30f; ls[rg][r] = 0.f; }
  const float sc = 0.08838834764831845f * 1.4426950408889634f;

  const int kRow0 = 16 * w + (l >> 4);
  const int kChunk = l & 15;
  const int vRow0 = 32 * w + (l >> 3);
  const int vChunk = l & 7;

  for (int kv0 = 0; kv0 < q0blk + 128; kv0 += 64) {
#pragma unroll
    for (int j = 0; j < 4; j++) {
      int R = kRow0 + 4 * j;
      async16(Ks + (16 * w + 4 * j) * 128,
              kp + (size_t)(kv0 + R) * QKS + ((kChunk ^ (R & 7)) << 3));
    }
#pragma unroll
    for (int j = 0; j < 4; j++) {
      int D = vRow0 + 8 * j;
      async16(Vs + (32 * w + 8 * j) * 64,
              vp + (size_t)D * T_SEQ + kv0 + ((vChunk ^ (D & 7)) << 3));
    }
    __syncthreads();

#pragma unroll
    for (int rg = 0; rg < 2; rg++) {
      const int rb = q0w + rg * 16;
      if (kv0 > rb + 15) continue;
      f32x4 s[4];
      __builtin_amdgcn_s_setprio(1);
#pragma unroll
      for (int ct = 0; ct < 4; ct++) {
        s[ct] = f32x4{0.f, 0.f, 0.f, 0.f};
#pragma unroll
        for (int ks = 0; ks < 4; ks++) {
          short8 kf = *(const short8*)(Ks + (ct * 16 + lq) * 128 +
                                       (((ks * 4 + g) ^ (lq & 7)) << 3));
          s[ct] = __builtin_amdgcn_mfma_f32_16x16x32_bf16(qf[rg][ks], kf, s[ct], 0, 0, 0);
        }
      }
      __builtin_amdgcn_s_setprio(0);
      float sv[4][4];
#pragma unroll
      for (int ct = 0; ct < 4; ct++)
#pragma unroll
        for (int r = 0; r < 4; r++) sv[ct][r] = s[ct][r] * sc;
      if (kv0 + 64 > rb) {
#pragma unroll
        for (int ct = 0; ct < 4; ct++)
#pragma unroll
          for (int r = 0; r < 4; r++)
            if (kv0 + ct * 16 + lq > rb + 4 * g + r) sv[ct][r] = -1e30f;
      }
      float mx[4];
#pragma unroll
      for (int r = 0; r < 4; r++)
        mx[r] = fmaxf(fmaxf(sv[0][r], sv[1][r]), fmaxf(sv[2][r], sv[3][r]));
#pragma unroll
      for (int off = 1; off < 16; off <<= 1)
#pragma unroll
        for (int r = 0; r < 4; r++) mx[r] = fmaxf(mx[r], __shfl_xor(mx[r], off));
#pragma unroll
      for (int r = 0; r < 4; r++) {
        float mn = fmaxf(m2[rg][r], mx[r]);
        float sca = exp2f(m2[rg][r] - mn);
        m2[rg][r] = mn;
        float sum = 0.f;
#pragma unroll
        for (int ct = 0; ct < 4; ct++) {
          float pv = exp2f(sv[ct][r] - mn);
          sum += pv;
          P[(rg * 16 + 4 * g + r) * 72 + ct * 16 + lq] = f2bf(pv);
        }
        ls[rg][r] = ls[rg][r] * sca + sum;
#pragma unroll
        for (int n = 0; n < 8; n++) acc[rg][n][r] *= sca;
      }
      short8 pa[2];
#pragma unroll
      for (int ks2 = 0; ks2 < 2; ks2++)
        pa[ks2] = *(const short8*)(P + (rg * 16 + lq) * 72 + ks2 * 32 + g * 8);
      __builtin_amdgcn_s_setprio(1);
#pragma unroll
      for (int n = 0; n < 8; n++)
#pragma unroll
        for (int ks2 = 0; ks2 < 2; ks2++) {
          short8 vf = *(const short8*)(Vs + (n * 16 + lq) * 64 +
                                       (((ks2 * 4 + g) ^ (lq & 7)) << 3));
          acc[rg][n] = __builtin_amdgcn_mfma_f32_16x16x32_bf16(pa[ks2], vf, acc[rg][n], 0, 0, 0);
        }
      __builtin_amdgcn_s_setprio(0);
    }
    __syncthreads();
  }

#pragma unroll
  for (int rg = 0; rg < 2; rg++) {
#pragma unroll
    for (int off = 1; off < 16; off <<= 1)
#pragma unroll
      for (int r = 0; r < 4; r++) ls[rg][r] += __shfl_xor(ls[rg][r], off);
  }
  u16* cp = CTX + ((size_t)b * T_SEQ + q0w) * E_DIM + h * D_HEAD;
#pragma unroll
  for (int rg = 0; rg < 2; rg++) {
    float inv[4];
#pragma unroll
    for (int r = 0; r < 4; r++) inv[r] = 1.f / ls[rg][r];
#pragma unroll
    for (int n = 0; n < 8; n++)
#pragma unroll
      for (int r = 0; r < 4; r++)
        cp[(size_t)(rg * 16 + 4 * g + r) * E_DIM + n * 16 + lq] =
            f2bf(acc[rg][n][r] * inv[r]);
  }
}

extern "C" void kernel_launch(void* const* d_in, const int* in_sizes, int n_in,
                              void* d_out, int out_size, void* d_ws, size_t ws_size,
                              hipStream_t stream) {
  (void)in_sizes; (void)n_in; (void)out_size; (void)ws_size;
  const float* x  = (const float*)d_in[0];
  const float* g1 = (const float*)d_in[1];
  const float* b1 = (const float*)d_in[2];
  const float* wq = (const float*)d_in[3];
  const float* wk = (const float*)d_in[4];
  const float* wv = (const float*)d_in[5];
  const float* wo = (const float*)d_in[6];
  const float* g2 = (const float*)d_in[7];
  const float* b2 = (const float*)d_in[8];
  const float* w1 = (const float*)d_in[9];
  const float* w2 = (const float*)d_in[10];
  const float* w3 = (const float*)d_in[11];
  float* out = (float*)d_out;

  const size_t EE = (size_t)E_DIM * E_DIM;           // elements
  const size_t EE2 = EE * 2;                         // bytes
  const size_t EF2 = (size_t)E_DIM * FFN_DIM * 2;
  const size_t ME2 = (size_t)M_ROWS * E_DIM * 2;
  char* p = (char*)d_ws;
  u16* wqkT = (u16*)p; p += 2 * EE2;   // [2E][E]: rows 0..E-1 = wq^T
  u16* wvT = (u16*)p; p += EE2;
  u16* woT = (u16*)p; p += EE2;
  u16* w1T = (u16*)p; p += EF2;
  u16* w2T = (u16*)p; p += EF2;
  u16* w3T = (u16*)p; p += EF2;
  u16* Hb  = (u16*)p; p += ME2;
  u16* QKb = (u16*)p; p += (size_t)M_ROWS * QKS * 2;  // [4096][4096]
  u16* Vb  = (u16*)p; p += ME2;
  u16* VTb = (u16*)p; p += ME2;
  u16* CTXb = (u16*)p; p += ME2;
  u16* U1b = QKb;   // gated (67MB) reuses QKb+Vb+VTb (33.6+16.8+16.8)
  u16* Pk = wqkT;   // w3 split-K bf16 partials (33.55MB over
                    // wqkT+wvT+woT = 33.55MB, all dead by w3; exact fit)

  dim3 blk32(32, 8);
  cvt_t_kernel<<<dim3(E_DIM / 32, E_DIM / 32), blk32, 0, stream>>>(wq, wqkT, E_DIM, E_DIM);
  cvt_t_kernel<<<dim3(E_DIM / 32, E_DIM / 32), blk32, 0, stream>>>(wk, wqkT + EE, E_DIM, E_DIM);
  cvt_t_kernel<<<dim3(E_DIM / 32, E_DIM / 32), blk32, 0, stream>>>(wv, wvT, E_DIM, E_DIM);
  cvt_t_kernel<<<dim3(E_DIM / 32, E_DIM / 32), blk32, 0, stream>>>(wo, woT, E_DIM, E_DIM);
  cvt_t_kernel<<<dim3(FFN_DIM / 32, E_DIM / 32), blk32, 0, stream>>>(w1, w1T, E_DIM, FFN_DIM);
  cvt_t_kernel<<<dim3(FFN_DIM / 32, E_DIM / 32), blk32, 0, stream>>>(w2, w2T, E_DIM, FFN_DIM);
  cvt_t_kernel<<<dim3(E_DIM / 32, FFN_DIM / 32), blk32, 0, stream>>>(w3, w3T, FFN_DIM, E_DIM);

  // attention block
  ln_kernel<<<M_ROWS, 256, 0, stream>>>(x, g1, b1, Hb);
  // fused QK GEMM at BM256: grid (16,16) = 256 blocks = 1 full round;
  // chunk 4x8 (nchx=4, nchy=2 -> 8 chunks, kz=0)
  gemm8p<0, 256><<<dim3(QKS / 256, M_ROWS / 256), 512, 0, stream>>>(
      Hb, wqkT, QKb, nullptr, QKS, E_DIM, E_DIM, E_DIM, 4, 8);
  // V GEMM at BM128: grid (8,32) = 256 blocks = 1 full round; chunk 4x8
  gemm8p<0, 128><<<dim3(E_DIM / 256, M_ROWS / 128), 512, 0, stream>>>(
      Hb, wvT, Vb, nullptr, E_DIM, E_DIM, E_DIM, E_DIM, 4, 8);
  transpose_v_kernel<<<dim3(T_SEQ / 32, E_DIM / 32, 2), blk32, 0, stream>>>(Vb, VTb);
  attn_kernel<<<dim3(T_SEQ / 128, 2 * N_HEAD), 256, 0, stream>>>(QKb, VTb, CTXb);
  // WO: BM128, grid (8,32); chunk 4x8
  gemm8p<1, 128><<<dim3(E_DIM / 256, M_ROWS / 128), 512, 0, stream>>>(
      CTXb, woT, out, x, E_DIM, E_DIM, E_DIM, E_DIM, 4, 8);

  // SwiGLU MLP block
  ln_kernel<<<M_ROWS, 256, 0, stream>>>(out, g2, b2, Hb);
  // fused FFN1+FFN2+silu-gate: grid (64,16) = 1024 blocks; chunk 16x8
  gemm_ffn<<<dim3(FFN_DIM / 128, M_ROWS / 256), 512, 0, stream>>>(
      Hb, w1T, w2T, U1b, FFN_DIM, E_DIM, E_DIM, E_DIM, 16, 8);
  // w3: BM256 split-K=2: grid (8,16,2) = 256 blocks; chunk 4x8 per kz
  gemm8p<3, 256><<<dim3(E_DIM / 256, M_ROWS / 256, 2), 512, 0, stream>>>(
      U1b, w3T, Pk, nullptr, E_DIM, FFN_DIM / 2, FFN_DIM, FFN_DIM, 4, 8);
  add3_kernel<<<4096, 256, 0, stream>>>(out, Pk);
}

// Round 18
// 875.416 us; speedup vs baseline: 1.2343x; 1.0152x over previous
//
#include <hip/hip_runtime.h>

// Transformer layer, bf16 MFMA compute, fp32 I/O.
// B=2 T=2048 E=2048 H=16 DH=128 FFN=8192. Needs ~256MB workspace.

#define T_SEQ 2048
#define E_DIM 2048
#define N_HEAD 16
#define D_HEAD 128
#define FFN_DIM 8192
#define M_ROWS 4096  // B*T
#define QKS (2 * E_DIM)  // fused QK output row stride

typedef unsigned short u16;
typedef short short8 __attribute__((ext_vector_type(8)));
typedef float f32x4 __attribute__((ext_vector_type(4)));

#define DEV __device__ __forceinline__

DEV u16 f2bf(float f) {
  unsigned u = __float_as_uint(f);
  u += 0x7fffu + ((u >> 16) & 1u);
  return (u16)(u >> 16);
}
DEV float bf2f(u16 h) { return __uint_as_float(((unsigned)h) << 16); }

DEV void async16(void* lds, const void* g) {
  __builtin_amdgcn_global_load_lds((const __attribute__((address_space(1))) void*)g,
                                   (__attribute__((address_space(3))) void*)lds, 16, 0, 0);
}

// ---------------- LayerNorm: fp32 [rows][E] -> bf16 -----------------
__global__ __launch_bounds__(256) void ln_kernel(const float* __restrict__ x,
                                                 const float* __restrict__ gw,
                                                 const float* __restrict__ bw,
                                                 u16* __restrict__ out) {
  int row = blockIdx.x;
  int t = threadIdx.x;
  const float4* xr = (const float4*)(x + (size_t)row * E_DIM);
  float4 a = xr[t], c = xr[t + 256];
  float s = a.x + a.y + a.z + a.w + c.x + c.y + c.z + c.w;
  float q = a.x * a.x + a.y * a.y + a.z * a.z + a.w * a.w +
            c.x * c.x + c.y * c.y + c.z * c.z + c.w * c.w;
  for (int off = 32; off > 0; off >>= 1) {
    s += __shfl_down(s, off);
    q += __shfl_down(q, off);
  }
  __shared__ float red[8];
  if ((t & 63) == 0) { red[(t >> 6) * 2] = s; red[(t >> 6) * 2 + 1] = q; }
  __syncthreads();
  s = red[0] + red[2] + red[4] + red[6];
  q = red[1] + red[3] + red[5] + red[7];
  float mu = s * (1.f / E_DIM);
  float rs = rsqrtf(q * (1.f / E_DIM) - mu * mu + 1e-5f);
  const float4* g4 = (const float4*)gw;
  const float4* b4 = (const float4*)bw;
  float4 g0 = g4[t], g1v = g4[t + 256], e0 = b4[t], e1 = b4[t + 256];
  ushort4 o0, o1;
  o0.x = f2bf((a.x - mu) * rs * g0.x + e0.x);
  o0.y = f2bf((a.y - mu) * rs * g0.y + e0.y);
  o0.z = f2bf((a.z - mu) * rs * g0.z + e0.z);
  o0.w = f2bf((a.w - mu) * rs * g0.w + e0.w);
  o1.x = f2bf((c.x - mu) * rs * g1v.x + e1.x);
  o1.y = f2bf((c.y - mu) * rs * g1v.y + e1.y);
  o1.z = f2bf((c.z - mu) * rs * g1v.z + e1.z);
  o1.w = f2bf((c.w - mu) * rs * g1v.w + e1.w);
  ((ushort4*)(out + (size_t)row * E_DIM))[t] = o0;
  ((ushort4*)(out + (size_t)row * E_DIM))[t + 256] = o1;
}

// ==== ALL-weights convert+transpose in ONE dispatch =================
// block ranges: [0,16384): wq/wk/wv/wo (4096 tiles each);
// [16384,49152): w1/w2 (16384 each); [49152,65536): w3.
__global__ __launch_bounds__(256) void cvt_all_kernel(
    const float* __restrict__ wq, const float* __restrict__ wk,
    const float* __restrict__ wv, const float* __restrict__ wo,
    const float* __restrict__ w1, const float* __restrict__ w2,
    const float* __restrict__ w3, u16* __restrict__ wqkT,
    u16* __restrict__ wvT, u16* __restrict__ woT, u16* __restrict__ w1T,
    u16* __restrict__ w2T, u16* __restrict__ w3T) {
  __shared__ float tile[32][33];
  const int b = blockIdx.x;
  const float* W;
  u16* WT;
  int Kd, Nd, n0, k0;
  if (b < 16384) {
    int widx = b >> 12, t_ = b & 4095;
    Kd = E_DIM; Nd = E_DIM;
    n0 = (t_ & 63) * 32; k0 = (t_ >> 6) * 32;
    W = widx == 0 ? wq : widx == 1 ? wk : widx == 2 ? wv : wo;
    WT = widx == 0 ? wqkT
         : widx == 1 ? (wqkT + (size_t)E_DIM * E_DIM)
         : widx == 2 ? wvT : woT;
  } else if (b < 49152) {
    int i = b - 16384;
    int widx = i >> 14, t_ = i & 16383;
    Kd = E_DIM; Nd = FFN_DIM;
    n0 = (t_ & 255) * 32; k0 = (t_ >> 8) * 32;
    W = widx ? w2 : w1;
    WT = widx ? w2T : w1T;
  } else {
    int t_ = b - 49152;
    Kd = FFN_DIM; Nd = E_DIM;
    n0 = (t_ & 63) * 32; k0 = (t_ >> 6) * 32;
    W = w3; WT = w3T;
  }
  int tx = threadIdx.x, ty = threadIdx.y;
#pragma unroll
  for (int i = 0; i < 4; i++)
    tile[ty + i * 8][tx] = W[(size_t)(k0 + ty + i * 8) * Nd + n0 + tx];
  __syncthreads();
#pragma unroll
  for (int i = 0; i < 4; i++)
    WT[(size_t)(n0 + ty + i * 8) * Kd + k0 + tx] = f2bf(tile[tx][ty + i * 8]);
}

// ------- transpose V: bf16 [B*T][E] -> [B][E][T] --------------------
__global__ __launch_bounds__(256) void transpose_v_kernel(const u16* __restrict__ v,
                                                          u16* __restrict__ vt) {
  __shared__ u16 tile[32][33];
  int tx = threadIdx.x, ty = threadIdx.y;
  int b = blockIdx.z;
  int t0 = blockIdx.x * 32, e0 = blockIdx.y * 32;
#pragma unroll
  for (int i = 0; i < 4; i++)
    tile[ty + i * 8][tx] =
        v[(size_t)(b * T_SEQ + t0 + ty + i * 8) * E_DIM + e0 + tx];
  __syncthreads();
#pragma unroll
  for (int i = 0; i < 4; i++)
    vt[((size_t)b * E_DIM + e0 + ty + i * 8) * T_SEQ + t0 + tx] = tile[tx][ty + i * 8];
}

// ------ add3: out += P0 + P1 (bf16 split-K partials) ----------------
__global__ __launch_bounds__(256) void add3_kernel(float* __restrict__ out,
                                                   const u16* __restrict__ pk) {
  const size_t MN = (size_t)M_ROWS * E_DIM;
  size_t base = ((size_t)blockIdx.x * 256 + threadIdx.x) * 8;
  short8 a = *(const short8*)(pk + base);
  short8 b = *(const short8*)(pk + MN + base);
  float4 o0 = *(float4*)(out + base), o1 = *(float4*)(out + base + 4);
  o0.x += bf2f((u16)a[0]) + bf2f((u16)b[0]);
  o0.y += bf2f((u16)a[1]) + bf2f((u16)b[1]);
  o0.z += bf2f((u16)a[2]) + bf2f((u16)b[2]);
  o0.w += bf2f((u16)a[3]) + bf2f((u16)b[3]);
  o1.x += bf2f((u16)a[4]) + bf2f((u16)b[4]);
  o1.y += bf2f((u16)a[5]) + bf2f((u16)b[5]);
  o1.z += bf2f((u16)a[6]) + bf2f((u16)b[6]);
  o1.w += bf2f((u16)a[7]) + bf2f((u16)b[7]);
  *(float4*)(out + base) = o0;
  *(float4*)(out + base + 4) = o1;
}

// ======= GEMM BM_x256xBK64, 8-phase schedule, paired-row LDS ========
// Round-10 structure (proven).  2-D XCD chunking; split-K via kz.
// MODE 0: bf16 C.  MODE 1: Cout(f32)=Extra(f32)+acc.
// MODE 2: Cout(bf16)=silu(Extra bf16)*acc.
// MODE 3: bf16 split-K partial at Cout + kz*M*N.
template <int MODE, int BM_>
__global__ __launch_bounds__(512, 1) void gemm8p(const u16* __restrict__ A,
                                                 const u16* __restrict__ BT,
                                                 void* __restrict__ Cout,
                                                 const void* __restrict__ Extra,
                                                 int N, int K, int lda, int ldb,
                                                 int CX, int CY) {
  constexpr int MM = BM_ / 64;
  constexpr int AUNIT = BM_ * 32;
  __shared__ u16 Abuf[4 * AUNIT];
  __shared__ u16 Bbuf[4 * 8192];
  const int t = threadIdx.x;
  const int w = t >> 6, l = t & 63, g = l >> 4, lq = l & 15;
  const int wm = w >> 2, wn = w & 3;

  const int bid = (blockIdx.z * gridDim.y + blockIdx.y) * gridDim.x + blockIdx.x;
  const int xcd = bid & 7, slot = bid >> 3;
  const int nchx = gridDim.x / CX;
  const int nchy = gridDim.y / CY;
  const int cpz = nchx * nchy;
  const int kz = xcd / cpz;
  const int cid = xcd % cpz;
  const int bx = (cid % nchx) * CX + (slot % CX);
  const int by = (cid / nchx) * CY + (slot / CX);
  const size_t bm = (size_t)by * BM_, bn = (size_t)bx * 256;
  const size_t koff = (size_t)kz * K;

  const int srcrow = ((l >> 3) << 1) | (l & 1);
  const int csrc = ((((l >> 1) & 3) ^ ((l >> 3) & 3)) << 3);
  const u16* aSrc = A + (bm + w * 16 + srcrow) * (size_t)lda + koff + csrc;
  const u16* bSrc = BT + (bn + w * 16 + srcrow) * (size_t)ldb + koff + csrc;
  const int rdoff = (((lq & 1) + 2 * (g ^ ((lq >> 1) & 3))) << 3);

#define STA8(DB, KS, TILE)                                                    \
  {                                                                           \
    u16* Ad = Abuf + (DB) * (2 * AUNIT) + (KS)*AUNIT + w * 512;               \
    const u16* as_ = aSrc + (size_t)(TILE)*64 + (KS)*32;                      \
    async16(Ad, as_);                                                         \
    if constexpr (BM_ == 256) async16(Ad + 4096, as_ + (size_t)128 * lda);    \
  }
#define STB8(DB, KS, TILE)                                                    \
  {                                                                           \
    u16* Bd = Bbuf + (DB)*16384 + (KS)*8192 + w * 512;                        \
    const u16* bs_ = bSrc + (size_t)(TILE)*64 + (KS)*32;                      \
    async16(Bd, bs_);                                                         \
    async16(Bd + 4096, bs_ + (size_t)128 * ldb);                              \
  }
#define RDA8(DB, KS, MH)                                                      \
  _Pragma("unroll") for (int mm = 0; mm < MM; ++mm)                           \
      af[mm] = *(const short8*)(Abuf + (DB) * (2 * AUNIT) + (KS)*AUNIT +      \
                                (wm * (BM_ / 4) + (MH) * (BM_ / 8) + mm * 8 + \
                                 (lq >> 1)) * 64 + rdoff);
#define RDB8(DB, KS)                                                          \
  _Pragma("unroll") for (int nn = 0; nn < 4; ++nn)                            \
      bf[nn] = *(const short8*)(Bbuf + (DB)*16384 + (KS)*8192 +               \
                                (wn * 32 + nn * 8 + (lq >> 1)) * 64 + rdoff);
#define MM168(MH)                                                             \
  _Pragma("unroll") for (int mm = 0; mm < MM; ++mm)                           \
      _Pragma("unroll") for (int nn = 0; nn < 4; ++nn)                        \
          acc[(MH)*MM + mm][nn] = __builtin_amdgcn_mfma_f32_16x16x32_bf16(    \
              af[mm], bf[nn], acc[(MH)*MM + mm][nn], 0, 0, 0);
#define SYNCA                                                                 \
  __builtin_amdgcn_s_barrier();                                               \
  asm volatile("s_waitcnt lgkmcnt(0)" ::: "memory");                          \
  __builtin_amdgcn_sched_barrier(0);                                          \
  __builtin_amdgcn_s_setprio(1);
#define ENDP __builtin_amdgcn_s_setprio(0);
#define BAR2 __builtin_amdgcn_s_barrier();
#define WAITN                                                                 \
  if constexpr (BM_ == 256) asm volatile("s_waitcnt vmcnt(8)" ::: "memory");  \
  else                      asm volatile("s_waitcnt vmcnt(6)" ::: "memory");
#define WAITH                                                                 \
  if constexpr (BM_ == 256) asm volatile("s_waitcnt vmcnt(4)" ::: "memory");  \
  else                      asm volatile("s_waitcnt vmcnt(3)" ::: "memory");

  const int NT = K >> 6, NI = NT >> 1;
  f32x4 acc[2 * MM][4] = {};
  short8 af[MM > 4 ? MM : 4], bf[4];

  STA8(0, 0, 0); STB8(0, 0, 0);
  STA8(0, 1, 0); STB8(0, 1, 0);
  STA8(1, 0, 1); STB8(1, 0, 1);
  WAITN;
  BAR2;

  for (int j = 0; j < NI; ++j) {
    const int t1 = 2 * j + 1, t2 = 2 * j + 2, t3 = 2 * j + 3;
    const bool s2 = t2 < NT, s3 = t3 < NT, lastI = (j + 1 == NI);
    RDB8(0, 0); RDA8(0, 0, 0);
    STA8(1, 1, t1);
    SYNCA; MM168(0); ENDP; BAR2;
    RDA8(0, 0, 1);
    STB8(1, 1, t1);
    SYNCA; MM168(1); ENDP;
    WAITN;
    BAR2;
    RDB8(0, 1); RDA8(0, 1, 0);
    if (s2) STA8(0, 0, t2);
    SYNCA; MM168(0); ENDP; BAR2;
    RDA8(0, 1, 1);
    if (s2) STB8(0, 0, t2);
    SYNCA; MM168(1); ENDP;
    if (lastI) { WAITH; } else { WAITN; }
    BAR2;
    RDB8(1, 0); RDA8(1, 0, 0);
    if (s2) STA8(0, 1, t2);
    SYNCA; MM168(0); ENDP; BAR2;
    RDA8(1, 0, 1);
    if (s2) STB8(0, 1, t2);
    SYNCA; MM168(1); ENDP;
    if (lastI) { asm volatile("s_waitcnt vmcnt(0)" ::: "memory"); } else { WAITN; }
    BAR2;
    RDB8(1, 1); RDA8(1, 1, 0);
    if (s3) STA8(1, 0, t3);
    SYNCA; MM168(0); ENDP; BAR2;
    RDA8(1, 1, 1);
    if (s3) STB8(1, 0, t3);
    SYNCA; MM168(1); ENDP;
    if (!lastI) { WAITN; }
    BAR2;
  }
#undef STA8
#undef STB8
#undef RDA8
#undef RDB8
#undef MM168
#undef SYNCA
#undef ENDP
#undef BAR2
#undef WAITN
#undef WAITH

  const size_t mn = (size_t)gridDim.y * BM_ * (size_t)N;
#pragma unroll
  for (int m = 0; m < 2 * MM; m++) {
    size_t row = bm + wm * (BM_ / 2) + m * 16 + 4 * g;
#pragma unroll
    for (int n = 0; n < 4; n++) {
      size_t col = bn + wn * 64 + n * 16 + lq;
#pragma unroll
      for (int r = 0; r < 4; r++) {
        size_t idx = (row + r) * (size_t)N + col;
        if constexpr (MODE == 0) {
          ((u16*)Cout)[idx] = f2bf(acc[m][n][r]);
        } else if constexpr (MODE == 1) {
          ((float*)Cout)[idx] = ((const float*)Extra)[idx] + acc[m][n][r];
        } else if constexpr (MODE == 2) {
          float a = bf2f(((const u16*)Extra)[idx]);
          float sil = a / (1.f + exp2f(-1.4426950408889634f * a));
          ((u16*)Cout)[idx] = f2bf(sil * acc[m][n][r]);
        } else {
          ((u16*)Cout)[(size_t)kz * mn + idx] = f2bf(acc[m][n][r]);
        }
      }
    }
  }
}

// ==== FUSED SwiGLU FFN GEMM: gated = silu(A@w1T^T) * (A@w2T^T) ======
__global__ __launch_bounds__(512, 1) void gemm_ffn(const u16* __restrict__ A,
                                                   const u16* __restrict__ B1T,
                                                   const u16* __restrict__ B2T,
                                                   u16* __restrict__ Cout,
                                                   int N, int K, int lda, int ldb,
                                                   int CX, int CY) {
  constexpr int AUNIT = 8192;
  __shared__ u16 Abuf[4 * AUNIT];
  __shared__ u16 Bbuf[4 * AUNIT];
  const int t = threadIdx.x;
  const int w = t >> 6, l = t & 63, g = l >> 4, lq = l & 15;
  const int wm = w >> 2, wn = w & 3;

  const int bid = blockIdx.y * gridDim.x + blockIdx.x;
  const int xcd = bid & 7, slot = bid >> 3;
  const int nchx = gridDim.x / CX;
  const int cid = xcd;
  const int bx = (cid % nchx) * CX + (slot % CX);
  const int by = (cid / nchx) * CY + (slot / CX);
  const size_t bm = (size_t)by * 256;
  const size_t c0 = (size_t)bx * 128;

  const int srcrow = ((l >> 3) << 1) | (l & 1);
  const int csrc = ((((l >> 1) & 3) ^ ((l >> 3) & 3)) << 3);
  const u16* aSrc = A + (bm + w * 16 + srcrow) * (size_t)lda + csrc;
  const u16* b1Src = B1T + (c0 + w * 16 + srcrow) * (size_t)ldb + csrc;
  const u16* b2Src = B2T + (c0 + w * 16 + srcrow) * (size_t)ldb + csrc;
  const int rdoff = (((lq & 1) + 2 * (g ^ ((lq >> 1) & 3))) << 3);

#define STA8(DB, KS, TILE)                                                    \
  {                                                                           \
    u16* Ad = Abuf + (DB) * (2 * AUNIT) + (KS)*AUNIT + w * 512;               \
    const u16* as_ = aSrc + (size_t)(TILE)*64 + (KS)*32;                      \
    async16(Ad, as_);                                                         \
    async16(Ad + 4096, as_ + (size_t)128 * lda);                              \
  }
#define STB8(DB, KS, TILE)                                                    \
  {                                                                           \
    u16* Bd = Bbuf + (DB) * (2 * AUNIT) + (KS)*AUNIT + w * 512;               \
    size_t off_ = (size_t)(TILE)*64 + (KS)*32;                                \
    async16(Bd, b1Src + off_);                                                \
    async16(Bd + 4096, b2Src + off_);                                         \
  }
#define RDA8(DB, KS, MH)                                                      \
  _Pragma("unroll") for (int mm = 0; mm < 4; ++mm)                            \
      af[mm] = *(const short8*)(Abuf + (DB) * (2 * AUNIT) + (KS)*AUNIT +      \
                                (wm * 64 + (MH)*32 + mm * 8 + (lq >> 1)) *    \
                                    64 + rdoff);
#define RDB8(DB, KS)                                                          \
  _Pragma("unroll") for (int nn = 0; nn < 4; ++nn)                            \
      bf[nn] = *(const short8*)(Bbuf + (DB) * (2 * AUNIT) + (KS)*AUNIT +      \
                                (wn * 32 + nn * 8 + (lq >> 1)) * 64 + rdoff);
#define MM168(MH)                                                             \
  _Pragma("unroll") for (int mm = 0; mm < 4; ++mm)                            \
      _Pragma("unroll") for (int nn = 0; nn < 4; ++nn)                        \
          acc[(MH)*4 + mm][nn] = __builtin_amdgcn_mfma_f32_16x16x32_bf16(     \
              af[mm], bf[nn], acc[(MH)*4 + mm][nn], 0, 0, 0);
#define SYNCA                                                                 \
  __builtin_amdgcn_s_barrier();                                               \
  asm volatile("s_waitcnt lgkmcnt(0)" ::: "memory");                          \
  __builtin_amdgcn_sched_barrier(0);                                          \
  __builtin_amdgcn_s_setprio(1);
#define ENDP __builtin_amdgcn_s_setprio(0);
#define BAR2 __builtin_amdgcn_s_barrier();
#define WAITN asm volatile("s_waitcnt vmcnt(8)" ::: "memory");
#define WAITH asm volatile("s_waitcnt vmcnt(4)" ::: "memory");

  const int NT = K >> 6, NI = NT >> 1;
  f32x4 acc[8][4] = {};
  short8 af[4], bf[4];

  STA8(0, 0, 0); STB8(0, 0, 0);
  STA8(0, 1, 0); STB8(0, 1, 0);
  STA8(1, 0, 1); STB8(1, 0, 1);
  WAITN;
  BAR2;

  for (int j = 0; j < NI; ++j) {
    const int t1 = 2 * j + 1, t2 = 2 * j + 2, t3 = 2 * j + 3;
    const bool s2 = t2 < NT, s3 = t3 < NT, lastI = (j + 1 == NI);
    RDB8(0, 0); RDA8(0, 0, 0);
    STA8(1, 1, t1);
    SYNCA; MM168(0); ENDP; BAR2;
    RDA8(0, 0, 1);
    STB8(1, 1, t1);
    SYNCA; MM168(1); ENDP;
    WAITN;
    BAR2;
    RDB8(0, 1); RDA8(0, 1, 0);
    if (s2) STA8(0, 0, t2);
    SYNCA; MM168(0); ENDP; BAR2;
    RDA8(0, 1, 1);
    if (s2) STB8(0, 0, t2);
    SYNCA; MM168(1); ENDP;
    if (lastI) { WAITH; } else { WAITN; }
    BAR2;
    RDB8(1, 0); RDA8(1, 0, 0);
    if (s2) STA8(0, 1, t2);
    SYNCA; MM168(0); ENDP; BAR2;
    RDA8(1, 0, 1);
    if (s2) STB8(0, 1, t2);
    SYNCA; MM168(1); ENDP;
    if (lastI) { asm volatile("s_waitcnt vmcnt(0)" ::: "memory"); } else { WAITN; }
    BAR2;
    RDB8(1, 1); RDA8(1, 1, 0);
    if (s3) STA8(1, 0, t3);
    SYNCA; MM168(0); ENDP; BAR2;
    RDA8(1, 1, 1);
    if (s3) STB8(1, 0, t3);
    SYNCA; MM168(1); ENDP;
    if (!lastI) { WAITN; }
    BAR2;
  }
#undef STA8
#undef STB8
#undef RDA8
#undef RDB8
#undef MM168
#undef SYNCA
#undef ENDP
#undef BAR2
#undef WAITN
#undef WAITH

  // ---- SwiGLU epilogue: exchange u2 via (dead) LDS, gate, store ----
  const int reg = wm * 2 + ((wn >= 2) ? (wn - 2) : wn);
  float* fb = (float*)((reg < 2 ? Abuf : Bbuf) + (reg & 1) * 16384);
  if (wn >= 2) {
#pragma unroll
    for (int m = 0; m < 8; m++)
#pragma unroll
      for (int n = 0; n < 4; n++)
#pragma unroll
        for (int r = 0; r < 4; r++) {
          int lrow = m * 16 + 4 * g + r;
          int pcol = (n * 16 + lq) ^ ((g & 1) << 4);
          fb[lrow * 64 + pcol] = acc[m][n][r];
        }
  }
  __syncthreads();
  if (wn < 2) {
#pragma unroll
    for (int m = 0; m < 8; m++) {
      size_t row = bm + wm * 128 + m * 16 + 4 * g;
#pragma unroll
      for (int n = 0; n < 4; n++) {
        size_t col = c0 + wn * 64 + n * 16 + lq;
#pragma unroll
        for (int r = 0; r < 4; r++) {
          int lrow = m * 16 + 4 * g + r;
          int pcol = (n * 16 + lq) ^ ((g & 1) << 4);
          float u1 = acc[m][n][r];
          float u2 = fb[lrow * 64 + pcol];
          float sil = u1 / (1.f + exp2f(-1.4426950408889634f * u1));
          Cout[(row + r) * (size_t)N + col] = f2bf(sil * u2);
        }
      }
    }
  }
}

// ----------------- causal flash attention (LDS-staged) --------------
// grid (T/128, B*H); 4 waves/block; wave owns 32 q-rows (2 rg of 16).
// Q,K from fused QK buffer [B*T][4096] (q cols 0..2047, k cols 2048+).
__global__ __launch_bounds__(256, 2) void attn_kernel(const u16* __restrict__ QK,
                                                      const u16* __restrict__ VT,
                                                      u16* __restrict__ CTX) {
  __shared__ u16 Ks[64 * 128];
  __shared__ u16 Vs[128 * 64];
  __shared__ u16 P_all[4][32 * 72];
  const int t = threadIdx.x;
  const int w = t >> 6, l = t & 63, g = l >> 4, lq = l & 15;
  u16* P = P_all[w];
  const int q0blk = blockIdx.x * 128;
  const int q0w = q0blk + w * 32;
  const int bh = blockIdx.y, b = bh >> 4, h = bh & 15;
  const u16* qp = QK + (size_t)b * T_SEQ * QKS + h * D_HEAD;
  const u16* kp = qp + E_DIM;
  const u16* vp = VT + ((size_t)b * E_DIM + h * D_HEAD) * T_SEQ;

  short8 qf[2][4];
#pragma unroll
  for (int rg = 0; rg < 2; rg++)
#pragma unroll
    for (int ks = 0; ks < 4; ks++)
      qf[rg][ks] =
          *(const short8*)(qp + (size_t)(q0w + rg * 16 + lq) * QKS + ks * 32 + g * 8);

  f32x4 acc[2][8] = {};
  float m2[2][4], ls[2][4];
#pragma unroll
  for (int rg = 0; rg < 2; rg++)
#pragma unroll
    for (int r = 0; r < 4; r++) { m2[rg][r] = -1e30f; ls[rg][r] = 0.f; }
  const float sc = 0.08838834764831845f * 1.4426950408889634f;

  const int kRow0 = 16 * w + (l >> 4);
  const int kChunk = l & 15;
  const int vRow0 = 32 * w + (l >> 3);
  const int vChunk = l & 7;

  for (int kv0 = 0; kv0 < q0blk + 128; kv0 += 64) {
#pragma unroll
    for (int j = 0; j < 4; j++) {
      int R = kRow0 + 4 * j;
      async16(Ks + (16 * w + 4 * j) * 128,
              kp + (size_t)(kv0 + R) * QKS + ((kChunk ^ (R & 7)) << 3));
    }
#pragma unroll
    for (int j = 0; j < 4; j++) {
      int D = vRow0 + 8 * j;
      async16(Vs + (32 * w + 8 * j) * 64,
              vp + (size_t)D * T_SEQ + kv0 + ((vChunk ^ (D & 7)) << 3));
    }
    __syncthreads();

#pragma unroll
    for (int rg = 0; rg < 2; rg++) {
      const int rb = q0w + rg * 16;
      if (kv0 > rb + 15) continue;
      f32x4 s[4];
      __builtin_amdgcn_s_setprio(1);
#pragma unroll
      for (int ct = 0; ct < 4; ct++) {
        s[ct] = f32x4{0.f, 0.f, 0.f, 0.f};
#pragma unroll
        for (int ks = 0; ks < 4; ks++) {
          short8 kf = *(const short8*)(Ks + (ct * 16 + lq) * 128 +
                                       (((ks * 4 + g) ^ (lq & 7)) << 3));
          s[ct] = __builtin_amdgcn_mfma_f32_16x16x32_bf16(qf[rg][ks], kf, s[ct], 0, 0, 0);
        }
      }
      __builtin_amdgcn_s_setprio(0);
      float sv[4][4];
#pragma unroll
      for (int ct = 0; ct < 4; ct++)
#pragma unroll
        for (int r = 0; r < 4; r++) sv[ct][r] = s[ct][r] * sc;
      if (kv0 + 64 > rb) {
#pragma unroll
        for (int ct = 0; ct < 4; ct++)
#pragma unroll
          for (int r = 0; r < 4; r++)
            if (kv0 + ct * 16 + lq > rb + 4 * g + r) sv[ct][r] = -1e30f;
      }
      float mx[4];
#pragma unroll
      for (int r = 0; r < 4; r++)
        mx[r] = fmaxf(fmaxf(sv[0][r], sv[1][r]), fmaxf(sv[2][r], sv[3][r]));
#pragma unroll
      for (int off = 1; off < 16; off <<= 1)
#pragma unroll
        for (int r = 0; r < 4; r++) mx[r] = fmaxf(mx[r], __shfl_xor(mx[r], off));
#pragma unroll
      for (int r = 0; r < 4; r++) {
        float mn = fmaxf(m2[rg][r], mx[r]);
        float sca = exp2f(m2[rg][r] - mn);
        m2[rg][r] = mn;
        float sum = 0.f;
#pragma unroll
        for (int ct = 0; ct < 4; ct++) {
          float pv = exp2f(sv[ct][r] - mn);
          sum += pv;
          P[(rg * 16 + 4 * g + r) * 72 + ct * 16 + lq] = f2bf(pv);
        }
        ls[rg][r] = ls[rg][r] * sca + sum;
#pragma unroll
        for (int n = 0; n < 8; n++) acc[rg][n][r] *= sca;
      }
      short8 pa[2];
#pragma unroll
      for (int ks2 = 0; ks2 < 2; ks2++)
        pa[ks2] = *(const short8*)(P + (rg * 16 + lq) * 72 + ks2 * 32 + g * 8);
      __builtin_amdgcn_s_setprio(1);
#pragma unroll
      for (int n = 0; n < 8; n++)
#pragma unroll
        for (int ks2 = 0; ks2 < 2; ks2++) {
          short8 vf = *(const short8*)(Vs + (n * 16 + lq) * 64 +
                                       (((ks2 * 4 + g) ^ (lq & 7)) << 3));
          acc[rg][n] = __builtin_amdgcn_mfma_f32_16x16x32_bf16(pa[ks2], vf, acc[rg][n], 0, 0, 0);
        }
      __builtin_amdgcn_s_setprio(0);
    }
    __syncthreads();
  }

#pragma unroll
  for (int rg = 0; rg < 2; rg++) {
#pragma unroll
    for (int off = 1; off < 16; off <<= 1)
#pragma unroll
      for (int r = 0; r < 4; r++) ls[rg][r] += __shfl_xor(ls[rg][r], off);
  }
  u16* cp = CTX + ((size_t)b * T_SEQ + q0w) * E_DIM + h * D_HEAD;
#pragma unroll
  for (int rg = 0; rg < 2; rg++) {
    float inv[4];
#pragma unroll
    for (int r = 0; r < 4; r++) inv[r] = 1.f / ls[rg][r];
#pragma unroll
    for (int n = 0; n < 8; n++)
#pragma unroll
      for (int r = 0; r < 4; r++)
        cp[(size_t)(rg * 16 + 4 * g + r) * E_DIM + n * 16 + lq] =
            f2bf(acc[rg][n][r] * inv[r]);
  }
}

extern "C" void kernel_launch(void* const* d_in, const int* in_sizes, int n_in,
                              void* d_out, int out_size, void* d_ws, size_t ws_size,
                              hipStream_t stream) {
  (void)in_sizes; (void)n_in; (void)out_size; (void)ws_size;
  const float* x  = (const float*)d_in[0];
  const float* g1 = (const float*)d_in[1];
  const float* b1 = (const float*)d_in[2];
  const float* wq = (const float*)d_in[3];
  const float* wk = (const float*)d_in[4];
  const float* wv = (const float*)d_in[5];
  const float* wo = (const float*)d_in[6];
  const float* g2 = (const float*)d_in[7];
  const float* b2 = (const float*)d_in[8];
  const float* w1 = (const float*)d_in[9];
  const float* w2 = (const float*)d_in[10];
  const float* w3 = (const float*)d_in[11];
  float* out = (float*)d_out;

  const size_t EE = (size_t)E_DIM * E_DIM;
  const size_t EE2 = EE * 2;
  const size_t EF2 = (size_t)E_DIM * FFN_DIM * 2;
  const size_t ME2 = (size_t)M_ROWS * E_DIM * 2;
  char* p = (char*)d_ws;
  u16* wqkT = (u16*)p; p += 2 * EE2;   // [2E][E]: rows 0..E-1 = wq^T
  u16* wvT = (u16*)p; p += EE2;
  u16* woT = (u16*)p; p += EE2;
  u16* w1T = (u16*)p; p += EF2;
  u16* w2T = (u16*)p; p += EF2;
  u16* w3T = (u16*)p; p += EF2;
  u16* Hb  = (u16*)p; p += ME2;
  u16* QKb = (u16*)p; p += (size_t)M_ROWS * QKS * 2;  // [4096][4096]
  u16* Vb  = (u16*)p; p += ME2;
  u16* VTb = (u16*)p; p += ME2;
  u16* CTXb = (u16*)p; p += ME2;
  u16* U1b = QKb;   // gated (67MB) reuses QKb+Vb+VTb
  u16* Pk = wqkT;   // w3 split-K bf16 partials (33.55MB; wqkT dead by w3)

  dim3 blk32(32, 8);
  // ALL weights -> bf16 transposed, one dispatch (65536 blocks)
  cvt_all_kernel<<<65536, blk32, 0, stream>>>(wq, wk, wv, wo, w1, w2, w3,
                                              wqkT, wvT, woT, w1T, w2T, w3T);

  // attention block
  ln_kernel<<<M_ROWS, 256, 0, stream>>>(x, g1, b1, Hb);
  // fused QK GEMM at BM256: grid (16,16) = 256 blocks; chunk 4x8
  gemm8p<0, 256><<<dim3(QKS / 256, M_ROWS / 256), 512, 0, stream>>>(
      Hb, wqkT, QKb, nullptr, QKS, E_DIM, E_DIM, E_DIM, 4, 8);
  // V GEMM at BM128: grid (8,32) = 256 blocks; chunk 4x8
  gemm8p<0, 128><<<dim3(E_DIM / 256, M_ROWS / 128), 512, 0, stream>>>(
      Hb, wvT, Vb, nullptr, E_DIM, E_DIM, E_DIM, E_DIM, 4, 8);
  transpose_v_kernel<<<dim3(T_SEQ / 32, E_DIM / 32, 2), blk32, 0, stream>>>(Vb, VTb);
  attn_kernel<<<dim3(T_SEQ / 128, 2 * N_HEAD), 256, 0, stream>>>(QKb, VTb, CTXb);
  // WO: BM128, grid (8,32); chunk 4x8
  gemm8p<1, 128><<<dim3(E_DIM / 256, M_ROWS / 128), 512, 0, stream>>>(
      CTXb, woT, out, x, E_DIM, E_DIM, E_DIM, E_DIM, 4, 8);

  // SwiGLU MLP block
  ln_kernel<<<M_ROWS, 256, 0, stream>>>(out, g2, b2, Hb);
  // fused FFN1+FFN2+silu-gate: grid (64,16) = 1024 blocks; chunk 16x8
  gemm_ffn<<<dim3(FFN_DIM / 128, M_ROWS / 256), 512, 0, stream>>>(
      Hb, w1T, w2T, U1b, FFN_DIM, E_DIM, E_DIM, E_DIM, 16, 8);
  // w3: BM256 split-K=2: grid (8,16,2) = 256 blocks; chunk 4x8 per kz
  gemm8p<3, 256><<<dim3(E_DIM / 256, M_ROWS / 256, 2), 512, 0, stream>>>(
      U1b, w3T, Pk, nullptr, E_DIM, FFN_DIM / 2, FFN_DIM, FFN_DIM, 4, 8);
  add3_kernel<<<4096, 256, 0, stream>>>(out, Pk);
}

// Round 19
// 847.810 us; speedup vs baseline: 1.2745x; 1.0326x over previous
//
#include <hip/hip_runtime.h>

// Transformer layer, bf16 MFMA compute, fp32 I/O.
// B=2 T=2048 E=2048 H=16 DH=128 FFN=8192. Needs ~256MB workspace.

#define T_SEQ 2048
#define E_DIM 2048
#define N_HEAD 16
#define D_HEAD 128
#define FFN_DIM 8192
#define M_ROWS 4096  // B*T
#define QKS (2 * E_DIM)  // fused QK output row stride

typedef unsigned short u16;
typedef short short8 __attribute__((ext_vector_type(8)));
typedef float f32x4 __attribute__((ext_vector_type(4)));

#define DEV __device__ __forceinline__

DEV u16 f2bf(float f) {
  unsigned u = __float_as_uint(f);
  u += 0x7fffu + ((u >> 16) & 1u);
  return (u16)(u >> 16);
}
DEV float bf2f(u16 h) { return __uint_as_float(((unsigned)h) << 16); }

DEV void async16(void* lds, const void* g) {
  __builtin_amdgcn_global_load_lds((const __attribute__((address_space(1))) void*)g,
                                   (__attribute__((address_space(3))) void*)lds, 16, 0, 0);
}

// ---------------- LayerNorm: fp32 [rows][E] -> bf16 -----------------
__global__ __launch_bounds__(256) void ln_kernel(const float* __restrict__ x,
                                                 const float* __restrict__ gw,
                                                 const float* __restrict__ bw,
                                                 u16* __restrict__ out) {
  int row = blockIdx.x;
  int t = threadIdx.x;
  const float4* xr = (const float4*)(x + (size_t)row * E_DIM);
  float4 a = xr[t], c = xr[t + 256];
  float s = a.x + a.y + a.z + a.w + c.x + c.y + c.z + c.w;
  float q = a.x * a.x + a.y * a.y + a.z * a.z + a.w * a.w +
            c.x * c.x + c.y * c.y + c.z * c.z + c.w * c.w;
  for (int off = 32; off > 0; off >>= 1) {
    s += __shfl_down(s, off);
    q += __shfl_down(q, off);
  }
  __shared__ float red[8];
  if ((t & 63) == 0) { red[(t >> 6) * 2] = s; red[(t >> 6) * 2 + 1] = q; }
  __syncthreads();
  s = red[0] + red[2] + red[4] + red[6];
  q = red[1] + red[3] + red[5] + red[7];
  float mu = s * (1.f / E_DIM);
  float rs = rsqrtf(q * (1.f / E_DIM) - mu * mu + 1e-5f);
  const float4* g4 = (const float4*)gw;
  const float4* b4 = (const float4*)bw;
  float4 g0 = g4[t], g1v = g4[t + 256], e0 = b4[t], e1 = b4[t + 256];
  ushort4 o0, o1;
  o0.x = f2bf((a.x - mu) * rs * g0.x + e0.x);
  o0.y = f2bf((a.y - mu) * rs * g0.y + e0.y);
  o0.z = f2bf((a.z - mu) * rs * g0.z + e0.z);
  o0.w = f2bf((a.w - mu) * rs * g0.w + e0.w);
  o1.x = f2bf((c.x - mu) * rs * g1v.x + e1.x);
  o1.y = f2bf((c.y - mu) * rs * g1v.y + e1.y);
  o1.z = f2bf((c.z - mu) * rs * g1v.z + e1.z);
  o1.w = f2bf((c.w - mu) * rs * g1v.w + e1.w);
  ((ushort4*)(out + (size_t)row * E_DIM))[t] = o0;
  ((ushort4*)(out + (size_t)row * E_DIM))[t + 256] = o1;
}

// ==== ALL-weights convert+transpose in ONE dispatch =================
// block ranges: [0,16384): wq/wk/wv/wo (4096 tiles each);
// [16384,49152): w1/w2 (16384 each); [49152,65536): w3.
__global__ __launch_bounds__(256) void cvt_all_kernel(
    const float* __restrict__ wq, const float* __restrict__ wk,
    const float* __restrict__ wv, const float* __restrict__ wo,
    const float* __restrict__ w1, const float* __restrict__ w2,
    const float* __restrict__ w3, u16* __restrict__ wqkT,
    u16* __restrict__ wvT, u16* __restrict__ woT, u16* __restrict__ w1T,
    u16* __restrict__ w2T, u16* __restrict__ w3T) {
  __shared__ float tile[32][33];
  const int b = blockIdx.x;
  const float* W;
  u16* WT;
  int Kd, Nd, n0, k0;
  if (b < 16384) {
    int widx = b >> 12, t_ = b & 4095;
    Kd = E_DIM; Nd = E_DIM;
    n0 = (t_ & 63) * 32; k0 = (t_ >> 6) * 32;
    W = widx == 0 ? wq : widx == 1 ? wk : widx == 2 ? wv : wo;
    WT = widx == 0 ? wqkT
         : widx == 1 ? (wqkT + (size_t)E_DIM * E_DIM)
         : widx == 2 ? wvT : woT;
  } else if (b < 49152) {
    int i = b - 16384;
    int widx = i >> 14, t_ = i & 16383;
    Kd = E_DIM; Nd = FFN_DIM;
    n0 = (t_ & 255) * 32; k0 = (t_ >> 8) * 32;
    W = widx ? w2 : w1;
    WT = widx ? w2T : w1T;
  } else {
    int t_ = b - 49152;
    Kd = FFN_DIM; Nd = E_DIM;
    n0 = (t_ & 63) * 32; k0 = (t_ >> 6) * 32;
    W = w3; WT = w3T;
  }
  int tx = threadIdx.x, ty = threadIdx.y;
#pragma unroll
  for (int i = 0; i < 4; i++)
    tile[ty + i * 8][tx] = W[(size_t)(k0 + ty + i * 8) * Nd + n0 + tx];
  __syncthreads();
#pragma unroll
  for (int i = 0; i < 4; i++)
    WT[(size_t)(n0 + ty + i * 8) * Kd + k0 + tx] = f2bf(tile[tx][ty + i * 8]);
}

// ------- transpose V: bf16 [B*T][E] -> [B][E][T] --------------------
__global__ __launch_bounds__(256) void transpose_v_kernel(const u16* __restrict__ v,
                                                          u16* __restrict__ vt) {
  __shared__ u16 tile[32][33];
  int tx = threadIdx.x, ty = threadIdx.y;
  int b = blockIdx.z;
  int t0 = blockIdx.x * 32, e0 = blockIdx.y * 32;
#pragma unroll
  for (int i = 0; i < 4; i++)
    tile[ty + i * 8][tx] =
        v[(size_t)(b * T_SEQ + t0 + ty + i * 8) * E_DIM + e0 + tx];
  __syncthreads();
#pragma unroll
  for (int i = 0; i < 4; i++)
    vt[((size_t)b * E_DIM + e0 + ty + i * 8) * T_SEQ + t0 + tx] = tile[tx][ty + i * 8];
}

// ------ add3: out += P0 + P1 (bf16 split-K partials) ----------------
__global__ __launch_bounds__(256) void add3_kernel(float* __restrict__ out,
                                                   const u16* __restrict__ pk) {
  const size_t MN = (size_t)M_ROWS * E_DIM;
  size_t base = ((size_t)blockIdx.x * 256 + threadIdx.x) * 8;
  short8 a = *(const short8*)(pk + base);
  short8 b = *(const short8*)(pk + MN + base);
  float4 o0 = *(float4*)(out + base), o1 = *(float4*)(out + base + 4);
  o0.x += bf2f((u16)a[0]) + bf2f((u16)b[0]);
  o0.y += bf2f((u16)a[1]) + bf2f((u16)b[1]);
  o0.z += bf2f((u16)a[2]) + bf2f((u16)b[2]);
  o0.w += bf2f((u16)a[3]) + bf2f((u16)b[3]);
  o1.x += bf2f((u16)a[4]) + bf2f((u16)b[4]);
  o1.y += bf2f((u16)a[5]) + bf2f((u16)b[5]);
  o1.z += bf2f((u16)a[6]) + bf2f((u16)b[6]);
  o1.w += bf2f((u16)a[7]) + bf2f((u16)b[7]);
  *(float4*)(out + base) = o0;
  *(float4*)(out + base + 4) = o1;
}

// ======= GEMM BM_x256xBK64, 8-phase schedule, paired-row LDS ========
// Round-10 structure (proven).  2-D XCD chunking; split-K via kz.
// MODE 0: bf16 C.  MODE 1: Cout(f32)=Extra(f32)+acc.
// MODE 2: Cout(bf16)=silu(Extra bf16)*acc.
// MODE 3: bf16 split-K partial at Cout + kz*M*N.
template <int MODE, int BM_>
__global__ __launch_bounds__(512, 1) void gemm8p(const u16* __restrict__ A,
                                                 const u16* __restrict__ BT,
                                                 void* __restrict__ Cout,
                                                 const void* __restrict__ Extra,
                                                 int N, int K, int lda, int ldb,
                                                 int CX, int CY) {
  constexpr int MM = BM_ / 64;
  constexpr int AUNIT = BM_ * 32;
  __shared__ u16 Abuf[4 * AUNIT];
  __shared__ u16 Bbuf[4 * 8192];
  const int t = threadIdx.x;
  const int w = t >> 6, l = t & 63, g = l >> 4, lq = l & 15;
  const int wm = w >> 2, wn = w & 3;

  const int bid = (blockIdx.z * gridDim.y + blockIdx.y) * gridDim.x + blockIdx.x;
  const int xcd = bid & 7, slot = bid >> 3;
  const int nchx = gridDim.x / CX;
  const int nchy = gridDim.y / CY;
  const int cpz = nchx * nchy;
  const int kz = xcd / cpz;
  const int cid = xcd % cpz;
  const int bx = (cid % nchx) * CX + (slot % CX);
  const int by = (cid / nchx) * CY + (slot / CX);
  const size_t bm = (size_t)by * BM_, bn = (size_t)bx * 256;
  const size_t koff = (size_t)kz * K;

  const int srcrow = ((l >> 3) << 1) | (l & 1);
  const int csrc = ((((l >> 1) & 3) ^ ((l >> 3) & 3)) << 3);
  const u16* aSrc = A + (bm + w * 16 + srcrow) * (size_t)lda + koff + csrc;
  const u16* bSrc = BT + (bn + w * 16 + srcrow) * (size_t)ldb + koff + csrc;
  const int rdoff = (((lq & 1) + 2 * (g ^ ((lq >> 1) & 3))) << 3);

#define STA8(DB, KS, TILE)                                                    \
  {                                                                           \
    u16* Ad = Abuf + (DB) * (2 * AUNIT) + (KS)*AUNIT + w * 512;               \
    const u16* as_ = aSrc + (size_t)(TILE)*64 + (KS)*32;                      \
    async16(Ad, as_);                                                         \
    if constexpr (BM_ == 256) async16(Ad + 4096, as_ + (size_t)128 * lda);    \
  }
#define STB8(DB, KS, TILE)                                                    \
  {                                                                           \
    u16* Bd = Bbuf + (DB)*16384 + (KS)*8192 + w * 512;                        \
    const u16* bs_ = bSrc + (size_t)(TILE)*64 + (KS)*32;                      \
    async16(Bd, bs_);                                                         \
    async16(Bd + 4096, bs_ + (size_t)128 * ldb);                              \
  }
#define RDA8(DB, KS, MH)                                                      \
  _Pragma("unroll") for (int mm = 0; mm < MM; ++mm)                           \
      af[mm] = *(const short8*)(Abuf + (DB) * (2 * AUNIT) + (KS)*AUNIT +      \
                                (wm * (BM_ / 4) + (MH) * (BM_ / 8) + mm * 8 + \
                                 (lq >> 1)) * 64 + rdoff);
#define RDB8(DB, KS)                                                          \
  _Pragma("unroll") for (int nn = 0; nn < 4; ++nn)                            \
      bf[nn] = *(const short8*)(Bbuf + (DB)*16384 + (KS)*8192 +               \
                                (wn * 32 + nn * 8 + (lq >> 1)) * 64 + rdoff);
#define MM168(MH)                                                             \
  _Pragma("unroll") for (int mm = 0; mm < MM; ++mm)                           \
      _Pragma("unroll") for (int nn = 0; nn < 4; ++nn)                        \
          acc[(MH)*MM + mm][nn] = __builtin_amdgcn_mfma_f32_16x16x32_bf16(    \
              af[mm], bf[nn], acc[(MH)*MM + mm][nn], 0, 0, 0);
#define SYNCA                                                                 \
  __builtin_amdgcn_s_barrier();                                               \
  asm volatile("s_waitcnt lgkmcnt(0)" ::: "memory");                          \
  __builtin_amdgcn_sched_barrier(0);                                          \
  __builtin_amdgcn_s_setprio(1);
#define ENDP __builtin_amdgcn_s_setprio(0);
#define BAR2 __builtin_amdgcn_s_barrier();
#define WAITN                                                                 \
  if constexpr (BM_ == 256) asm volatile("s_waitcnt vmcnt(8)" ::: "memory");  \
  else                      asm volatile("s_waitcnt vmcnt(6)" ::: "memory");
#define WAITH                                                                 \
  if constexpr (BM_ == 256) asm volatile("s_waitcnt vmcnt(4)" ::: "memory");  \
  else                      asm volatile("s_waitcnt vmcnt(3)" ::: "memory");

  const int NT = K >> 6, NI = NT >> 1;
  f32x4 acc[2 * MM][4] = {};
  short8 af[MM > 4 ? MM : 4], bf[4];

  STA8(0, 0, 0); STB8(0, 0, 0);
  STA8(0, 1, 0); STB8(0, 1, 0);
  STA8(1, 0, 1); STB8(1, 0, 1);
  WAITN;
  BAR2;

  for (int j = 0; j < NI; ++j) {
    const int t1 = 2 * j + 1, t2 = 2 * j + 2, t3 = 2 * j + 3;
    const bool s2 = t2 < NT, s3 = t3 < NT, lastI = (j + 1 == NI);
    RDB8(0, 0); RDA8(0, 0, 0);
    STA8(1, 1, t1);
    SYNCA; MM168(0); ENDP; BAR2;
    RDA8(0, 0, 1);
    STB8(1, 1, t1);
    SYNCA; MM168(1); ENDP;
    WAITN;
    BAR2;
    RDB8(0, 1); RDA8(0, 1, 0);
    if (s2) STA8(0, 0, t2);
    SYNCA; MM168(0); ENDP; BAR2;
    RDA8(0, 1, 1);
    if (s2) STB8(0, 0, t2);
    SYNCA; MM168(1); ENDP;
    if (lastI) { WAITH; } else { WAITN; }
    BAR2;
    RDB8(1, 0); RDA8(1, 0, 0);
    if (s2) STA8(0, 1, t2);
    SYNCA; MM168(0); ENDP; BAR2;
    RDA8(1, 0, 1);
    if (s2) STB8(0, 1, t2);
    SYNCA; MM168(1); ENDP;
    if (lastI) { asm volatile("s_waitcnt vmcnt(0)" ::: "memory"); } else { WAITN; }
    BAR2;
    RDB8(1, 1); RDA8(1, 1, 0);
    if (s3) STA8(1, 0, t3);
    SYNCA; MM168(0); ENDP; BAR2;
    RDA8(1, 1, 1);
    if (s3) STB8(1, 0, t3);
    SYNCA; MM168(1); ENDP;
    if (!lastI) { WAITN; }
    BAR2;
  }
#undef STA8
#undef STB8
#undef RDA8
#undef RDB8
#undef MM168
#undef SYNCA
#undef ENDP
#undef BAR2
#undef WAITN
#undef WAITH

  const size_t mn = (size_t)gridDim.y * BM_ * (size_t)N;
#pragma unroll
  for (int m = 0; m < 2 * MM; m++) {
    size_t row = bm + wm * (BM_ / 2) + m * 16 + 4 * g;
#pragma unroll
    for (int n = 0; n < 4; n++) {
      size_t col = bn + wn * 64 + n * 16 + lq;
#pragma unroll
      for (int r = 0; r < 4; r++) {
        size_t idx = (row + r) * (size_t)N + col;
        if constexpr (MODE == 0) {
          ((u16*)Cout)[idx] = f2bf(acc[m][n][r]);
        } else if constexpr (MODE == 1) {
          ((float*)Cout)[idx] = ((const float*)Extra)[idx] + acc[m][n][r];
        } else if constexpr (MODE == 2) {
          float a = bf2f(((const u16*)Extra)[idx]);
          float sil = a / (1.f + exp2f(-1.4426950408889634f * a));
          ((u16*)Cout)[idx] = f2bf(sil * acc[m][n][r]);
        } else {
          ((u16*)Cout)[(size_t)kz * mn + idx] = f2bf(acc[m][n][r]);
        }
      }
    }
  }
}

// ==== FUSED SwiGLU FFN GEMM: gated = silu(A@w1T^T) * (A@w2T^T) ======
__global__ __launch_bounds__(512, 1) void gemm_ffn(const u16* __restrict__ A,
                                                   const u16* __restrict__ B1T,
                                                   const u16* __restrict__ B2T,
                                                   u16* __restrict__ Cout,
                                                   int N, int K, int lda, int ldb,
                                                   int CX, int CY) {
  constexpr int AUNIT = 8192;
  __shared__ u16 Abuf[4 * AUNIT];
  __shared__ u16 Bbuf[4 * AUNIT];
  const int t = threadIdx.x;
  const int w = t >> 6, l = t & 63, g = l >> 4, lq = l & 15;
  const int wm = w >> 2, wn = w & 3;

  const int bid = blockIdx.y * gridDim.x + blockIdx.x;
  const int xcd = bid & 7, slot = bid >> 3;
  const int nchx = gridDim.x / CX;
  const int cid = xcd;
  const int bx = (cid % nchx) * CX + (slot % CX);
  const int by = (cid / nchx) * CY + (slot / CX);
  const size_t bm = (size_t)by * 256;
  const size_t c0 = (size_t)bx * 128;

  const int srcrow = ((l >> 3) << 1) | (l & 1);
  const int csrc = ((((l >> 1) & 3) ^ ((l >> 3) & 3)) << 3);
  const u16* aSrc = A + (bm + w * 16 + srcrow) * (size_t)lda + csrc;
  const u16* b1Src = B1T + (c0 + w * 16 + srcrow) * (size_t)ldb + csrc;
  const u16* b2Src = B2T + (c0 + w * 16 + srcrow) * (size_t)ldb + csrc;
  const int rdoff = (((lq & 1) + 2 * (g ^ ((lq >> 1) & 3))) << 3);

#define STA8(DB, KS, TILE)                                                    \
  {                                                                           \
    u16* Ad = Abuf + (DB) * (2 * AUNIT) + (KS)*AUNIT + w * 512;               \
    const u16* as_ = aSrc + (size_t)(TILE)*64 + (KS)*32;                      \
    async16(Ad, as_);                                                         \
    async16(Ad + 4096, as_ + (size_t)128 * lda);                              \
  }
#define STB8(DB, KS, TILE)                                                    \
  {                                                                           \
    u16* Bd = Bbuf + (DB) * (2 * AUNIT) + (KS)*AUNIT + w * 512;               \
    size_t off_ = (size_t)(TILE)*64 + (KS)*32;                                \
    async16(Bd, b1Src + off_);                                                \
    async16(Bd + 4096, b2Src + off_);                                         \
  }
#define RDA8(DB, KS, MH)                                                      \
  _Pragma("unroll") for (int mm = 0; mm < 4; ++mm)                            \
      af[mm] = *(const short8*)(Abuf + (DB) * (2 * AUNIT) + (KS)*AUNIT +      \
                                (wm * 64 + (MH)*32 + mm * 8 + (lq >> 1)) *    \
                                    64 + rdoff);
#define RDB8(DB, KS)                                                          \
  _Pragma("unroll") for (int nn = 0; nn < 4; ++nn)                            \
      bf[nn] = *(const short8*)(Bbuf + (DB) * (2 * AUNIT) + (KS)*AUNIT +      \
                                (wn * 32 + nn * 8 + (lq >> 1)) * 64 + rdoff);
#define MM168(MH)                                                             \
  _Pragma("unroll") for (int mm = 0; mm < 4; ++mm)                            \
      _Pragma("unroll") for (int nn = 0; nn < 4; ++nn)                        \
          acc[(MH)*4 + mm][nn] = __builtin_amdgcn_mfma_f32_16x16x32_bf16(     \
              af[mm], bf[nn], acc[(MH)*4 + mm][nn], 0, 0, 0);
#define SYNCA                                                                 \
  __builtin_amdgcn_s_barrier();                                               \
  asm volatile("s_waitcnt lgkmcnt(0)" ::: "memory");                          \
  __builtin_amdgcn_sched_barrier(0);                                          \
  __builtin_amdgcn_s_setprio(1);
#define ENDP __builtin_amdgcn_s_setprio(0);
#define BAR2 __builtin_amdgcn_s_barrier();
#define WAITN asm volatile("s_waitcnt vmcnt(8)" ::: "memory");
#define WAITH asm volatile("s_waitcnt vmcnt(4)" ::: "memory");

  const int NT = K >> 6, NI = NT >> 1;
  f32x4 acc[8][4] = {};
  short8 af[4], bf[4];

  STA8(0, 0, 0); STB8(0, 0, 0);
  STA8(0, 1, 0); STB8(0, 1, 0);
  STA8(1, 0, 1); STB8(1, 0, 1);
  WAITN;
  BAR2;

  for (int j = 0; j < NI; ++j) {
    const int t1 = 2 * j + 1, t2 = 2 * j + 2, t3 = 2 * j + 3;
    const bool s2 = t2 < NT, s3 = t3 < NT, lastI = (j + 1 == NI);
    RDB8(0, 0); RDA8(0, 0, 0);
    STA8(1, 1, t1);
    SYNCA; MM168(0); ENDP; BAR2;
    RDA8(0, 0, 1);
    STB8(1, 1, t1);
    SYNCA; MM168(1); ENDP;
    WAITN;
    BAR2;
    RDB8(0, 1); RDA8(0, 1, 0);
    if (s2) STA8(0, 0, t2);
    SYNCA; MM168(0); ENDP; BAR2;
    RDA8(0, 1, 1);
    if (s2) STB8(0, 0, t2);
    SYNCA; MM168(1); ENDP;
    if (lastI) { WAITH; } else { WAITN; }
    BAR2;
    RDB8(1, 0); RDA8(1, 0, 0);
    if (s2) STA8(0, 1, t2);
    SYNCA; MM168(0); ENDP; BAR2;
    RDA8(1, 0, 1);
    if (s2) STB8(0, 1, t2);
    SYNCA; MM168(1); ENDP;
    if (lastI) { asm volatile("s_waitcnt vmcnt(0)" ::: "memory"); } else { WAITN; }
    BAR2;
    RDB8(1, 1); RDA8(1, 1, 0);
    if (s3) STA8(1, 0, t3);
    SYNCA; MM168(0); ENDP; BAR2;
    RDA8(1, 1, 1);
    if (s3) STB8(1, 0, t3);
    SYNCA; MM168(1); ENDP;
    if (!lastI) { WAITN; }
    BAR2;
  }
#undef STA8
#undef STB8
#undef RDA8
#undef RDB8
#undef MM168
#undef SYNCA
#undef ENDP
#undef BAR2
#undef WAITN
#undef WAITH

  // ---- SwiGLU epilogue: exchange u2 via (dead) LDS, gate, store ----
  const int reg = wm * 2 + ((wn >= 2) ? (wn - 2) : wn);
  float* fb = (float*)((reg < 2 ? Abuf : Bbuf) + (reg & 1) * 16384);
  if (wn >= 2) {
#pragma unroll
    for (int m = 0; m < 8; m++)
#pragma unroll
      for (int n = 0; n < 4; n++)
#pragma unroll
        for (int r = 0; r < 4; r++) {
          int lrow = m * 16 + 4 * g + r;
          int pcol = (n * 16 + lq) ^ ((g & 1) << 4);
          fb[lrow * 64 + pcol] = acc[m][n][r];
        }
  }
  __syncthreads();
  if (wn < 2) {
#pragma unroll
    for (int m = 0; m < 8; m++) {
      size_t row = bm + wm * 128 + m * 16 + 4 * g;
#pragma unroll
      for (int n = 0; n < 4; n++) {
        size_t col = c0 + wn * 64 + n * 16 + lq;
#pragma unroll
        for (int r = 0; r < 4; r++) {
          int lrow = m * 16 + 4 * g + r;
          int pcol = (n * 16 + lq) ^ ((g & 1) << 4);
          float u1 = acc[m][n][r];
          float u2 = fb[lrow * 64 + pcol];
          float sil = u1 / (1.f + exp2f(-1.4426950408889634f * u1));
          Cout[(row + r) * (size_t)N + col] = f2bf(sil * u2);
        }
      }
    }
  }
}

// ----------------- causal flash attention (LDS-staged) --------------
// grid (T/128, B*H); 4 waves/block; wave owns 32 q-rows (2 rg of 16).
// Q,K from fused QK buffer [B*T][4096] (q cols 0..2047, k cols 2048+).
// Causal load-balance remap: blocks y>=16 flip qx -> 15-qx so the CU
// hosting blocks {i, i+256} (same x, y and y+16) runs q-tiles x and
// 15-x: per-CU kv-tile count = 34 constant instead of 4..64.
__global__ __launch_bounds__(256, 2) void attn_kernel(const u16* __restrict__ QK,
                                                      const u16* __restrict__ VT,
                                                      u16* __restrict__ CTX) {
  __shared__ u16 Ks[64 * 128];
  __shared__ u16 Vs[128 * 64];
  __shared__ u16 P_all[4][32 * 72];
  const int t = threadIdx.x;
  const int w = t >> 6, l = t & 63, g = l >> 4, lq = l & 15;
  u16* P = P_all[w];
  const int qx = (blockIdx.y & 16) ? (15 - blockIdx.x) : blockIdx.x;
  const int q0blk = qx * 128;
  const int q0w = q0blk + w * 32;
  const int bh = blockIdx.y, b = bh >> 4, h = bh & 15;
  const u16* qp = QK + (size_t)b * T_SEQ * QKS + h * D_HEAD;
  const u16* kp = qp + E_DIM;
  const u16* vp = VT + ((size_t)b * E_DIM + h * D_HEAD) * T_SEQ;

  short8 qf[2][4];
#pragma unroll
  for (int rg = 0; rg < 2; rg++)
#pragma unroll
    for (int ks = 0; ks < 4; ks++)
      qf[rg][ks] =
          *(const short8*)(qp + (size_t)(q0w + rg * 16 + lq) * QKS + ks * 32 + g * 8);

  f32x4 acc[2][8] = {};
  float m2[2][4], ls[2][4];
#pragma unroll
  for (int rg = 0; rg < 2; rg++)
#pragma unroll
    for (int r = 0; r < 4; r++) { m2[rg][r] = -1e30f; ls[rg][r] = 0.f; }
  const float sc = 0.08838834764831845f * 1.4426950408889634f;

  const int kRow0 = 16 * w + (l >> 4);
  const int kChunk = l & 15;
  const int vRow0 = 32 * w + (l >> 3);
  const int vChunk = l & 7;

  for (int kv0 = 0; kv0 < q0blk + 128; kv0 += 64) {
#pragma unroll
    for (int j = 0; j < 4; j++) {
      int R = kRow0 + 4 * j;
      async16(Ks + (16 * w + 4 * j) * 128,
              kp + (size_t)(kv0 + R) * QKS + ((kChunk ^ (R & 7)) << 3));
    }
#pragma unroll
    for (int j = 0; j < 4; j++) {
      int D = vRow0 + 8 * j;
      async16(Vs + (32 * w + 8 * j) * 64,
              vp + (size_t)D * T_SEQ + kv0 + ((vChunk ^ (D & 7)) << 3));
    }
    __syncthreads();

#pragma unroll
    for (int rg = 0; rg < 2; rg++) {
      const int rb = q0w + rg * 16;
      if (kv0 > rb + 15) continue;
      f32x4 s[4];
      __builtin_amdgcn_s_setprio(1);
#pragma unroll
      for (int ct = 0; ct < 4; ct++) {
        s[ct] = f32x4{0.f, 0.f, 0.f, 0.f};
#pragma unroll
        for (int ks = 0; ks < 4; ks++) {
          short8 kf = *(const short8*)(Ks + (ct * 16 + lq) * 128 +
                                       (((ks * 4 + g) ^ (lq & 7)) << 3));
          s[ct] = __builtin_amdgcn_mfma_f32_16x16x32_bf16(qf[rg][ks], kf, s[ct], 0, 0, 0);
        }
      }
      __builtin_amdgcn_s_setprio(0);
      float sv[4][4];
#pragma unroll
      for (int ct = 0; ct < 4; ct++)
#pragma unroll
        for (int r = 0; r < 4; r++) sv[ct][r] = s[ct][r] * sc;
      if (kv0 + 64 > rb) {
#pragma unroll
        for (int ct = 0; ct < 4; ct++)
#pragma unroll
          for (int r = 0; r < 4; r++)
            if (kv0 + ct * 16 + lq > rb + 4 * g + r) sv[ct][r] = -1e30f;
      }
      float mx[4];
#pragma unroll
      for (int r = 0; r < 4; r++)
        mx[r] = fmaxf(fmaxf(sv[0][r], sv[1][r]), fmaxf(sv[2][r], sv[3][r]));
#pragma unroll
      for (int off = 1; off < 16; off <<= 1)
#pragma unroll
        for (int r = 0; r < 4; r++) mx[r] = fmaxf(mx[r], __shfl_xor(mx[r], off));
#pragma unroll
      for (int r = 0; r < 4; r++) {
        float mn = fmaxf(m2[rg][r], mx[r]);
        float sca = exp2f(m2[rg][r] - mn);
        m2[rg][r] = mn;
        float sum = 0.f;
#pragma unroll
        for (int ct = 0; ct < 4; ct++) {
          float pv = exp2f(sv[ct][r] - mn);
          sum += pv;
          P[(rg * 16 + 4 * g + r) * 72 + ct * 16 + lq] = f2bf(pv);
        }
        ls[rg][r] = ls[rg][r] * sca + sum;
#pragma unroll
        for (int n = 0; n < 8; n++) acc[rg][n][r] *= sca;
      }
      short8 pa[2];
#pragma unroll
      for (int ks2 = 0; ks2 < 2; ks2++)
        pa[ks2] = *(const short8*)(P + (rg * 16 + lq) * 72 + ks2 * 32 + g * 8);
      __builtin_amdgcn_s_setprio(1);
#pragma unroll
      for (int n = 0; n < 8; n++)
#pragma unroll
        for (int ks2 = 0; ks2 < 2; ks2++) {
          short8 vf = *(const short8*)(Vs + (n * 16 + lq) * 64 +
                                       (((ks2 * 4 + g) ^ (lq & 7)) << 3));
          acc[rg][n] = __builtin_amdgcn_mfma_f32_16x16x32_bf16(pa[ks2], vf, acc[rg][n], 0, 0, 0);
        }
      __builtin_amdgcn_s_setprio(0);
    }
    __syncthreads();
  }

#pragma unroll
  for (int rg = 0; rg < 2; rg++) {
#pragma unroll
    for (int off = 1; off < 16; off <<= 1)
#pragma unroll
      for (int r = 0; r < 4; r++) ls[rg][r] += __shfl_xor(ls[rg][r], off);
  }
  u16* cp = CTX + ((size_t)b * T_SEQ + q0w) * E_DIM + h * D_HEAD;
#pragma unroll
  for (int rg = 0; rg < 2; rg++) {
    float inv[4];
#pragma unroll
    for (int r = 0; r < 4; r++) inv[r] = 1.f / ls[rg][r];
#pragma unroll
    for (int n = 0; n < 8; n++)
#pragma unroll
      for (int r = 0; r < 4; r++)
        cp[(size_t)(rg * 16 + 4 * g + r) * E_DIM + n * 16 + lq] =
            f2bf(acc[rg][n][r] * inv[r]);
  }
}

extern "C" void kernel_launch(void* const* d_in, const int* in_sizes, int n_in,
                              void* d_out, int out_size, void* d_ws, size_t ws_size,
                              hipStream_t stream) {
  (void)in_sizes; (void)n_in; (void)out_size; (void)ws_size;
  const float* x  = (const float*)d_in[0];
  const float* g1 = (const float*)d_in[1];
  const float* b1 = (const float*)d_in[2];
  const float* wq = (const float*)d_in[3];
  const float* wk = (const float*)d_in[4];
  const float* wv = (const float*)d_in[5];
  const float* wo = (const float*)d_in[6];
  const float* g2 = (const float*)d_in[7];
  const float* b2 = (const float*)d_in[8];
  const float* w1 = (const float*)d_in[9];
  const float* w2 = (const float*)d_in[10];
  const float* w3 = (const float*)d_in[11];
  float* out = (float*)d_out;

  const size_t EE = (size_t)E_DIM * E_DIM;
  const size_t EE2 = EE * 2;
  const size_t EF2 = (size_t)E_DIM * FFN_DIM * 2;
  const size_t ME2 = (size_t)M_ROWS * E_DIM * 2;
  char* p = (char*)d_ws;
  u16* wqkT = (u16*)p; p += 2 * EE2;   // [2E][E]: rows 0..E-1 = wq^T
  u16* wvT = (u16*)p; p += EE2;
  u16* woT = (u16*)p; p += EE2;
  u16* w1T = (u16*)p; p += EF2;
  u16* w2T = (u16*)p; p += EF2;
  u16* w3T = (u16*)p; p += EF2;
  u16* Hb  = (u16*)p; p += ME2;
  u16* QKb = (u16*)p; p += (size_t)M_ROWS * QKS * 2;  // [4096][4096]
  u16* Vb  = (u16*)p; p += ME2;
  u16* VTb = (u16*)p; p += ME2;
  u16* CTXb = (u16*)p; p += ME2;
  u16* U1b = QKb;   // gated (67MB) reuses QKb+Vb+VTb
  u16* Pk = wqkT;   // w3 split-K bf16 partials (33.55MB; wqkT dead by w3)

  dim3 blk32(32, 8);
  // ALL weights -> bf16 transposed, one dispatch (65536 blocks)
  cvt_all_kernel<<<65536, blk32, 0, stream>>>(wq, wk, wv, wo, w1, w2, w3,
                                              wqkT, wvT, woT, w1T, w2T, w3T);

  // attention block
  ln_kernel<<<M_ROWS, 256, 0, stream>>>(x, g1, b1, Hb);
  // fused QK GEMM at BM256: grid (16,16) = 256 blocks; chunk 4x8
  gemm8p<0, 256><<<dim3(QKS / 256, M_ROWS / 256), 512, 0, stream>>>(
      Hb, wqkT, QKb, nullptr, QKS, E_DIM, E_DIM, E_DIM, 4, 8);
  // V GEMM at BM128: grid (8,32) = 256 blocks; chunk 4x8
  gemm8p<0, 128><<<dim3(E_DIM / 256, M_ROWS / 128), 512, 0, stream>>>(
      Hb, wvT, Vb, nullptr, E_DIM, E_DIM, E_DIM, E_DIM, 4, 8);
  transpose_v_kernel<<<dim3(T_SEQ / 32, E_DIM / 32, 2), blk32, 0, stream>>>(Vb, VTb);
  attn_kernel<<<dim3(T_SEQ / 128, 2 * N_HEAD), 256, 0, stream>>>(QKb, VTb, CTXb);
  // WO: BM128, grid (8,32); chunk 4x8
  gemm8p<1, 128><<<dim3(E_DIM / 256, M_ROWS / 128), 512, 0, stream>>>(
      CTXb, woT, out, x, E_DIM, E_DIM, E_DIM, E_DIM, 4, 8);

  // SwiGLU MLP block
  ln_kernel<<<M_ROWS, 256, 0, stream>>>(out, g2, b2, Hb);
  // fused FFN1+FFN2+silu-gate: grid (64,16) = 1024 blocks; chunk 16x8
  gemm_ffn<<<dim3(FFN_DIM / 128, M_ROWS / 256), 512, 0, stream>>>(
      Hb, w1T, w2T, U1b, FFN_DIM, E_DIM, E_DIM, E_DIM, 16, 8);
  // w3: BM256 split-K=2: grid (8,16,2) = 256 blocks; chunk 4x8 per kz
  gemm8p<3, 256><<<dim3(E_DIM / 256, M_ROWS / 256, 2), 512, 0, stream>>>(
      U1b, w3T, Pk, nullptr, E_DIM, FFN_DIM / 2, FFN_DIM, FFN_DIM, 4, 8);
  add3_kernel<<<4096, 256, 0, stream>>>(out, Pk);
}

// Round 20
// 838.848 us; speedup vs baseline: 1.2881x; 1.0107x over previous
//
#include <hip/hip_runtime.h>

// Transformer layer, bf16 MFMA compute, fp32 I/O.
// B=2 T=2048 E=2048 H=16 DH=128 FFN=8192. Needs ~230MB workspace.

#define T_SEQ 2048
#define E_DIM 2048
#define N_HEAD 16
#define D_HEAD 128
#define FFN_DIM 8192
#define M_ROWS 4096  // B*T
#define QKS (2 * E_DIM)  // fused QK output row stride

typedef unsigned short u16;
typedef short short8 __attribute__((ext_vector_type(8)));
typedef float f32x4 __attribute__((ext_vector_type(4)));

#define DEV __device__ __forceinline__

DEV u16 f2bf(float f) {
  unsigned u = __float_as_uint(f);
  u += 0x7fffu + ((u >> 16) & 1u);
  return (u16)(u >> 16);
}
DEV float bf2f(u16 h) { return __uint_as_float(((unsigned)h) << 16); }

DEV void async16(void* lds, const void* g) {
  __builtin_amdgcn_global_load_lds((const __attribute__((address_space(1))) void*)g,
                                   (__attribute__((address_space(3))) void*)lds, 16, 0, 0);
}

// ---------------- LayerNorm: fp32 [rows][E] -> bf16 -----------------
__global__ __launch_bounds__(256) void ln_kernel(const float* __restrict__ x,
                                                 const float* __restrict__ gw,
                                                 const float* __restrict__ bw,
                                                 u16* __restrict__ out) {
  int row = blockIdx.x;
  int t = threadIdx.x;
  const float4* xr = (const float4*)(x + (size_t)row * E_DIM);
  float4 a = xr[t], c = xr[t + 256];
  float s = a.x + a.y + a.z + a.w + c.x + c.y + c.z + c.w;
  float q = a.x * a.x + a.y * a.y + a.z * a.z + a.w * a.w +
            c.x * c.x + c.y * c.y + c.z * c.z + c.w * c.w;
  for (int off = 32; off > 0; off >>= 1) {
    s += __shfl_down(s, off);
    q += __shfl_down(q, off);
  }
  __shared__ float red[8];
  if ((t & 63) == 0) { red[(t >> 6) * 2] = s; red[(t >> 6) * 2 + 1] = q; }
  __syncthreads();
  s = red[0] + red[2] + red[4] + red[6];
  q = red[1] + red[3] + red[5] + red[7];
  float mu = s * (1.f / E_DIM);
  float rs = rsqrtf(q * (1.f / E_DIM) - mu * mu + 1e-5f);
  const float4* g4 = (const float4*)gw;
  const float4* b4 = (const float4*)bw;
  float4 g0 = g4[t], g1v = g4[t + 256], e0 = b4[t], e1 = b4[t + 256];
  ushort4 o0, o1;
  o0.x = f2bf((a.x - mu) * rs * g0.x + e0.x);
  o0.y = f2bf((a.y - mu) * rs * g0.y + e0.y);
  o0.z = f2bf((a.z - mu) * rs * g0.z + e0.z);
  o0.w = f2bf((a.w - mu) * rs * g0.w + e0.w);
  o1.x = f2bf((c.x - mu) * rs * g1v.x + e1.x);
  o1.y = f2bf((c.y - mu) * rs * g1v.y + e1.y);
  o1.z = f2bf((c.z - mu) * rs * g1v.z + e1.z);
  o1.w = f2bf((c.w - mu) * rs * g1v.w + e1.w);
  ((ushort4*)(out + (size_t)row * E_DIM))[t] = o0;
  ((ushort4*)(out + (size_t)row * E_DIM))[t + 256] = o1;
}

// ==== ALL-weights convert+transpose in ONE dispatch =================
// block ranges: [0,16384): wq/wk/wv/wo (4096 tiles each);
// [16384,49152): w1/w2 (16384 each); [49152,65536): w3.
__global__ __launch_bounds__(256) void cvt_all_kernel(
    const float* __restrict__ wq, const float* __restrict__ wk,
    const float* __restrict__ wv, const float* __restrict__ wo,
    const float* __restrict__ w1, const float* __restrict__ w2,
    const float* __restrict__ w3, u16* __restrict__ wqkT,
    u16* __restrict__ wvT, u16* __restrict__ woT, u16* __restrict__ w1T,
    u16* __restrict__ w2T, u16* __restrict__ w3T) {
  __shared__ float tile[32][33];
  const int b = blockIdx.x;
  const float* W;
  u16* WT;
  int Kd, Nd, n0, k0;
  if (b < 16384) {
    int widx = b >> 12, t_ = b & 4095;
    Kd = E_DIM; Nd = E_DIM;
    n0 = (t_ & 63) * 32; k0 = (t_ >> 6) * 32;
    W = widx == 0 ? wq : widx == 1 ? wk : widx == 2 ? wv : wo;
    WT = widx == 0 ? wqkT
         : widx == 1 ? (wqkT + (size_t)E_DIM * E_DIM)
         : widx == 2 ? wvT : woT;
  } else if (b < 49152) {
    int i = b - 16384;
    int widx = i >> 14, t_ = i & 16383;
    Kd = E_DIM; Nd = FFN_DIM;
    n0 = (t_ & 255) * 32; k0 = (t_ >> 8) * 32;
    W = widx ? w2 : w1;
    WT = widx ? w2T : w1T;
  } else {
    int t_ = b - 49152;
    Kd = FFN_DIM; Nd = E_DIM;
    n0 = (t_ & 63) * 32; k0 = (t_ >> 6) * 32;
    W = w3; WT = w3T;
  }
  int tx = threadIdx.x, ty = threadIdx.y;
#pragma unroll
  for (int i = 0; i < 4; i++)
    tile[ty + i * 8][tx] = W[(size_t)(k0 + ty + i * 8) * Nd + n0 + tx];
  __syncthreads();
#pragma unroll
  for (int i = 0; i < 4; i++)
    WT[(size_t)(n0 + ty + i * 8) * Kd + k0 + tx] = f2bf(tile[tx][ty + i * 8]);
}

// ------ add3: out += P0 + P1 (bf16 split-K partials) ----------------
__global__ __launch_bounds__(256) void add3_kernel(float* __restrict__ out,
                                                   const u16* __restrict__ pk) {
  const size_t MN = (size_t)M_ROWS * E_DIM;
  size_t base = ((size_t)blockIdx.x * 256 + threadIdx.x) * 8;
  short8 a = *(const short8*)(pk + base);
  short8 b = *(const short8*)(pk + MN + base);
  float4 o0 = *(float4*)(out + base), o1 = *(float4*)(out + base + 4);
  o0.x += bf2f((u16)a[0]) + bf2f((u16)b[0]);
  o0.y += bf2f((u16)a[1]) + bf2f((u16)b[1]);
  o0.z += bf2f((u16)a[2]) + bf2f((u16)b[2]);
  o0.w += bf2f((u16)a[3]) + bf2f((u16)b[3]);
  o1.x += bf2f((u16)a[4]) + bf2f((u16)b[4]);
  o1.y += bf2f((u16)a[5]) + bf2f((u16)b[5]);
  o1.z += bf2f((u16)a[6]) + bf2f((u16)b[6]);
  o1.w += bf2f((u16)a[7]) + bf2f((u16)b[7]);
  *(float4*)(out + base) = o0;
  *(float4*)(out + base + 4) = o1;
}

// ------ addv: VT = Pv0 + Pv1 (bf16 V^T split-K partials) ------------
__global__ __launch_bounds__(256) void addv_kernel(u16* __restrict__ vt,
                                                   const u16* __restrict__ pv0,
                                                   const u16* __restrict__ pv1) {
  size_t base = ((size_t)blockIdx.x * 256 + threadIdx.x) * 8;
  short8 a = *(const short8*)(pv0 + base);
  short8 b = *(const short8*)(pv1 + base);
  short8 o;
#pragma unroll
  for (int i = 0; i < 8; i++)
    o[i] = (short)f2bf(bf2f((u16)a[i]) + bf2f((u16)b[i]));
  *(short8*)(vt + base) = o;
}

// ======= GEMM BM_x256xBK64, 8-phase schedule, paired-row LDS ========
// Round-10 structure (proven).  2-D XCD chunking; split-K via kz.
// MODE 0: bf16 C.  MODE 1: Cout(f32)=Extra(f32)+acc.
// MODE 2: Cout(bf16)=silu(Extra bf16)*acc.
// MODE 3: bf16 split-K partial at Cout + kz*M*N.
// MODE 4: bf16 V^T split-K partial: col->(b,t), row=e;
//         dst = kz ? Extra : Cout;  dst[(b*E+row)*T + t].
template <int MODE, int BM_>
__global__ __launch_bounds__(512, 1) void gemm8p(const u16* __restrict__ A,
                                                 const u16* __restrict__ BT,
                                                 void* __restrict__ Cout,
                                                 const void* __restrict__ Extra,
                                                 int N, int K, int lda, int ldb,
                                                 int CX, int CY) {
  constexpr int MM = BM_ / 64;
  constexpr int AUNIT = BM_ * 32;
  __shared__ u16 Abuf[4 * AUNIT];
  __shared__ u16 Bbuf[4 * 8192];
  const int t = threadIdx.x;
  const int w = t >> 6, l = t & 63, g = l >> 4, lq = l & 15;
  const int wm = w >> 2, wn = w & 3;

  const int bid = (blockIdx.z * gridDim.y + blockIdx.y) * gridDim.x + blockIdx.x;
  const int xcd = bid & 7, slot = bid >> 3;
  const int nchx = gridDim.x / CX;
  const int nchy = gridDim.y / CY;
  const int cpz = nchx * nchy;
  const int kz = xcd / cpz;
  const int cid = xcd % cpz;
  const int bx = (cid % nchx) * CX + (slot % CX);
  const int by = (cid / nchx) * CY + (slot / CX);
  const size_t bm = (size_t)by * BM_, bn = (size_t)bx * 256;
  const size_t koff = (size_t)kz * K;

  const int srcrow = ((l >> 3) << 1) | (l & 1);
  const int csrc = ((((l >> 1) & 3) ^ ((l >> 3) & 3)) << 3);
  const u16* aSrc = A + (bm + w * 16 + srcrow) * (size_t)lda + koff + csrc;
  const u16* bSrc = BT + (bn + w * 16 + srcrow) * (size_t)ldb + koff + csrc;
  const int rdoff = (((lq & 1) + 2 * (g ^ ((lq >> 1) & 3))) << 3);

#define STA8(DB, KS, TILE)                                                    \
  {                                                                           \
    u16* Ad = Abuf + (DB) * (2 * AUNIT) + (KS)*AUNIT + w * 512;               \
    const u16* as_ = aSrc + (size_t)(TILE)*64 + (KS)*32;                      \
    async16(Ad, as_);                                                         \
    if constexpr (BM_ == 256) async16(Ad + 4096, as_ + (size_t)128 * lda);    \
  }
#define STB8(DB, KS, TILE)                                                    \
  {                                                                           \
    u16* Bd = Bbuf + (DB)*16384 + (KS)*8192 + w * 512;                        \
    const u16* bs_ = bSrc + (size_t)(TILE)*64 + (KS)*32;                      \
    async16(Bd, bs_);                                                         \
    async16(Bd + 4096, bs_ + (size_t)128 * ldb);                              \
  }
#define RDA8(DB, KS, MH)                                                      \
  _Pragma("unroll") for (int mm = 0; mm < MM; ++mm)                           \
      af[mm] = *(const short8*)(Abuf + (DB) * (2 * AUNIT) + (KS)*AUNIT +      \
                                (wm * (BM_ / 4) + (MH) * (BM_ / 8) + mm * 8 + \
                                 (lq >> 1)) * 64 + rdoff);
#define RDB8(DB, KS)                                                          \
  _Pragma("unroll") for (int nn = 0; nn < 4; ++nn)                            \
      bf[nn] = *(const short8*)(Bbuf + (DB)*16384 + (KS)*8192 +               \
                                (wn * 32 + nn * 8 + (lq >> 1)) * 64 + rdoff);
#define MM168(MH)                                                             \
  _Pragma("unroll") for (int mm = 0; mm < MM; ++mm)                           \
      _Pragma("unroll") for (int nn = 0; nn < 4; ++nn)                        \
          acc[(MH)*MM + mm][nn] = __builtin_amdgcn_mfma_f32_16x16x32_bf16(    \
              af[mm], bf[nn], acc[(MH)*MM + mm][nn], 0, 0, 0);
#define SYNCA                                                                 \
  __builtin_amdgcn_s_barrier();                                               \
  asm volatile("s_waitcnt lgkmcnt(0)" ::: "memory");                          \
  __builtin_amdgcn_sched_barrier(0);                                          \
  __builtin_amdgcn_s_setprio(1);
#define ENDP __builtin_amdgcn_s_setprio(0);
#define BAR2 __builtin_amdgcn_s_barrier();
#define WAITN                                                                 \
  if constexpr (BM_ == 256) asm volatile("s_waitcnt vmcnt(8)" ::: "memory");  \
  else                      asm volatile("s_waitcnt vmcnt(6)" ::: "memory");
#define WAITH                                                                 \
  if constexpr (BM_ == 256) asm volatile("s_waitcnt vmcnt(4)" ::: "memory");  \
  else                      asm volatile("s_waitcnt vmcnt(3)" ::: "memory");

  const int NT = K >> 6, NI = NT >> 1;
  f32x4 acc[2 * MM][4] = {};
  short8 af[MM > 4 ? MM : 4], bf[4];

  STA8(0, 0, 0); STB8(0, 0, 0);
  STA8(0, 1, 0); STB8(0, 1, 0);
  STA8(1, 0, 1); STB8(1, 0, 1);
  WAITN;
  BAR2;

  for (int j = 0; j < NI; ++j) {
    const int t1 = 2 * j + 1, t2 = 2 * j + 2, t3 = 2 * j + 3;
    const bool s2 = t2 < NT, s3 = t3 < NT, lastI = (j + 1 == NI);
    RDB8(0, 0); RDA8(0, 0, 0);
    STA8(1, 1, t1);
    SYNCA; MM168(0); ENDP; BAR2;
    RDA8(0, 0, 1);
    STB8(1, 1, t1);
    SYNCA; MM168(1); ENDP;
    WAITN;
    BAR2;
    RDB8(0, 1); RDA8(0, 1, 0);
    if (s2) STA8(0, 0, t2);
    SYNCA; MM168(0); ENDP; BAR2;
    RDA8(0, 1, 1);
    if (s2) STB8(0, 0, t2);
    SYNCA; MM168(1); ENDP;
    if (lastI) { WAITH; } else { WAITN; }
    BAR2;
    RDB8(1, 0); RDA8(1, 0, 0);
    if (s2) STA8(0, 1, t2);
    SYNCA; MM168(0); ENDP; BAR2;
    RDA8(1, 0, 1);
    if (s2) STB8(0, 1, t2);
    SYNCA; MM168(1); ENDP;
    if (lastI) { asm volatile("s_waitcnt vmcnt(0)" ::: "memory"); } else { WAITN; }
    BAR2;
    RDB8(1, 1); RDA8(1, 1, 0);
    if (s3) STA8(1, 0, t3);
    SYNCA; MM168(0); ENDP; BAR2;
    RDA8(1, 1, 1);
    if (s3) STB8(1, 0, t3);
    SYNCA; MM168(1); ENDP;
    if (!lastI) { WAITN; }
    BAR2;
  }
#undef STA8
#undef STB8
#undef RDA8
#undef RDB8
#undef MM168
#undef SYNCA
#undef ENDP
#undef BAR2
#undef WAITN
#undef WAITH

  const size_t mn = (size_t)gridDim.y * BM_ * (size_t)N;
#pragma unroll
  for (int m = 0; m < 2 * MM; m++) {
    size_t row = bm + wm * (BM_ / 2) + m * 16 + 4 * g;
#pragma unroll
    for (int n = 0; n < 4; n++) {
      size_t col = bn + wn * 64 + n * 16 + lq;
#pragma unroll
      for (int r = 0; r < 4; r++) {
        size_t idx = (row + r) * (size_t)N + col;
        if constexpr (MODE == 0) {
          ((u16*)Cout)[idx] = f2bf(acc[m][n][r]);
        } else if constexpr (MODE == 1) {
          ((float*)Cout)[idx] = ((const float*)Extra)[idx] + acc[m][n][r];
        } else if constexpr (MODE == 2) {
          float a = bf2f(((const u16*)Extra)[idx]);
          float sil = a / (1.f + exp2f(-1.4426950408889634f * a));
          ((u16*)Cout)[idx] = f2bf(sil * acc[m][n][r]);
        } else if constexpr (MODE == 3) {
          ((u16*)Cout)[(size_t)kz * mn + idx] = f2bf(acc[m][n][r]);
        } else {
          size_t bb = col >> 11, tt = col & 2047;
          u16* dst = kz ? (u16*)Extra : (u16*)Cout;
          dst[(bb * E_DIM + row + r) * (size_t)T_SEQ + tt] = f2bf(acc[m][n][r]);
        }
      }
    }
  }
}

// ==== FUSED SwiGLU FFN GEMM: gated = silu(A@w1T^T) * (A@w2T^T) ======
__global__ __launch_bounds__(512, 1) void gemm_ffn(const u16* __restrict__ A,
                                                   const u16* __restrict__ B1T,
                                                   const u16* __restrict__ B2T,
                                                   u16* __restrict__ Cout,
                                                   int N, int K, int lda, int ldb,
                                                   int CX, int CY) {
  constexpr int AUNIT = 8192;
  __shared__ u16 Abuf[4 * AUNIT];
  __shared__ u16 Bbuf[4 * AUNIT];
  const int t = threadIdx.x;
  const int w = t >> 6, l = t & 63, g = l >> 4, lq = l & 15;
  const int wm = w >> 2, wn = w & 3;

  const int bid = blockIdx.y * gridDim.x + blockIdx.x;
  const int xcd = bid & 7, slot = bid >> 3;
  const int nchx = gridDim.x / CX;
  const int cid = xcd;
  const int bx = (cid % nchx) * CX + (slot % CX);
  const int by = (cid / nchx) * CY + (slot / CX);
  const size_t bm = (size_t)by * 256;
  const size_t c0 = (size_t)bx * 128;

  const int srcrow = ((l >> 3) << 1) | (l & 1);
  const int csrc = ((((l >> 1) & 3) ^ ((l >> 3) & 3)) << 3);
  const u16* aSrc = A + (bm + w * 16 + srcrow) * (size_t)lda + csrc;
  const u16* b1Src = B1T + (c0 + w * 16 + srcrow) * (size_t)ldb + csrc;
  const u16* b2Src = B2T + (c0 + w * 16 + srcrow) * (size_t)ldb + csrc;
  const int rdoff = (((lq & 1) + 2 * (g ^ ((lq >> 1) & 3))) << 3);

#define STA8(DB, KS, TILE)                                                    \
  {                                                                           \
    u16* Ad = Abuf + (DB) * (2 * AUNIT) + (KS)*AUNIT + w * 512;               \
    const u16* as_ = aSrc + (size_t)(TILE)*64 + (KS)*32;                      \
    async16(Ad, as_);                                                         \
    async16(Ad + 4096, as_ + (size_t)128 * lda);                              \
  }
#define STB8(DB, KS, TILE)                                                    \
  {                                                                           \
    u16* Bd = Bbuf + (DB) * (2 * AUNIT) + (KS)*AUNIT + w * 512;               \
    size_t off_ = (size_t)(TILE)*64 + (KS)*32;                                \
    async16(Bd, b1Src + off_);                                                \
    async16(Bd + 4096, b2Src + off_);                                         \
  }
#define RDA8(DB, KS, MH)                                                      \
  _Pragma("unroll") for (int mm = 0; mm < 4; ++mm)                            \
      af[mm] = *(const short8*)(Abuf + (DB) * (2 * AUNIT) + (KS)*AUNIT +      \
                                (wm * 64 + (MH)*32 + mm * 8 + (lq >> 1)) *    \
                                    64 + rdoff);
#define RDB8(DB, KS)                                                          \
  _Pragma("unroll") for (int nn = 0; nn < 4; ++nn)                            \
      bf[nn] = *(const short8*)(Bbuf + (DB) * (2 * AUNIT) + (KS)*AUNIT +      \
                                (wn * 32 + nn * 8 + (lq >> 1)) * 64 + rdoff);
#define MM168(MH)                                                             \
  _Pragma("unroll") for (int mm = 0; mm < 4; ++mm)                            \
      _Pragma("unroll") for (int nn = 0; nn < 4; ++nn)                        \
          acc[(MH)*4 + mm][nn] = __builtin_amdgcn_mfma_f32_16x16x32_bf16(     \
              af[mm], bf[nn], acc[(MH)*4 + mm][nn], 0, 0, 0);
#define SYNCA                                                                 \
  __builtin_amdgcn_s_barrier();                                               \
  asm volatile("s_waitcnt lgkmcnt(0)" ::: "memory");                          \
  __builtin_amdgcn_sched_barrier(0);                                          \
  __builtin_amdgcn_s_setprio(1);
#define ENDP __builtin_amdgcn_s_setprio(0);
#define BAR2 __builtin_amdgcn_s_barrier();
#define WAITN asm volatile("s_waitcnt vmcnt(8)" ::: "memory");
#define WAITH asm volatile("s_waitcnt vmcnt(4)" ::: "memory");

  const int NT = K >> 6, NI = NT >> 1;
  f32x4 acc[8][4] = {};
  short8 af[4], bf[4];

  STA8(0, 0, 0); STB8(0, 0, 0);
  STA8(0, 1, 0); STB8(0, 1, 0);
  STA8(1, 0, 1); STB8(1, 0, 1);
  WAITN;
  BAR2;

  for (int j = 0; j < NI; ++j) {
    const int t1 = 2 * j + 1, t2 = 2 * j + 2, t3 = 2 * j + 3;
    const bool s2 = t2 < NT, s3 = t3 < NT, lastI = (j + 1 == NI);
    RDB8(0, 0); RDA8(0, 0, 0);
    STA8(1, 1, t1);
    SYNCA; MM168(0); ENDP; BAR2;
    RDA8(0, 0, 1);
    STB8(1, 1, t1);
    SYNCA; MM168(1); ENDP;
    WAITN;
    BAR2;
    RDB8(0, 1); RDA8(0, 1, 0);
    if (s2) STA8(0, 0, t2);
    SYNCA; MM168(0); ENDP; BAR2;
    RDA8(0, 1, 1);
    if (s2) STB8(0, 0, t2);
    SYNCA; MM168(1); ENDP;
    if (lastI) { WAITH; } else { WAITN; }
    BAR2;
    RDB8(1, 0); RDA8(1, 0, 0);
    if (s2) STA8(0, 1, t2);
    SYNCA; MM168(0); ENDP; BAR2;
    RDA8(1, 0, 1);
    if (s2) STB8(0, 1, t2);
    SYNCA; MM168(1); ENDP;
    if (lastI) { asm volatile("s_waitcnt vmcnt(0)" ::: "memory"); } else { WAITN; }
    BAR2;
    RDB8(1, 1); RDA8(1, 1, 0);
    if (s3) STA8(1, 0, t3);
    SYNCA; MM168(0); ENDP; BAR2;
    RDA8(1, 1, 1);
    if (s3) STB8(1, 0, t3);
    SYNCA; MM168(1); ENDP;
    if (!lastI) { WAITN; }
    BAR2;
  }
#undef STA8
#undef STB8
#undef RDA8
#undef RDB8
#undef MM168
#undef SYNCA
#undef ENDP
#undef BAR2
#undef WAITN
#undef WAITH

  // ---- SwiGLU epilogue: exchange u2 via (dead) LDS, gate, store ----
  const int reg = wm * 2 + ((wn >= 2) ? (wn - 2) : wn);
  float* fb = (float*)((reg < 2 ? Abuf : Bbuf) + (reg & 1) * 16384);
  if (wn >= 2) {
#pragma unroll
    for (int m = 0; m < 8; m++)
#pragma unroll
      for (int n = 0; n < 4; n++)
#pragma unroll
        for (int r = 0; r < 4; r++) {
          int lrow = m * 16 + 4 * g + r;
          int pcol = (n * 16 + lq) ^ ((g & 1) << 4);
          fb[lrow * 64 + pcol] = acc[m][n][r];
        }
  }
  __syncthreads();
  if (wn < 2) {
#pragma unroll
    for (int m = 0; m < 8; m++) {
      size_t row = bm + wm * 128 + m * 16 + 4 * g;
#pragma unroll
      for (int n = 0; n < 4; n++) {
        size_t col = c0 + wn * 64 + n * 16 + lq;
#pragma unroll
        for (int r = 0; r < 4; r++) {
          int lrow = m * 16 + 4 * g + r;
          int pcol = (n * 16 + lq) ^ ((g & 1) << 4);
          float u1 = acc[m][n][r];
          float u2 = fb[lrow * 64 + pcol];
          float sil = u1 / (1.f + exp2f(-1.4426950408889634f * u1));
          Cout[(row + r) * (size_t)N + col] = f2bf(sil * u2);
        }
      }
    }
  }
}

// ----------------- causal flash attention (LDS-staged) --------------
// grid (T/128, B*H); 4 waves/block; wave owns 32 q-rows (2 rg of 16).
// Q,K from fused QK buffer [B*T][4096] (q cols 0..2047, k cols 2048+).
// Causal load-balance remap: blocks y>=16 flip qx -> 15-qx (r18 win).
__global__ __launch_bounds__(256, 2) void attn_kernel(const u16* __restrict__ QK,
                                                      const u16* __restrict__ VT,
                                                      u16* __restrict__ CTX) {
  __shared__ u16 Ks[64 * 128];
  __shared__ u16 Vs[128 * 64];
  __shared__ u16 P_all[4][32 * 72];
  const int t = threadIdx.x;
  const int w = t >> 6, l = t & 63, g = l >> 4, lq = l & 15;
  u16* P = P_all[w];
  const int qx = (blockIdx.y & 16) ? (15 - blockIdx.x) : blockIdx.x;
  const int q0blk = qx * 128;
  const int q0w = q0blk + w * 32;
  const int bh = blockIdx.y, b = bh >> 4, h = bh & 15;
  const u16* qp = QK + (size_t)b * T_SEQ * QKS + h * D_HEAD;
  const u16* kp = qp + E_DIM;
  const u16* vp = VT + ((size_t)b * E_DIM + h * D_HEAD) * T_SEQ;

  short8 qf[2][4];
#pragma unroll
  for (int rg = 0; rg < 2; rg++)
#pragma unroll
    for (int ks = 0; ks < 4; ks++)
      qf[rg][ks] =
          *(const short8*)(qp + (size_t)(q0w + rg * 16 + lq) * QKS + ks * 32 + g * 8);

  f32x4 acc[2][8] = {};
  float m2[2][4], ls[2][4];
#pragma unroll
  for (int rg = 0; rg < 2; rg++)
#pragma unroll
    for (int r = 0; r < 4; r++) { m2[rg][r] = -1e30f; ls[rg][r] = 0.f; }
  const float sc = 0.08838834764831845f * 1.4426950408889634f;

  const int kRow0 = 16 * w + (l >> 4);
  const int kChunk = l & 15;
  const int vRow0 = 32 * w + (l >> 3);
  const int vChunk = l & 7;

  for (int kv0 = 0; kv0 < q0blk + 128; kv0 += 64) {
#pragma unroll
    for (int j = 0; j < 4; j++) {
      int R = kRow0 + 4 * j;
      async16(Ks + (16 * w + 4 * j) * 128,
              kp + (size_t)(kv0 + R) * QKS + ((kChunk ^ (R & 7)) << 3));
    }
#pragma unroll
    for (int j = 0; j < 4; j++) {
      int D = vRow0 + 8 * j;
      async16(Vs + (32 * w + 8 * j) * 64,
              vp + (size_t)D * T_SEQ + kv0 + ((vChunk ^ (D & 7)) << 3));
    }
    __syncthreads();

#pragma unroll
    for (int rg = 0; rg < 2; rg++) {
      const int rb = q0w + rg * 16;
      if (kv0 > rb + 15) continue;
      f32x4 s[4];
      __builtin_amdgcn_s_setprio(1);
#pragma unroll
      for (int ct = 0; ct < 4; ct++) {
        s[ct] = f32x4{0.f, 0.f, 0.f, 0.f};
#pragma unroll
        for (int ks = 0; ks < 4; ks++) {
          short8 kf = *(const short8*)(Ks + (ct * 16 + lq) * 128 +
                                       (((ks * 4 + g) ^ (lq & 7)) << 3));
          s[ct] = __builtin_amdgcn_mfma_f32_16x16x32_bf16(qf[rg][ks], kf, s[ct], 0, 0, 0);
        }
      }
      __builtin_amdgcn_s_setprio(0);
      float sv[4][4];
#pragma unroll
      for (int ct = 0; ct < 4; ct++)
#pragma unroll
        for (int r = 0; r < 4; r++) sv[ct][r] = s[ct][r] * sc;
      if (kv0 + 64 > rb) {
#pragma unroll
        for (int ct = 0; ct < 4; ct++)
#pragma unroll
          for (int r = 0; r < 4; r++)
            if (kv0 + ct * 16 + lq > rb + 4 * g + r) sv[ct][r] = -1e30f;
      }
      float mx[4];
#pragma unroll
      for (int r = 0; r < 4; r++)
        mx[r] = fmaxf(fmaxf(sv[0][r], sv[1][r]), fmaxf(sv[2][r], sv[3][r]));
#pragma unroll
      for (int off = 1; off < 16; off <<= 1)
#pragma unroll
        for (int r = 0; r < 4; r++) mx[r] = fmaxf(mx[r], __shfl_xor(mx[r], off));
#pragma unroll
      for (int r = 0; r < 4; r++) {
        float mn = fmaxf(m2[rg][r], mx[r]);
        float sca = exp2f(m2[rg][r] - mn);
        m2[rg][r] = mn;
        float sum = 0.f;
#pragma unroll
        for (int ct = 0; ct < 4; ct++) {
          float pv = exp2f(sv[ct][r] - mn);
          sum += pv;
          P[(rg * 16 + 4 * g + r) * 72 + ct * 16 + lq] = f2bf(pv);
        }
        ls[rg][r] = ls[rg][r] * sca + sum;
#pragma unroll
        for (int n = 0; n < 8; n++) acc[rg][n][r] *= sca;
      }
      short8 pa[2];
#pragma unroll
      for (int ks2 = 0; ks2 < 2; ks2++)
        pa[ks2] = *(const short8*)(P + (rg * 16 + lq) * 72 + ks2 * 32 + g * 8);
      __builtin_amdgcn_s_setprio(1);
#pragma unroll
      for (int n = 0; n < 8; n++)
#pragma unroll
        for (int ks2 = 0; ks2 < 2; ks2++) {
          short8 vf = *(const short8*)(Vs + (n * 16 + lq) * 64 +
                                       (((ks2 * 4 + g) ^ (lq & 7)) << 3));
          acc[rg][n] = __builtin_amdgcn_mfma_f32_16x16x32_bf16(pa[ks2], vf, acc[rg][n], 0, 0, 0);
        }
      __builtin_amdgcn_s_setprio(0);
    }
    __syncthreads();
  }

#pragma unroll
  for (int rg = 0; rg < 2; rg++) {
#pragma unroll
    for (int off = 1; off < 16; off <<= 1)
#pragma unroll
      for (int r = 0; r < 4; r++) ls[rg][r] += __shfl_xor(ls[rg][r], off);
  }
  u16* cp = CTX + ((size_t)b * T_SEQ + q0w) * E_DIM + h * D_HEAD;
#pragma unroll
  for (int rg = 0; rg < 2; rg++) {
    float inv[4];
#pragma unroll
    for (int r = 0; r < 4; r++) inv[r] = 1.f / ls[rg][r];
#pragma unroll
    for (int n = 0; n < 8; n++)
#pragma unroll
      for (int r = 0; r < 4; r++)
        cp[(size_t)(rg * 16 + 4 * g + r) * E_DIM + n * 16 + lq] =
            f2bf(acc[rg][n][r] * inv[r]);
  }
}

extern "C" void kernel_launch(void* const* d_in, const int* in_sizes, int n_in,
                              void* d_out, int out_size, void* d_ws, size_t ws_size,
                              hipStream_t stream) {
  (void)in_sizes; (void)n_in; (void)out_size; (void)ws_size;
  const float* x  = (const float*)d_in[0];
  const float* g1 = (const float*)d_in[1];
  const float* b1 = (const float*)d_in[2];
  const float* wq = (const float*)d_in[3];
  const float* wk = (const float*)d_in[4];
  const float* wv = (const float*)d_in[5];
  const float* wo = (const float*)d_in[6];
  const float* g2 = (const float*)d_in[7];
  const float* b2 = (const float*)d_in[8];
  const float* w1 = (const float*)d_in[9];
  const float* w2 = (const float*)d_in[10];
  const float* w3 = (const float*)d_in[11];
  float* out = (float*)d_out;

  const size_t EE = (size_t)E_DIM * E_DIM;
  const size_t EE2 = EE * 2;
  const size_t EF2 = (size_t)E_DIM * FFN_DIM * 2;
  const size_t ME2 = (size_t)M_ROWS * E_DIM * 2;
  char* p = (char*)d_ws;
  u16* wqkT = (u16*)p; p += 2 * EE2;   // [2E][E]: rows 0..E-1 = wq^T
  u16* wvT = (u16*)p; p += EE2;
  u16* woT = (u16*)p; p += EE2;
  u16* w1T = (u16*)p; p += EF2;
  u16* w2T = (u16*)p; p += EF2;
  u16* w3T = (u16*)p; p += EF2;
  u16* Hb  = (u16*)p; p += ME2;
  u16* QKb = (u16*)p; p += (size_t)M_ROWS * QKS * 2;  // [4096][4096]
  u16* VTb = (u16*)p; p += ME2;
  u16* CTXb = (u16*)p; p += ME2;
  u16* U1b = QKb;    // gated (67MB) reuses QKb+VTb+CTXb
  u16* Pv0 = wqkT;   // V^T kz=0 partial (16.78MB; wqkT dead after QK)
  u16* Pv1 = CTXb;   // V^T kz=1 partial (CTXb untouched until attn)
  u16* Pk = wqkT;    // w3 split-K partials (33.55MB over wqkT+wvT+woT,
                     // all dead by w3 time)

  dim3 blk32(32, 8);
  // ALL weights -> bf16 transposed, one dispatch (65536 blocks)
  cvt_all_kernel<<<65536, blk32, 0, stream>>>(wq, wk, wv, wo, w1, w2, w3,
                                              wqkT, wvT, woT, w1T, w2T, w3T);

  // attention block
  ln_kernel<<<M_ROWS, 256, 0, stream>>>(x, g1, b1, Hb);
  // fused QK GEMM at BM256: grid (16,16) = 256 blocks; chunk 4x8
  gemm8p<0, 256><<<dim3(QKS / 256, M_ROWS / 256), 512, 0, stream>>>(
      Hb, wqkT, QKb, nullptr, QKS, E_DIM, E_DIM, E_DIM, 4, 8);
  // V^T direct: A=wvT (M=E), B=Hb (N=B*T), split-K=2:
  // grid (16,8,2) = 256 blocks; chunk 8x4 (nchx=2,nchy=2,gz=2 -> 8);
  // kz=0 partial -> Pv0 (dead wqkT), kz=1 -> Pv1 (dead CTXb)
  gemm8p<4, 256><<<dim3(M_ROWS / 256, E_DIM / 256, 2), 512, 0, stream>>>(
      wvT, Hb, Pv0, Pv1, M_ROWS, E_DIM / 2, E_DIM, E_DIM, 8, 4);
  addv_kernel<<<4096, 256, 0, stream>>>(VTb, Pv0, Pv1);
  attn_kernel<<<dim3(T_SEQ / 128, 2 * N_HEAD), 256, 0, stream>>>(QKb, VTb, CTXb);
  // WO: BM128, grid (8,32); chunk 4x8
  gemm8p<1, 128><<<dim3(E_DIM / 256, M_ROWS / 128), 512, 0, stream>>>(
      CTXb, woT, out, x, E_DIM, E_DIM, E_DIM, E_DIM, 4, 8);

  // SwiGLU MLP block
  ln_kernel<<<M_ROWS, 256, 0, stream>>>(out, g2, b2, Hb);
  // fused FFN1+FFN2+silu-gate: grid (64,16) = 1024 blocks; chunk 16x8
  gemm_ffn<<<dim3(FFN_DIM / 128, M_ROWS / 256), 512, 0, stream>>>(
      Hb, w1T, w2T, U1b, FFN_DIM, E_DIM, E_DIM, E_DIM, 16, 8);
  // w3: BM256 split-K=2: grid (8,16,2) = 256 blocks; chunk 4x8 per kz
  gemm8p<3, 256><<<dim3(E_DIM / 256, M_ROWS / 256, 2), 512, 0, stream>>>(
      U1b, w3T, Pk, nullptr, E_DIM, FFN_DIM / 2, FFN_DIM, FFN_DIM, 4, 8);
  add3_kernel<<<4096, 256, 0, stream>>>(out, Pk);
}

// Round 21
// 835.029 us; speedup vs baseline: 1.2940x; 1.0046x over previous
//
#include <hip/hip_runtime.h>

// Transformer layer, bf16 MFMA compute, fp32 I/O.
// B=2 T=2048 E=2048 H=16 DH=128 FFN=8192. Needs ~230MB workspace.

#define T_SEQ 2048
#define E_DIM 2048
#define N_HEAD 16
#define D_HEAD 128
#define FFN_DIM 8192
#define M_ROWS 4096  // B*T
#define QKS (2 * E_DIM)  // fused QK output row stride

typedef unsigned short u16;
typedef short short8 __attribute__((ext_vector_type(8)));
typedef float f32x4 __attribute__((ext_vector_type(4)));

#define DEV __device__ __forceinline__

DEV u16 f2bf(float f) {
  unsigned u = __float_as_uint(f);
  u += 0x7fffu + ((u >> 16) & 1u);
  return (u16)(u >> 16);
}
DEV float bf2f(u16 h) { return __uint_as_float(((unsigned)h) << 16); }

DEV void async16(void* lds, const void* g) {
  __builtin_amdgcn_global_load_lds((const __attribute__((address_space(1))) void*)g,
                                   (__attribute__((address_space(3))) void*)lds, 16, 0, 0);
}

// ---------------- LayerNorm: fp32 [rows][E] -> bf16 -----------------
__global__ __launch_bounds__(256) void ln_kernel(const float* __restrict__ x,
                                                 const float* __restrict__ gw,
                                                 const float* __restrict__ bw,
                                                 u16* __restrict__ out) {
  int row = blockIdx.x;
  int t = threadIdx.x;
  const float4* xr = (const float4*)(x + (size_t)row * E_DIM);
  float4 a = xr[t], c = xr[t + 256];
  float s = a.x + a.y + a.z + a.w + c.x + c.y + c.z + c.w;
  float q = a.x * a.x + a.y * a.y + a.z * a.z + a.w * a.w +
            c.x * c.x + c.y * c.y + c.z * c.z + c.w * c.w;
  for (int off = 32; off > 0; off >>= 1) {
    s += __shfl_down(s, off);
    q += __shfl_down(q, off);
  }
  __shared__ float red[8];
  if ((t & 63) == 0) { red[(t >> 6) * 2] = s; red[(t >> 6) * 2 + 1] = q; }
  __syncthreads();
  s = red[0] + red[2] + red[4] + red[6];
  q = red[1] + red[3] + red[5] + red[7];
  float mu = s * (1.f / E_DIM);
  float rs = rsqrtf(q * (1.f / E_DIM) - mu * mu + 1e-5f);
  const float4* g4 = (const float4*)gw;
  const float4* b4 = (const float4*)bw;
  float4 g0 = g4[t], g1v = g4[t + 256], e0 = b4[t], e1 = b4[t + 256];
  ushort4 o0, o1;
  o0.x = f2bf((a.x - mu) * rs * g0.x + e0.x);
  o0.y = f2bf((a.y - mu) * rs * g0.y + e0.y);
  o0.z = f2bf((a.z - mu) * rs * g0.z + e0.z);
  o0.w = f2bf((a.w - mu) * rs * g0.w + e0.w);
  o1.x = f2bf((c.x - mu) * rs * g1v.x + e1.x);
  o1.y = f2bf((c.y - mu) * rs * g1v.y + e1.y);
  o1.z = f2bf((c.z - mu) * rs * g1v.z + e1.z);
  o1.w = f2bf((c.w - mu) * rs * g1v.w + e1.w);
  ((ushort4*)(out + (size_t)row * E_DIM))[t] = o0;
  ((ushort4*)(out + (size_t)row * E_DIM))[t + 256] = o1;
}

// ==== ALL-weights convert+transpose in ONE dispatch =================
__global__ __launch_bounds__(256) void cvt_all_kernel(
    const float* __restrict__ wq, const float* __restrict__ wk,
    const float* __restrict__ wv, const float* __restrict__ wo,
    const float* __restrict__ w1, const float* __restrict__ w2,
    const float* __restrict__ w3, u16* __restrict__ wqkT,
    u16* __restrict__ wvT, u16* __restrict__ woT, u16* __restrict__ w1T,
    u16* __restrict__ w2T, u16* __restrict__ w3T) {
  __shared__ float tile[32][33];
  const int b = blockIdx.x;
  const float* W;
  u16* WT;
  int Kd, Nd, n0, k0;
  if (b < 16384) {
    int widx = b >> 12, t_ = b & 4095;
    Kd = E_DIM; Nd = E_DIM;
    n0 = (t_ & 63) * 32; k0 = (t_ >> 6) * 32;
    W = widx == 0 ? wq : widx == 1 ? wk : widx == 2 ? wv : wo;
    WT = widx == 0 ? wqkT
         : widx == 1 ? (wqkT + (size_t)E_DIM * E_DIM)
         : widx == 2 ? wvT : woT;
  } else if (b < 49152) {
    int i = b - 16384;
    int widx = i >> 14, t_ = i & 16383;
    Kd = E_DIM; Nd = FFN_DIM;
    n0 = (t_ & 255) * 32; k0 = (t_ >> 8) * 32;
    W = widx ? w2 : w1;
    WT = widx ? w2T : w1T;
  } else {
    int t_ = b - 49152;
    Kd = FFN_DIM; Nd = E_DIM;
    n0 = (t_ & 63) * 32; k0 = (t_ >> 6) * 32;
    W = w3; WT = w3T;
  }
  int tx = threadIdx.x, ty = threadIdx.y;
#pragma unroll
  for (int i = 0; i < 4; i++)
    tile[ty + i * 8][tx] = W[(size_t)(k0 + ty + i * 8) * Nd + n0 + tx];
  __syncthreads();
#pragma unroll
  for (int i = 0; i < 4; i++)
    WT[(size_t)(n0 + ty + i * 8) * Kd + k0 + tx] = f2bf(tile[tx][ty + i * 8]);
}

// ------ add3: out += P0 + P1 (bf16 split-K partials) ----------------
__global__ __launch_bounds__(256) void add3_kernel(float* __restrict__ out,
                                                   const u16* __restrict__ pk) {
  const size_t MN = (size_t)M_ROWS * E_DIM;
  size_t base = ((size_t)blockIdx.x * 256 + threadIdx.x) * 8;
  short8 a = *(const short8*)(pk + base);
  short8 b = *(const short8*)(pk + MN + base);
  float4 o0 = *(float4*)(out + base), o1 = *(float4*)(out + base + 4);
  o0.x += bf2f((u16)a[0]) + bf2f((u16)b[0]);
  o0.y += bf2f((u16)a[1]) + bf2f((u16)b[1]);
  o0.z += bf2f((u16)a[2]) + bf2f((u16)b[2]);
  o0.w += bf2f((u16)a[3]) + bf2f((u16)b[3]);
  o1.x += bf2f((u16)a[4]) + bf2f((u16)b[4]);
  o1.y += bf2f((u16)a[5]) + bf2f((u16)b[5]);
  o1.z += bf2f((u16)a[6]) + bf2f((u16)b[6]);
  o1.w += bf2f((u16)a[7]) + bf2f((u16)b[7]);
  *(float4*)(out + base) = o0;
  *(float4*)(out + base + 4) = o1;
}

// ------ addv: VT = Pv0 + Pv1 (bf16 V^T split-K partials) ------------
__global__ __launch_bounds__(256) void addv_kernel(u16* __restrict__ vt,
                                                   const u16* __restrict__ pv0,
                                                   const u16* __restrict__ pv1) {
  size_t base = ((size_t)blockIdx.x * 256 + threadIdx.x) * 8;
  short8 a = *(const short8*)(pv0 + base);
  short8 b = *(const short8*)(pv1 + base);
  short8 o;
#pragma unroll
  for (int i = 0; i < 8; i++)
    o[i] = (short)f2bf(bf2f((u16)a[i]) + bf2f((u16)b[i]));
  *(short8*)(vt + base) = o;
}

// ==== addwo_ln: out = x + P0 + P1; Hb = LN(out)*g2 + b2 (fused) =====
// One block per row (256 thr x 8 contiguous elems = 2048 = E).
__global__ __launch_bounds__(256) void addwo_ln_kernel(
    float* __restrict__ out, const float* __restrict__ x,
    const u16* __restrict__ p, const float* __restrict__ gw,
    const float* __restrict__ bw, u16* __restrict__ hb) {
  const size_t MN = (size_t)M_ROWS * E_DIM;
  const int t = threadIdx.x;
  const size_t base = (size_t)blockIdx.x * E_DIM + t * 8;
  short8 a = *(const short8*)(p + base);
  short8 b = *(const short8*)(p + MN + base);
  float4 x0 = *(const float4*)(x + base), x1 = *(const float4*)(x + base + 4);
  float o[8];
  o[0] = x0.x + bf2f((u16)a[0]) + bf2f((u16)b[0]);
  o[1] = x0.y + bf2f((u16)a[1]) + bf2f((u16)b[1]);
  o[2] = x0.z + bf2f((u16)a[2]) + bf2f((u16)b[2]);
  o[3] = x0.w + bf2f((u16)a[3]) + bf2f((u16)b[3]);
  o[4] = x1.x + bf2f((u16)a[4]) + bf2f((u16)b[4]);
  o[5] = x1.y + bf2f((u16)a[5]) + bf2f((u16)b[5]);
  o[6] = x1.z + bf2f((u16)a[6]) + bf2f((u16)b[6]);
  o[7] = x1.w + bf2f((u16)a[7]) + bf2f((u16)b[7]);
  *(float4*)(out + base) = make_float4(o[0], o[1], o[2], o[3]);
  *(float4*)(out + base + 4) = make_float4(o[4], o[5], o[6], o[7]);
  float s = 0.f, q = 0.f;
#pragma unroll
  for (int i = 0; i < 8; i++) { s += o[i]; q += o[i] * o[i]; }
  for (int off = 32; off > 0; off >>= 1) {
    s += __shfl_down(s, off);
    q += __shfl_down(q, off);
  }
  __shared__ float red[8];
  if ((t & 63) == 0) { red[(t >> 6) * 2] = s; red[(t >> 6) * 2 + 1] = q; }
  __syncthreads();
  s = red[0] + red[2] + red[4] + red[6];
  q = red[1] + red[3] + red[5] + red[7];
  float mu = s * (1.f / E_DIM);
  float rs = rsqrtf(q * (1.f / E_DIM) - mu * mu + 1e-5f);
  float4 g0 = *(const float4*)(gw + t * 8), g1v = *(const float4*)(gw + t * 8 + 4);
  float4 e0 = *(const float4*)(bw + t * 8), e1 = *(const float4*)(bw + t * 8 + 4);
  short8 hv;
  hv[0] = (short)f2bf((o[0] - mu) * rs * g0.x + e0.x);
  hv[1] = (short)f2bf((o[1] - mu) * rs * g0.y + e0.y);
  hv[2] = (short)f2bf((o[2] - mu) * rs * g0.z + e0.z);
  hv[3] = (short)f2bf((o[3] - mu) * rs * g0.w + e0.w);
  hv[4] = (short)f2bf((o[4] - mu) * rs * g1v.x + e1.x);
  hv[5] = (short)f2bf((o[5] - mu) * rs * g1v.y + e1.y);
  hv[6] = (short)f2bf((o[6] - mu) * rs * g1v.z + e1.z);
  hv[7] = (short)f2bf((o[7] - mu) * rs * g1v.w + e1.w);
  *(short8*)(hb + base) = hv;
}

// ======= GEMM BM_x256xBK64, 8-phase schedule, paired-row LDS ========
// Round-10 structure (proven).  2-D XCD chunking; split-K via kz.
// MODE 0: bf16 C.  MODE 1: Cout(f32)=Extra(f32)+acc.
// MODE 2: Cout(bf16)=silu(Extra bf16)*acc.
// MODE 3: bf16 split-K partial at Cout + kz*M*N.
// MODE 4: bf16 V^T split-K partial: col->(b,t), row=e;
//         dst = kz ? Extra : Cout;  dst[(b*E+row)*T + t].
template <int MODE, int BM_>
__global__ __launch_bounds__(512, 1) void gemm8p(const u16* __restrict__ A,
                                                 const u16* __restrict__ BT,
                                                 void* __restrict__ Cout,
                                                 const void* __restrict__ Extra,
                                                 int N, int K, int lda, int ldb,
                                                 int CX, int CY) {
  constexpr int MM = BM_ / 64;
  constexpr int AUNIT = BM_ * 32;
  __shared__ u16 Abuf[4 * AUNIT];
  __shared__ u16 Bbuf[4 * 8192];
  const int t = threadIdx.x;
  const int w = t >> 6, l = t & 63, g = l >> 4, lq = l & 15;
  const int wm = w >> 2, wn = w & 3;

  const int bid = (blockIdx.z * gridDim.y + blockIdx.y) * gridDim.x + blockIdx.x;
  const int xcd = bid & 7, slot = bid >> 3;
  const int nchx = gridDim.x / CX;
  const int nchy = gridDim.y / CY;
  const int cpz = nchx * nchy;
  const int kz = xcd / cpz;
  const int cid = xcd % cpz;
  const int bx = (cid % nchx) * CX + (slot % CX);
  const int by = (cid / nchx) * CY + (slot / CX);
  const size_t bm = (size_t)by * BM_, bn = (size_t)bx * 256;
  const size_t koff = (size_t)kz * K;

  const int srcrow = ((l >> 3) << 1) | (l & 1);
  const int csrc = ((((l >> 1) & 3) ^ ((l >> 3) & 3)) << 3);
  const u16* aSrc = A + (bm + w * 16 + srcrow) * (size_t)lda + koff + csrc;
  const u16* bSrc = BT + (bn + w * 16 + srcrow) * (size_t)ldb + koff + csrc;
  const int rdoff = (((lq & 1) + 2 * (g ^ ((lq >> 1) & 3))) << 3);

#define STA8(DB, KS, TILE)                                                    \
  {                                                                           \
    u16* Ad = Abuf + (DB) * (2 * AUNIT) + (KS)*AUNIT + w * 512;               \
    const u16* as_ = aSrc + (size_t)(TILE)*64 + (KS)*32;                      \
    async16(Ad, as_);                                                         \
    if constexpr (BM_ == 256) async16(Ad + 4096, as_ + (size_t)128 * lda);    \
  }
#define STB8(DB, KS, TILE)                                                    \
  {                                                                           \
    u16* Bd = Bbuf + (DB)*16384 + (KS)*8192 + w * 512;                        \
    const u16* bs_ = bSrc + (size_t)(TILE)*64 + (KS)*32;                      \
    async16(Bd, bs_);                                                         \
    async16(Bd + 4096, bs_ + (size_t)128 * ldb);                              \
  }
#define RDA8(DB, KS, MH)                                                      \
  _Pragma("unroll") for (int mm = 0; mm < MM; ++mm)                           \
      af[mm] = *(const short8*)(Abuf + (DB) * (2 * AUNIT) + (KS)*AUNIT +      \
                                (wm * (BM_ / 4) + (MH) * (BM_ / 8) + mm * 8 + \
                                 (lq >> 1)) * 64 + rdoff);
#define RDB8(DB, KS)                                                          \
  _Pragma("unroll") for (int nn = 0; nn < 4; ++nn)                            \
      bf[nn] = *(const short8*)(Bbuf + (DB)*16384 + (KS)*8192 +               \
                                (wn * 32 + nn * 8 + (lq >> 1)) * 64 + rdoff);
#define MM168(MH)                                                             \
  _Pragma("unroll") for (int mm = 0; mm < MM; ++mm)                           \
      _Pragma("unroll") for (int nn = 0; nn < 4; ++nn)                        \
          acc[(MH)*MM + mm][nn] = __builtin_amdgcn_mfma_f32_16x16x32_bf16(    \
              af[mm], bf[nn], acc[(MH)*MM + mm][nn], 0, 0, 0);
#define SYNCA                                                                 \
  __builtin_amdgcn_s_barrier();                                               \
  asm volatile("s_waitcnt lgkmcnt(0)" ::: "memory");                          \
  __builtin_amdgcn_sched_barrier(0);                                          \
  __builtin_amdgcn_s_setprio(1);
#define ENDP __builtin_amdgcn_s_setprio(0);
#define BAR2 __builtin_amdgcn_s_barrier();
#define WAITN                                                                 \
  if constexpr (BM_ == 256) asm volatile("s_waitcnt vmcnt(8)" ::: "memory");  \
  else                      asm volatile("s_waitcnt vmcnt(6)" ::: "memory");
#define WAITH                                                                 \
  if constexpr (BM_ == 256) asm volatile("s_waitcnt vmcnt(4)" ::: "memory");  \
  else                      asm volatile("s_waitcnt vmcnt(3)" ::: "memory");

  const int NT = K >> 6, NI = NT >> 1;
  f32x4 acc[2 * MM][4] = {};
  short8 af[MM > 4 ? MM : 4], bf[4];

  STA8(0, 0, 0); STB8(0, 0, 0);
  STA8(0, 1, 0); STB8(0, 1, 0);
  STA8(1, 0, 1); STB8(1, 0, 1);
  WAITN;
  BAR2;

  for (int j = 0; j < NI; ++j) {
    const int t1 = 2 * j + 1, t2 = 2 * j + 2, t3 = 2 * j + 3;
    const bool s2 = t2 < NT, s3 = t3 < NT, lastI = (j + 1 == NI);
    RDB8(0, 0); RDA8(0, 0, 0);
    STA8(1, 1, t1);
    SYNCA; MM168(0); ENDP; BAR2;
    RDA8(0, 0, 1);
    STB8(1, 1, t1);
    SYNCA; MM168(1); ENDP;
    WAITN;
    BAR2;
    RDB8(0, 1); RDA8(0, 1, 0);
    if (s2) STA8(0, 0, t2);
    SYNCA; MM168(0); ENDP; BAR2;
    RDA8(0, 1, 1);
    if (s2) STB8(0, 0, t2);
    SYNCA; MM168(1); ENDP;
    if (lastI) { WAITH; } else { WAITN; }
    BAR2;
    RDB8(1, 0); RDA8(1, 0, 0);
    if (s2) STA8(0, 1, t2);
    SYNCA; MM168(0); ENDP; BAR2;
    RDA8(1, 0, 1);
    if (s2) STB8(0, 1, t2);
    SYNCA; MM168(1); ENDP;
    if (lastI) { asm volatile("s_waitcnt vmcnt(0)" ::: "memory"); } else { WAITN; }
    BAR2;
    RDB8(1, 1); RDA8(1, 1, 0);
    if (s3) STA8(1, 0, t3);
    SYNCA; MM168(0); ENDP; BAR2;
    RDA8(1, 1, 1);
    if (s3) STB8(1, 0, t3);
    SYNCA; MM168(1); ENDP;
    if (!lastI) { WAITN; }
    BAR2;
  }
#undef STA8
#undef STB8
#undef RDA8
#undef RDB8
#undef MM168
#undef SYNCA
#undef ENDP
#undef BAR2
#undef WAITN
#undef WAITH

  const size_t mn = (size_t)gridDim.y * BM_ * (size_t)N;
#pragma unroll
  for (int m = 0; m < 2 * MM; m++) {
    size_t row = bm + wm * (BM_ / 2) + m * 16 + 4 * g;
#pragma unroll
    for (int n = 0; n < 4; n++) {
      size_t col = bn + wn * 64 + n * 16 + lq;
#pragma unroll
      for (int r = 0; r < 4; r++) {
        size_t idx = (row + r) * (size_t)N + col;
        if constexpr (MODE == 0) {
          ((u16*)Cout)[idx] = f2bf(acc[m][n][r]);
        } else if constexpr (MODE == 1) {
          ((float*)Cout)[idx] = ((const float*)Extra)[idx] + acc[m][n][r];
        } else if constexpr (MODE == 2) {
          float a = bf2f(((const u16*)Extra)[idx]);
          float sil = a / (1.f + exp2f(-1.4426950408889634f * a));
          ((u16*)Cout)[idx] = f2bf(sil * acc[m][n][r]);
        } else if constexpr (MODE == 3) {
          ((u16*)Cout)[(size_t)kz * mn + idx] = f2bf(acc[m][n][r]);
        } else {
          size_t bb = col >> 11, tt = col & 2047;
          u16* dst = kz ? (u16*)Extra : (u16*)Cout;
          dst[(bb * E_DIM + row + r) * (size_t)T_SEQ + tt] = f2bf(acc[m][n][r]);
        }
      }
    }
  }
}

// ==== FUSED SwiGLU FFN GEMM: gated = silu(A@w1T^T) * (A@w2T^T) ======
__global__ __launch_bounds__(512, 1) void gemm_ffn(const u16* __restrict__ A,
                                                   const u16* __restrict__ B1T,
                                                   const u16* __restrict__ B2T,
                                                   u16* __restrict__ Cout,
                                                   int N, int K, int lda, int ldb,
                                                   int CX, int CY) {
  constexpr int AUNIT = 8192;
  __shared__ u16 Abuf[4 * AUNIT];
  __shared__ u16 Bbuf[4 * AUNIT];
  const int t = threadIdx.x;
  const int w = t >> 6, l = t & 63, g = l >> 4, lq = l & 15;
  const int wm = w >> 2, wn = w & 3;

  const int bid = blockIdx.y * gridDim.x + blockIdx.x;
  const int xcd = bid & 7, slot = bid >> 3;
  const int nchx = gridDim.x / CX;
  const int cid = xcd;
  const int bx = (cid % nchx) * CX + (slot % CX);
  const int by = (cid / nchx) * CY + (slot / CX);
  const size_t bm = (size_t)by * 256;
  const size_t c0 = (size_t)bx * 128;

  const int srcrow = ((l >> 3) << 1) | (l & 1);
  const int csrc = ((((l >> 1) & 3) ^ ((l >> 3) & 3)) << 3);
  const u16* aSrc = A + (bm + w * 16 + srcrow) * (size_t)lda + csrc;
  const u16* b1Src = B1T + (c0 + w * 16 + srcrow) * (size_t)ldb + csrc;
  const u16* b2Src = B2T + (c0 + w * 16 + srcrow) * (size_t)ldb + csrc;
  const int rdoff = (((lq & 1) + 2 * (g ^ ((lq >> 1) & 3))) << 3);

#define STA8(DB, KS, TILE)                                                    \
  {                                                                           \
    u16* Ad = Abuf + (DB) * (2 * AUNIT) + (KS)*AUNIT + w * 512;               \
    const u16* as_ = aSrc + (size_t)(TILE)*64 + (KS)*32;                      \
    async16(Ad, as_);                                                         \
    async16(Ad + 4096, as_ + (size_t)128 * lda);                              \
  }
#define STB8(DB, KS, TILE)                                                    \
  {                                                                           \
    u16* Bd = Bbuf + (DB) * (2 * AUNIT) + (KS)*AUNIT + w * 512;               \
    size_t off_ = (size_t)(TILE)*64 + (KS)*32;                                \
    async16(Bd, b1Src + off_);                                                \
    async16(Bd + 4096, b2Src + off_);                                         \
  }
#define RDA8(DB, KS, MH)                                                      \
  _Pragma("unroll") for (int mm = 0; mm < 4; ++mm)                            \
      af[mm] = *(const short8*)(Abuf + (DB) * (2 * AUNIT) + (KS)*AUNIT +      \
                                (wm * 64 + (MH)*32 + mm * 8 + (lq >> 1)) *    \
                                    64 + rdoff);
#define RDB8(DB, KS)                                                          \
  _Pragma("unroll") for (int nn = 0; nn < 4; ++nn)                            \
      bf[nn] = *(const short8*)(Bbuf + (DB) * (2 * AUNIT) + (KS)*AUNIT +      \
                                (wn * 32 + nn * 8 + (lq >> 1)) * 64 + rdoff);
#define MM168(MH)                                                             \
  _Pragma("unroll") for (int mm = 0; mm < 4; ++mm)                            \
      _Pragma("unroll") for (int nn = 0; nn < 4; ++nn)                        \
          acc[(MH)*4 + mm][nn] = __builtin_amdgcn_mfma_f32_16x16x32_bf16(     \
              af[mm], bf[nn], acc[(MH)*4 + mm][nn], 0, 0, 0);
#define SYNCA                                                                 \
  __builtin_amdgcn_s_barrier();                                               \
  asm volatile("s_waitcnt lgkmcnt(0)" ::: "memory");                          \
  __builtin_amdgcn_sched_barrier(0);                                          \
  __builtin_amdgcn_s_setprio(1);
#define ENDP __builtin_amdgcn_s_setprio(0);
#define BAR2 __builtin_amdgcn_s_barrier();
#define WAITN asm volatile("s_waitcnt vmcnt(8)" ::: "memory");
#define WAITH asm volatile("s_waitcnt vmcnt(4)" ::: "memory");

  const int NT = K >> 6, NI = NT >> 1;
  f32x4 acc[8][4] = {};
  short8 af[4], bf[4];

  STA8(0, 0, 0); STB8(0, 0, 0);
  STA8(0, 1, 0); STB8(0, 1, 0);
  STA8(1, 0, 1); STB8(1, 0, 1);
  WAITN;
  BAR2;

  for (int j = 0; j < NI; ++j) {
    const int t1 = 2 * j + 1, t2 = 2 * j + 2, t3 = 2 * j + 3;
    const bool s2 = t2 < NT, s3 = t3 < NT, lastI = (j + 1 == NI);
    RDB8(0, 0); RDA8(0, 0, 0);
    STA8(1, 1, t1);
    SYNCA; MM168(0); ENDP; BAR2;
    RDA8(0, 0, 1);
    STB8(1, 1, t1);
    SYNCA; MM168(1); ENDP;
    WAITN;
    BAR2;
    RDB8(0, 1); RDA8(0, 1, 0);
    if (s2) STA8(0, 0, t2);
    SYNCA; MM168(0); ENDP; BAR2;
    RDA8(0, 1, 1);
    if (s2) STB8(0, 0, t2);
    SYNCA; MM168(1); ENDP;
    if (lastI) { WAITH; } else { WAITN; }
    BAR2;
    RDB8(1, 0); RDA8(1, 0, 0);
    if (s2) STA8(0, 1, t2);
    SYNCA; MM168(0); ENDP; BAR2;
    RDA8(1, 0, 1);
    if (s2) STB8(0, 1, t2);
    SYNCA; MM168(1); ENDP;
    if (lastI) { asm volatile("s_waitcnt vmcnt(0)" ::: "memory"); } else { WAITN; }
    BAR2;
    RDB8(1, 1); RDA8(1, 1, 0);
    if (s3) STA8(1, 0, t3);
    SYNCA; MM168(0); ENDP; BAR2;
    RDA8(1, 1, 1);
    if (s3) STB8(1, 0, t3);
    SYNCA; MM168(1); ENDP;
    if (!lastI) { WAITN; }
    BAR2;
  }
#undef STA8
#undef STB8
#undef RDA8
#undef RDB8
#undef MM168
#undef SYNCA
#undef ENDP
#undef BAR2
#undef WAITN
#undef WAITH

  // ---- SwiGLU epilogue: exchange u2 via (dead) LDS, gate, store ----
  const int reg = wm * 2 + ((wn >= 2) ? (wn - 2) : wn);
  float* fb = (float*)((reg < 2 ? Abuf : Bbuf) + (reg & 1) * 16384);
  if (wn >= 2) {
#pragma unroll
    for (int m = 0; m < 8; m++)
#pragma unroll
      for (int n = 0; n < 4; n++)
#pragma unroll
        for (int r = 0; r < 4; r++) {
          int lrow = m * 16 + 4 * g + r;
          int pcol = (n * 16 + lq) ^ ((g & 1) << 4);
          fb[lrow * 64 + pcol] = acc[m][n][r];
        }
  }
  __syncthreads();
  if (wn < 2) {
#pragma unroll
    for (int m = 0; m < 8; m++) {
      size_t row = bm + wm * 128 + m * 16 + 4 * g;
#pragma unroll
      for (int n = 0; n < 4; n++) {
        size_t col = c0 + wn * 64 + n * 16 + lq;
#pragma unroll
        for (int r = 0; r < 4; r++) {
          int lrow = m * 16 + 4 * g + r;
          int pcol = (n * 16 + lq) ^ ((g & 1) << 4);
          float u1 = acc[m][n][r];
          float u2 = fb[lrow * 64 + pcol];
          float sil = u1 / (1.f + exp2f(-1.4426950408889634f * u1));
          Cout[(row + r) * (size_t)N + col] = f2bf(sil * u2);
        }
      }
    }
  }
}

// ----------------- causal flash attention (LDS-staged) --------------
// grid (T/128, B*H); 4 waves/block; wave owns 32 q-rows (2 rg of 16).
// Q,K from fused QK buffer [B*T][4096] (q cols 0..2047, k cols 2048+).
// Causal load-balance remap: blocks y>=16 flip qx -> 15-qx (r18 win).
__global__ __launch_bounds__(256, 2) void attn_kernel(const u16* __restrict__ QK,
                                                      const u16* __restrict__ VT,
                                                      u16* __restrict__ CTX) {
  __shared__ u16 Ks[64 * 128];
  __shared__ u16 Vs[128 * 64];
  __shared__ u16 P_all[4][32 * 72];
  const int t = threadIdx.x;
  const int w = t >> 6, l = t & 63, g = l >> 4, lq = l & 15;
  u16* P = P_all[w];
  const int qx = (blockIdx.y & 16) ? (15 - blockIdx.x) : blockIdx.x;
  const int q0blk = qx * 128;
  const int q0w = q0blk + w * 32;
  const int bh = blockIdx.y, b = bh >> 4, h = bh & 15;
  const u16* qp = QK + (size_t)b * T_SEQ * QKS + h * D_HEAD;
  const u16* kp = qp + E_DIM;
  const u16* vp = VT + ((size_t)b * E_DIM + h * D_HEAD) * T_SEQ;

  short8 qf[2][4];
#pragma unroll
  for (int rg = 0; rg < 2; rg++)
#pragma unroll
    for (int ks = 0; ks < 4; ks++)
      qf[rg][ks] =
          *(const short8*)(qp + (size_t)(q0w + rg * 16 + lq) * QKS + ks * 32 + g * 8);

  f32x4 acc[2][8] = {};
  float m2[2][4], ls[2][4];
#pragma unroll
  for (int rg = 0; rg < 2; rg++)
#pragma unroll
    for (int r = 0; r < 4; r++) { m2[rg][r] = -1e30f; ls[rg][r] = 0.f; }
  const float sc = 0.08838834764831845f * 1.4426950408889634f;

  const int kRow0 = 16 * w + (l >> 4);
  const int kChunk = l & 15;
  const int vRow0 = 32 * w + (l >> 3);
  const int vChunk = l & 7;

  for (int kv0 = 0; kv0 < q0blk + 128; kv0 += 64) {
#pragma unroll
    for (int j = 0; j < 4; j++) {
      int R = kRow0 + 4 * j;
      async16(Ks + (16 * w + 4 * j) * 128,
              kp + (size_t)(kv0 + R) * QKS + ((kChunk ^ (R & 7)) << 3));
    }
#pragma unroll
    for (int j = 0; j < 4; j++) {
      int D = vRow0 + 8 * j;
      async16(Vs + (32 * w + 8 * j) * 64,
              vp + (size_t)D * T_SEQ + kv0 + ((vChunk ^ (D & 7)) << 3));
    }
    __syncthreads();

#pragma unroll
    for (int rg = 0; rg < 2; rg++) {
      const int rb = q0w + rg * 16;
      if (kv0 > rb + 15) continue;
      f32x4 s[4];
      __builtin_amdgcn_s_setprio(1);
#pragma unroll
      for (int ct = 0; ct < 4; ct++) {
        s[ct] = f32x4{0.f, 0.f, 0.f, 0.f};
#pragma unroll
        for (int ks = 0; ks < 4; ks++) {
          short8 kf = *(const short8*)(Ks + (ct * 16 + lq) * 128 +
                                       (((ks * 4 + g) ^ (lq & 7)) << 3));
          s[ct] = __builtin_amdgcn_mfma_f32_16x16x32_bf16(qf[rg][ks], kf, s[ct], 0, 0, 0);
        }
      }
      __builtin_amdgcn_s_setprio(0);
      float sv[4][4];
#pragma unroll
      for (int ct = 0; ct < 4; ct++)
#pragma unroll
        for (int r = 0; r < 4; r++) sv[ct][r] = s[ct][r] * sc;
      if (kv0 + 64 > rb) {
#pragma unroll
        for (int ct = 0; ct < 4; ct++)
#pragma unroll
          for (int r = 0; r < 4; r++)
            if (kv0 + ct * 16 + lq > rb + 4 * g + r) sv[ct][r] = -1e30f;
      }
      float mx[4];
#pragma unroll
      for (int r = 0; r < 4; r++)
        mx[r] = fmaxf(fmaxf(sv[0][r], sv[1][r]), fmaxf(sv[2][r], sv[3][r]));
#pragma unroll
      for (int off = 1; off < 16; off <<= 1)
#pragma unroll
        for (int r = 0; r < 4; r++) mx[r] = fmaxf(mx[r], __shfl_xor(mx[r], off));
#pragma unroll
      for (int r = 0; r < 4; r++) {
        float mn = fmaxf(m2[rg][r], mx[r]);
        float sca = exp2f(m2[rg][r] - mn);
        m2[rg][r] = mn;
        float sum = 0.f;
#pragma unroll
        for (int ct = 0; ct < 4; ct++) {
          float pv = exp2f(sv[ct][r] - mn);
          sum += pv;
          P[(rg * 16 + 4 * g + r) * 72 + ct * 16 + lq] = f2bf(pv);
        }
        ls[rg][r] = ls[rg][r] * sca + sum;
#pragma unroll
        for (int n = 0; n < 8; n++) acc[rg][n][r] *= sca;
      }
      short8 pa[2];
#pragma unroll
      for (int ks2 = 0; ks2 < 2; ks2++)
        pa[ks2] = *(const short8*)(P + (rg * 16 + lq) * 72 + ks2 * 32 + g * 8);
      __builtin_amdgcn_s_setprio(1);
#pragma unroll
      for (int n = 0; n < 8; n++)
#pragma unroll
        for (int ks2 = 0; ks2 < 2; ks2++) {
          short8 vf = *(const short8*)(Vs + (n * 16 + lq) * 64 +
                                       (((ks2 * 4 + g) ^ (lq & 7)) << 3));
          acc[rg][n] = __builtin_amdgcn_mfma_f32_16x16x32_bf16(pa[ks2], vf, acc[rg][n], 0, 0, 0);
        }
      __builtin_amdgcn_s_setprio(0);
    }
    __syncthreads();
  }

#pragma unroll
  for (int rg = 0; rg < 2; rg++) {
#pragma unroll
    for (int off = 1; off < 16; off <<= 1)
#pragma unroll
      for (int r = 0; r < 4; r++) ls[rg][r] += __shfl_xor(ls[rg][r], off);
  }
  u16* cp = CTX + ((size_t)b * T_SEQ + q0w) * E_DIM + h * D_HEAD;
#pragma unroll
  for (int rg = 0; rg < 2; rg++) {
    float inv[4];
#pragma unroll
    for (int r = 0; r < 4; r++) inv[r] = 1.f / ls[rg][r];
#pragma unroll
    for (int n = 0; n < 8; n++)
#pragma unroll
      for (int r = 0; r < 4; r++)
        cp[(size_t)(rg * 16 + 4 * g + r) * E_DIM + n * 16 + lq] =
            f2bf(acc[rg][n][r] * inv[r]);
  }
}

extern "C" void kernel_launch(void* const* d_in, const int* in_sizes, int n_in,
                              void* d_out, int out_size, void* d_ws, size_t ws_size,
                              hipStream_t stream) {
  (void)in_sizes; (void)n_in; (void)out_size; (void)ws_size;
  const float* x  = (const float*)d_in[0];
  const float* g1 = (const float*)d_in[1];
  const float* b1 = (const float*)d_in[2];
  const float* wq = (const float*)d_in[3];
  const float* wk = (const float*)d_in[4];
  const float* wv = (const float*)d_in[5];
  const float* wo = (const float*)d_in[6];
  const float* g2 = (const float*)d_in[7];
  const float* b2 = (const float*)d_in[8];
  const float* w1 = (const float*)d_in[9];
  const float* w2 = (const float*)d_in[10];
  const float* w3 = (const float*)d_in[11];
  float* out = (float*)d_out;

  const size_t EE = (size_t)E_DIM * E_DIM;
  const size_t EE2 = EE * 2;
  const size_t EF2 = (size_t)E_DIM * FFN_DIM * 2;
  const size_t ME2 = (size_t)M_ROWS * E_DIM * 2;
  char* p = (char*)d_ws;
  u16* wqkT = (u16*)p; p += 2 * EE2;   // [2E][E]: rows 0..E-1 = wq^T
  u16* wvT = (u16*)p; p += EE2;
  u16* woT = (u16*)p; p += EE2;
  u16* w1T = (u16*)p; p += EF2;
  u16* w2T = (u16*)p; p += EF2;
  u16* w3T = (u16*)p; p += EF2;
  u16* Hb  = (u16*)p; p += ME2;
  u16* QKb = (u16*)p; p += (size_t)M_ROWS * QKS * 2;  // [4096][4096]
  u16* VTb = (u16*)p; p += ME2;
  u16* CTXb = (u16*)p; p += ME2;
  u16* U1b = QKb;    // gated (67MB) reuses QKb+VTb+CTXb
  u16* Pv0 = wqkT;   // V^T kz=0 partial (wqkT dead after QK GEMM)
  u16* Pv1 = CTXb;   // V^T kz=1 partial (CTXb untouched until attn)
  u16* Pwo = wqkT;   // WO split-K partials (33.55MB = wqkT exactly;
                     // Pv0 consumed by addv before WO)
  u16* Pk = wqkT;    // w3 split-K partials (wqkT dead after addwo_ln)

  dim3 blk32(32, 8);
  // ALL weights -> bf16 transposed, one dispatch (65536 blocks)
  cvt_all_kernel<<<65536, blk32, 0, stream>>>(wq, wk, wv, wo, w1, w2, w3,
                                              wqkT, wvT, woT, w1T, w2T, w3T);

  // attention block
  ln_kernel<<<M_ROWS, 256, 0, stream>>>(x, g1, b1, Hb);
  // fused QK GEMM at BM256: grid (16,16) = 256 blocks; chunk 4x8
  gemm8p<0, 256><<<dim3(QKS / 256, M_ROWS / 256), 512, 0, stream>>>(
      Hb, wqkT, QKb, nullptr, QKS, E_DIM, E_DIM, E_DIM, 4, 8);
  // V^T direct: A=wvT (M=E), B=Hb (N=B*T), split-K=2:
  // grid (16,8,2) = 256 blocks; chunk 8x4; kz=0 -> Pv0, kz=1 -> Pv1
  gemm8p<4, 256><<<dim3(M_ROWS / 256, E_DIM / 256, 2), 512, 0, stream>>>(
      wvT, Hb, Pv0, Pv1, M_ROWS, E_DIM / 2, E_DIM, E_DIM, 8, 4);
  addv_kernel<<<4096, 256, 0, stream>>>(VTb, Pv0, Pv1);
  attn_kernel<<<dim3(T_SEQ / 128, 2 * N_HEAD), 256, 0, stream>>>(QKb, VTb, CTXb);
  // WO at BM256 split-K=2: grid (8,16,2) = 256 blocks; chunk 4x8;
  // bf16 partials -> Pwo
  gemm8p<3, 256><<<dim3(E_DIM / 256, M_ROWS / 256, 2), 512, 0, stream>>>(
      CTXb, woT, Pwo, nullptr, E_DIM, E_DIM / 2, E_DIM, E_DIM, 4, 8);
  // fused: out = x + Pwo0 + Pwo1;  Hb = LN(out)*g2 + b2
  addwo_ln_kernel<<<M_ROWS, 256, 0, stream>>>(out, x, Pwo, g2, b2, Hb);

  // SwiGLU MLP block
  // fused FFN1+FFN2+silu-gate: grid (64,16) = 1024 blocks; chunk 16x8
  gemm_ffn<<<dim3(FFN_DIM / 128, M_ROWS / 256), 512, 0, stream>>>(
      Hb, w1T, w2T, U1b, FFN_DIM, E_DIM, E_DIM, E_DIM, 16, 8);
  // w3: BM256 split-K=2: grid (8,16,2) = 256 blocks; chunk 4x8 per kz
  gemm8p<3, 256><<<dim3(E_DIM / 256, M_ROWS / 256, 2), 512, 0, stream>>>(
      U1b, w3T, Pk, nullptr, E_DIM, FFN_DIM / 2, FFN_DIM, FFN_DIM, 4, 8);
  add3_kernel<<<4096, 256, 0, stream>>>(out, Pk);
}

// Round 22
// 831.823 us; speedup vs baseline: 1.2990x; 1.0039x over previous
//
#include <hip/hip_runtime.h>

// Transformer layer, bf16 MFMA compute, fp32 I/O.
// B=2 T=2048 E=2048 H=16 DH=128 FFN=8192. Needs ~230MB workspace.

#define T_SEQ 2048
#define E_DIM 2048
#define N_HEAD 16
#define D_HEAD 128
#define FFN_DIM 8192
#define M_ROWS 4096  // B*T
#define QKS (2 * E_DIM)  // fused QK output row stride

typedef unsigned short u16;
typedef short short8 __attribute__((ext_vector_type(8)));
typedef float f32x4 __attribute__((ext_vector_type(4)));

#define DEV __device__ __forceinline__

DEV u16 f2bf(float f) {
  unsigned u = __float_as_uint(f);
  u += 0x7fffu + ((u >> 16) & 1u);
  return (u16)(u >> 16);
}
DEV float bf2f(u16 h) { return __uint_as_float(((unsigned)h) << 16); }

DEV void async16(void* lds, const void* g) {
  __builtin_amdgcn_global_load_lds((const __attribute__((address_space(1))) void*)g,
                                   (__attribute__((address_space(3))) void*)lds, 16, 0, 0);
}

// ==== PREP: all weight cvt+transpose AND LayerNorm1, ONE dispatch ===
// block ranges: [0,16384): wq/wk/wv/wo (4096 tiles each);
// [16384,49152): w1/w2 (16384 each); [49152,65536): w3;
// [65536,69632): LN1 row (b-65536) of x -> Hb (bf16).
__global__ __launch_bounds__(256) void prep_kernel(
    const float* __restrict__ wq, const float* __restrict__ wk,
    const float* __restrict__ wv, const float* __restrict__ wo,
    const float* __restrict__ w1, const float* __restrict__ w2,
    const float* __restrict__ w3, u16* __restrict__ wqkT,
    u16* __restrict__ wvT, u16* __restrict__ woT, u16* __restrict__ w1T,
    u16* __restrict__ w2T, u16* __restrict__ w3T,
    const float* __restrict__ x, const float* __restrict__ g1,
    const float* __restrict__ b1, u16* __restrict__ hb) {
  __shared__ float tile[32][33];
  __shared__ float red[8];
  const int b = blockIdx.x;
  const int tx = threadIdx.x, ty = threadIdx.y;
  if (b >= 65536) {
    // ---- LayerNorm1 path: one row per block ----
    const int row = b - 65536;
    const int t = ty * 32 + tx;
    const float4* xr = (const float4*)(x + (size_t)row * E_DIM);
    float4 a = xr[t], c = xr[t + 256];
    float s = a.x + a.y + a.z + a.w + c.x + c.y + c.z + c.w;
    float q = a.x * a.x + a.y * a.y + a.z * a.z + a.w * a.w +
              c.x * c.x + c.y * c.y + c.z * c.z + c.w * c.w;
    for (int off = 32; off > 0; off >>= 1) {
      s += __shfl_down(s, off);
      q += __shfl_down(q, off);
    }
    if ((t & 63) == 0) { red[(t >> 6) * 2] = s; red[(t >> 6) * 2 + 1] = q; }
    __syncthreads();
    s = red[0] + red[2] + red[4] + red[6];
    q = red[1] + red[3] + red[5] + red[7];
    float mu = s * (1.f / E_DIM);
    float rs = rsqrtf(q * (1.f / E_DIM) - mu * mu + 1e-5f);
    const float4* g4 = (const float4*)g1;
    const float4* b4 = (const float4*)b1;
    float4 g0 = g4[t], g1v = g4[t + 256], e0 = b4[t], e1 = b4[t + 256];
    ushort4 o0, o1;
    o0.x = f2bf((a.x - mu) * rs * g0.x + e0.x);
    o0.y = f2bf((a.y - mu) * rs * g0.y + e0.y);
    o0.z = f2bf((a.z - mu) * rs * g0.z + e0.z);
    o0.w = f2bf((a.w - mu) * rs * g0.w + e0.w);
    o1.x = f2bf((c.x - mu) * rs * g1v.x + e1.x);
    o1.y = f2bf((c.y - mu) * rs * g1v.y + e1.y);
    o1.z = f2bf((c.z - mu) * rs * g1v.z + e1.z);
    o1.w = f2bf((c.w - mu) * rs * g1v.w + e1.w);
    ((ushort4*)(hb + (size_t)row * E_DIM))[t] = o0;
    ((ushort4*)(hb + (size_t)row * E_DIM))[t + 256] = o1;
    return;
  }
  // ---- weight convert+transpose path ----
  const float* W;
  u16* WT;
  int Kd, Nd, n0, k0;
  if (b < 16384) {
    int widx = b >> 12, t_ = b & 4095;
    Kd = E_DIM; Nd = E_DIM;
    n0 = (t_ & 63) * 32; k0 = (t_ >> 6) * 32;
    W = widx == 0 ? wq : widx == 1 ? wk : widx == 2 ? wv : wo;
    WT = widx == 0 ? wqkT
         : widx == 1 ? (wqkT + (size_t)E_DIM * E_DIM)
         : widx == 2 ? wvT : woT;
  } else if (b < 49152) {
    int i = b - 16384;
    int widx = i >> 14, t_ = i & 16383;
    Kd = E_DIM; Nd = FFN_DIM;
    n0 = (t_ & 255) * 32; k0 = (t_ >> 8) * 32;
    W = widx ? w2 : w1;
    WT = widx ? w2T : w1T;
  } else {
    int t_ = b - 49152;
    Kd = FFN_DIM; Nd = E_DIM;
    n0 = (t_ & 63) * 32; k0 = (t_ >> 6) * 32;
    W = w3; WT = w3T;
  }
#pragma unroll
  for (int i = 0; i < 4; i++)
    tile[ty + i * 8][tx] = W[(size_t)(k0 + ty + i * 8) * Nd + n0 + tx];
  __syncthreads();
#pragma unroll
  for (int i = 0; i < 4; i++)
    WT[(size_t)(n0 + ty + i * 8) * Kd + k0 + tx] = f2bf(tile[tx][ty + i * 8]);
}

// ------ add3: out += P0 + P1 (bf16 split-K partials) ----------------
__global__ __launch_bounds__(256) void add3_kernel(float* __restrict__ out,
                                                   const u16* __restrict__ pk) {
  const size_t MN = (size_t)M_ROWS * E_DIM;
  size_t base = ((size_t)blockIdx.x * 256 + threadIdx.x) * 8;
  short8 a = *(const short8*)(pk + base);
  short8 b = *(const short8*)(pk + MN + base);
  float4 o0 = *(float4*)(out + base), o1 = *(float4*)(out + base + 4);
  o0.x += bf2f((u16)a[0]) + bf2f((u16)b[0]);
  o0.y += bf2f((u16)a[1]) + bf2f((u16)b[1]);
  o0.z += bf2f((u16)a[2]) + bf2f((u16)b[2]);
  o0.w += bf2f((u16)a[3]) + bf2f((u16)b[3]);
  o1.x += bf2f((u16)a[4]) + bf2f((u16)b[4]);
  o1.y += bf2f((u16)a[5]) + bf2f((u16)b[5]);
  o1.z += bf2f((u16)a[6]) + bf2f((u16)b[6]);
  o1.w += bf2f((u16)a[7]) + bf2f((u16)b[7]);
  *(float4*)(out + base) = o0;
  *(float4*)(out + base + 4) = o1;
}

// ------ addv: VT = Pv0 + Pv1 (bf16 V^T split-K partials) ------------
__global__ __launch_bounds__(256) void addv_kernel(u16* __restrict__ vt,
                                                   const u16* __restrict__ pv0,
                                                   const u16* __restrict__ pv1) {
  size_t base = ((size_t)blockIdx.x * 256 + threadIdx.x) * 8;
  short8 a = *(const short8*)(pv0 + base);
  short8 b = *(const short8*)(pv1 + base);
  short8 o;
#pragma unroll
  for (int i = 0; i < 8; i++)
    o[i] = (short)f2bf(bf2f((u16)a[i]) + bf2f((u16)b[i]));
  *(short8*)(vt + base) = o;
}

// ==== addwo_ln: out = x + P0 + P1; Hb = LN(out)*g2 + b2 (fused) =====
__global__ __launch_bounds__(256) void addwo_ln_kernel(
    float* __restrict__ out, const float* __restrict__ x,
    const u16* __restrict__ p, const float* __restrict__ gw,
    const float* __restrict__ bw, u16* __restrict__ hb) {
  const size_t MN = (size_t)M_ROWS * E_DIM;
  const int t = threadIdx.x;
  const size_t base = (size_t)blockIdx.x * E_DIM + t * 8;
  short8 a = *(const short8*)(p + base);
  short8 b = *(const short8*)(p + MN + base);
  float4 x0 = *(const float4*)(x + base), x1 = *(const float4*)(x + base + 4);
  float o[8];
  o[0] = x0.x + bf2f((u16)a[0]) + bf2f((u16)b[0]);
  o[1] = x0.y + bf2f((u16)a[1]) + bf2f((u16)b[1]);
  o[2] = x0.z + bf2f((u16)a[2]) + bf2f((u16)b[2]);
  o[3] = x0.w + bf2f((u16)a[3]) + bf2f((u16)b[3]);
  o[4] = x1.x + bf2f((u16)a[4]) + bf2f((u16)b[4]);
  o[5] = x1.y + bf2f((u16)a[5]) + bf2f((u16)b[5]);
  o[6] = x1.z + bf2f((u16)a[6]) + bf2f((u16)b[6]);
  o[7] = x1.w + bf2f((u16)a[7]) + bf2f((u16)b[7]);
  *(float4*)(out + base) = make_float4(o[0], o[1], o[2], o[3]);
  *(float4*)(out + base + 4) = make_float4(o[4], o[5], o[6], o[7]);
  float s = 0.f, q = 0.f;
#pragma unroll
  for (int i = 0; i < 8; i++) { s += o[i]; q += o[i] * o[i]; }
  for (int off = 32; off > 0; off >>= 1) {
    s += __shfl_down(s, off);
    q += __shfl_down(q, off);
  }
  __shared__ float red[8];
  if ((t & 63) == 0) { red[(t >> 6) * 2] = s; red[(t >> 6) * 2 + 1] = q; }
  __syncthreads();
  s = red[0] + red[2] + red[4] + red[6];
  q = red[1] + red[3] + red[5] + red[7];
  float mu = s * (1.f / E_DIM);
  float rs = rsqrtf(q * (1.f / E_DIM) - mu * mu + 1e-5f);
  float4 g0 = *(const float4*)(gw + t * 8), g1v = *(const float4*)(gw + t * 8 + 4);
  float4 e0 = *(const float4*)(bw + t * 8), e1 = *(const float4*)(bw + t * 8 + 4);
  short8 hv;
  hv[0] = (short)f2bf((o[0] - mu) * rs * g0.x + e0.x);
  hv[1] = (short)f2bf((o[1] - mu) * rs * g0.y + e0.y);
  hv[2] = (short)f2bf((o[2] - mu) * rs * g0.z + e0.z);
  hv[3] = (short)f2bf((o[3] - mu) * rs * g0.w + e0.w);
  hv[4] = (short)f2bf((o[4] - mu) * rs * g1v.x + e1.x);
  hv[5] = (short)f2bf((o[5] - mu) * rs * g1v.y + e1.y);
  hv[6] = (short)f2bf((o[6] - mu) * rs * g1v.z + e1.z);
  hv[7] = (short)f2bf((o[7] - mu) * rs * g1v.w + e1.w);
  *(short8*)(hb + base) = hv;
}

// ======= GEMM BM_x256xBK64, 8-phase schedule, paired-row LDS ========
// Round-10 structure (proven).  2-D XCD chunking; split-K via kz.
// MODE 0: bf16 C.  MODE 1: Cout(f32)=Extra(f32)+acc.
// MODE 2: Cout(bf16)=silu(Extra bf16)*acc.
// MODE 3: bf16 split-K partial at Cout + kz*M*N.
// MODE 4: bf16 V^T split-K partial: col->(b,t), row=e;
//         dst = kz ? Extra : Cout;  dst[(b*E+row)*T + t].
template <int MODE, int BM_>
__global__ __launch_bounds__(512, 1) void gemm8p(const u16* __restrict__ A,
                                                 const u16* __restrict__ BT,
                                                 void* __restrict__ Cout,
                                                 const void* __restrict__ Extra,
                                                 int N, int K, int lda, int ldb,
                                                 int CX, int CY) {
  constexpr int MM = BM_ / 64;
  constexpr int AUNIT = BM_ * 32;
  __shared__ u16 Abuf[4 * AUNIT];
  __shared__ u16 Bbuf[4 * 8192];
  const int t = threadIdx.x;
  const int w = t >> 6, l = t & 63, g = l >> 4, lq = l & 15;
  const int wm = w >> 2, wn = w & 3;

  const int bid = (blockIdx.z * gridDim.y + blockIdx.y) * gridDim.x + blockIdx.x;
  const int xcd = bid & 7, slot = bid >> 3;
  const int nchx = gridDim.x / CX;
  const int nchy = gridDim.y / CY;
  const int cpz = nchx * nchy;
  const int kz = xcd / cpz;
  const int cid = xcd % cpz;
  const int bx = (cid % nchx) * CX + (slot % CX);
  const int by = (cid / nchx) * CY + (slot / CX);
  const size_t bm = (size_t)by * BM_, bn = (size_t)bx * 256;
  const size_t koff = (size_t)kz * K;

  const int srcrow = ((l >> 3) << 1) | (l & 1);
  const int csrc = ((((l >> 1) & 3) ^ ((l >> 3) & 3)) << 3);
  const u16* aSrc = A + (bm + w * 16 + srcrow) * (size_t)lda + koff + csrc;
  const u16* bSrc = BT + (bn + w * 16 + srcrow) * (size_t)ldb + koff + csrc;
  const int rdoff = (((lq & 1) + 2 * (g ^ ((lq >> 1) & 3))) << 3);

#define STA8(DB, KS, TILE)                                                    \
  {                                                                           \
    u16* Ad = Abuf + (DB) * (2 * AUNIT) + (KS)*AUNIT + w * 512;               \
    const u16* as_ = aSrc + (size_t)(TILE)*64 + (KS)*32;                      \
    async16(Ad, as_);                                                         \
    if constexpr (BM_ == 256) async16(Ad + 4096, as_ + (size_t)128 * lda);    \
  }
#define STB8(DB, KS, TILE)                                                    \
  {                                                                           \
    u16* Bd = Bbuf + (DB)*16384 + (KS)*8192 + w * 512;                        \
    const u16* bs_ = bSrc + (size_t)(TILE)*64 + (KS)*32;                      \
    async16(Bd, bs_);                                                         \
    async16(Bd + 4096, bs_ + (size_t)128 * ldb);                              \
  }
#define RDA8(DB, KS, MH)                                                      \
  _Pragma("unroll") for (int mm = 0; mm < MM; ++mm)                           \
      af[mm] = *(const short8*)(Abuf + (DB) * (2 * AUNIT) + (KS)*AUNIT +      \
                                (wm * (BM_ / 4) + (MH) * (BM_ / 8) + mm * 8 + \
                                 (lq >> 1)) * 64 + rdoff);
#define RDB8(DB, KS)                                                          \
  _Pragma("unroll") for (int nn = 0; nn < 4; ++nn)                            \
      bf[nn] = *(const short8*)(Bbuf + (DB)*16384 + (KS)*8192 +               \
                                (wn * 32 + nn * 8 + (lq >> 1)) * 64 + rdoff);
#define MM168(MH)                                                             \
  _Pragma("unroll") for (int mm = 0; mm < MM; ++mm)                           \
      _Pragma("unroll") for (int nn = 0; nn < 4; ++nn)                        \
          acc[(MH)*MM + mm][nn] = __builtin_amdgcn_mfma_f32_16x16x32_bf16(    \
              af[mm], bf[nn], acc[(MH)*MM + mm][nn], 0, 0, 0);
#define SYNCA                                                                 \
  __builtin_amdgcn_s_barrier();                                               \
  asm volatile("s_waitcnt lgkmcnt(0)" ::: "memory");                          \
  __builtin_amdgcn_sched_barrier(0);                                          \
  __builtin_amdgcn_s_setprio(1);
#define ENDP __builtin_amdgcn_s_setprio(0);
#define BAR2 __builtin_amdgcn_s_barrier();
#define WAITN                                                                 \
  if constexpr (BM_ == 256) asm volatile("s_waitcnt vmcnt(8)" ::: "memory");  \
  else                      asm volatile("s_waitcnt vmcnt(6)" ::: "memory");
#define WAITH                                                                 \
  if constexpr (BM_ == 256) asm volatile("s_waitcnt vmcnt(4)" ::: "memory");  \
  else                      asm volatile("s_waitcnt vmcnt(3)" ::: "memory");

  const int NT = K >> 6, NI = NT >> 1;
  f32x4 acc[2 * MM][4] = {};
  short8 af[MM > 4 ? MM : 4], bf[4];

  STA8(0, 0, 0); STB8(0, 0, 0);
  STA8(0, 1, 0); STB8(0, 1, 0);
  STA8(1, 0, 1); STB8(1, 0, 1);
  WAITN;
  BAR2;

  for (int j = 0; j < NI; ++j) {
    const int t1 = 2 * j + 1, t2 = 2 * j + 2, t3 = 2 * j + 3;
    const bool s2 = t2 < NT, s3 = t3 < NT, lastI = (j + 1 == NI);
    RDB8(0, 0); RDA8(0, 0, 0);
    STA8(1, 1, t1);
    SYNCA; MM168(0); ENDP; BAR2;
    RDA8(0, 0, 1);
    STB8(1, 1, t1);
    SYNCA; MM168(1); ENDP;
    WAITN;
    BAR2;
    RDB8(0, 1); RDA8(0, 1, 0);
    if (s2) STA8(0, 0, t2);
    SYNCA; MM168(0); ENDP; BAR2;
    RDA8(0, 1, 1);
    if (s2) STB8(0, 0, t2);
    SYNCA; MM168(1); ENDP;
    if (lastI) { WAITH; } else { WAITN; }
    BAR2;
    RDB8(1, 0); RDA8(1, 0, 0);
    if (s2) STA8(0, 1, t2);
    SYNCA; MM168(0); ENDP; BAR2;
    RDA8(1, 0, 1);
    if (s2) STB8(0, 1, t2);
    SYNCA; MM168(1); ENDP;
    if (lastI) { asm volatile("s_waitcnt vmcnt(0)" ::: "memory"); } else { WAITN; }
    BAR2;
    RDB8(1, 1); RDA8(1, 1, 0);
    if (s3) STA8(1, 0, t3);
    SYNCA; MM168(0); ENDP; BAR2;
    RDA8(1, 1, 1);
    if (s3) STB8(1, 0, t3);
    SYNCA; MM168(1); ENDP;
    if (!lastI) { WAITN; }
    BAR2;
  }
#undef STA8
#undef STB8
#undef RDA8
#undef RDB8
#undef MM168
#undef SYNCA
#undef ENDP
#undef BAR2
#undef WAITN
#undef WAITH

  const size_t mn = (size_t)gridDim.y * BM_ * (size_t)N;
#pragma unroll
  for (int m = 0; m < 2 * MM; m++) {
    size_t row = bm + wm * (BM_ / 2) + m * 16 + 4 * g;
#pragma unroll
    for (int n = 0; n < 4; n++) {
      size_t col = bn + wn * 64 + n * 16 + lq;
#pragma unroll
      for (int r = 0; r < 4; r++) {
        size_t idx = (row + r) * (size_t)N + col;
        if constexpr (MODE == 0) {
          ((u16*)Cout)[idx] = f2bf(acc[m][n][r]);
        } else if constexpr (MODE == 1) {
          ((float*)Cout)[idx] = ((const float*)Extra)[idx] + acc[m][n][r];
        } else if constexpr (MODE == 2) {
          float a = bf2f(((const u16*)Extra)[idx]);
          float sil = a / (1.f + exp2f(-1.4426950408889634f * a));
          ((u16*)Cout)[idx] = f2bf(sil * acc[m][n][r]);
        } else if constexpr (MODE == 3) {
          ((u16*)Cout)[(size_t)kz * mn + idx] = f2bf(acc[m][n][r]);
        } else {
          size_t bb = col >> 11, tt = col & 2047;
          u16* dst = kz ? (u16*)Extra : (u16*)Cout;
          dst[(bb * E_DIM + row + r) * (size_t)T_SEQ + tt] = f2bf(acc[m][n][r]);
        }
      }
    }
  }
}

// ==== FUSED SwiGLU FFN GEMM: gated = silu(A@w1T^T) * (A@w2T^T) ======
__global__ __launch_bounds__(512, 1) void gemm_ffn(const u16* __restrict__ A,
                                                   const u16* __restrict__ B1T,
                                                   const u16* __restrict__ B2T,
                                                   u16* __restrict__ Cout,
                                                   int N, int K, int lda, int ldb,
                                                   int CX, int CY) {
  constexpr int AUNIT = 8192;
  __shared__ u16 Abuf[4 * AUNIT];
  __shared__ u16 Bbuf[4 * AUNIT];
  const int t = threadIdx.x;
  const int w = t >> 6, l = t & 63, g = l >> 4, lq = l & 15;
  const int wm = w >> 2, wn = w & 3;

  const int bid = blockIdx.y * gridDim.x + blockIdx.x;
  const int xcd = bid & 7, slot = bid >> 3;
  const int nchx = gridDim.x / CX;
  const int cid = xcd;
  const int bx = (cid % nchx) * CX + (slot % CX);
  const int by = (cid / nchx) * CY + (slot / CX);
  const size_t bm = (size_t)by * 256;
  const size_t c0 = (size_t)bx * 128;

  const int srcrow = ((l >> 3) << 1) | (l & 1);
  const int csrc = ((((l >> 1) & 3) ^ ((l >> 3) & 3)) << 3);
  const u16* aSrc = A + (bm + w * 16 + srcrow) * (size_t)lda + csrc;
  const u16* b1Src = B1T + (c0 + w * 16 + srcrow) * (size_t)ldb + csrc;
  const u16* b2Src = B2T + (c0 + w * 16 + srcrow) * (size_t)ldb + csrc;
  const int rdoff = (((lq & 1) + 2 * (g ^ ((lq >> 1) & 3))) << 3);

#define STA8(DB, KS, TILE)                                                    \
  {                                                                           \
    u16* Ad = Abuf + (DB) * (2 * AUNIT) + (KS)*AUNIT + w * 512;               \
    const u16* as_ = aSrc + (size_t)(TILE)*64 + (KS)*32;                      \
    async16(Ad, as_);                                                         \
    async16(Ad + 4096, as_ + (size_t)128 * lda);                              \
  }
#define STB8(DB, KS, TILE)                                                    \
  {                                                                           \
    u16* Bd = Bbuf + (DB) * (2 * AUNIT) + (KS)*AUNIT + w * 512;               \
    size_t off_ = (size_t)(TILE)*64 + (KS)*32;                                \
    async16(Bd, b1Src + off_);                                                \
    async16(Bd + 4096, b2Src + off_);                                         \
  }
#define RDA8(DB, KS, MH)                                                      \
  _Pragma("unroll") for (int mm = 0; mm < 4; ++mm)                            \
      af[mm] = *(const short8*)(Abuf + (DB) * (2 * AUNIT) + (KS)*AUNIT +      \
                                (wm * 64 + (MH)*32 + mm * 8 + (lq >> 1)) *    \
                                    64 + rdoff);
#define RDB8(DB, KS)                                                          \
  _Pragma("unroll") for (int nn = 0; nn < 4; ++nn)                            \
      bf[nn] = *(const short8*)(Bbuf + (DB) * (2 * AUNIT) + (KS)*AUNIT +      \
                                (wn * 32 + nn * 8 + (lq >> 1)) * 64 + rdoff);
#define MM168(MH)                                                             \
  _Pragma("unroll") for (int mm = 0; mm < 4; ++mm)                            \
      _Pragma("unroll") for (int nn = 0; nn < 4; ++nn)                        \
          acc[(MH)*4 + mm][nn] = __builtin_amdgcn_mfma_f32_16x16x32_bf16(     \
              af[mm], bf[nn], acc[(MH)*4 + mm][nn], 0, 0, 0);
#define SYNCA                                                                 \
  __builtin_amdgcn_s_barrier();                                               \
  asm volatile("s_waitcnt lgkmcnt(0)" ::: "memory");                          \
  __builtin_amdgcn_sched_barrier(0);                                          \
  __builtin_amdgcn_s_setprio(1);
#define ENDP __builtin_amdgcn_s_setprio(0);
#define BAR2 __builtin_amdgcn_s_barrier();
#define WAITN asm volatile("s_waitcnt vmcnt(8)" ::: "memory");
#define WAITH asm volatile("s_waitcnt vmcnt(4)" ::: "memory");

  const int NT = K >> 6, NI = NT >> 1;
  f32x4 acc[8][4] = {};
  short8 af[4], bf[4];

  STA8(0, 0, 0); STB8(0, 0, 0);
  STA8(0, 1, 0); STB8(0, 1, 0);
  STA8(1, 0, 1); STB8(1, 0, 1);
  WAITN;
  BAR2;

  for (int j = 0; j < NI; ++j) {
    const int t1 = 2 * j + 1, t2 = 2 * j + 2, t3 = 2 * j + 3;
    const bool s2 = t2 < NT, s3 = t3 < NT, lastI = (j + 1 == NI);
    RDB8(0, 0); RDA8(0, 0, 0);
    STA8(1, 1, t1);
    SYNCA; MM168(0); ENDP; BAR2;
    RDA8(0, 0, 1);
    STB8(1, 1, t1);
    SYNCA; MM168(1); ENDP;
    WAITN;
    BAR2;
    RDB8(0, 1); RDA8(0, 1, 0);
    if (s2) STA8(0, 0, t2);
    SYNCA; MM168(0); ENDP; BAR2;
    RDA8(0, 1, 1);
    if (s2) STB8(0, 0, t2);
    SYNCA; MM168(1); ENDP;
    if (lastI) { WAITH; } else { WAITN; }
    BAR2;
    RDB8(1, 0); RDA8(1, 0, 0);
    if (s2) STA8(0, 1, t2);
    SYNCA; MM168(0); ENDP; BAR2;
    RDA8(1, 0, 1);
    if (s2) STB8(0, 1, t2);
    SYNCA; MM168(1); ENDP;
    if (lastI) { asm volatile("s_waitcnt vmcnt(0)" ::: "memory"); } else { WAITN; }
    BAR2;
    RDB8(1, 1); RDA8(1, 1, 0);
    if (s3) STA8(1, 0, t3);
    SYNCA; MM168(0); ENDP; BAR2;
    RDA8(1, 1, 1);
    if (s3) STB8(1, 0, t3);
    SYNCA; MM168(1); ENDP;
    if (!lastI) { WAITN; }
    BAR2;
  }
#undef STA8
#undef STB8
#undef RDA8
#undef RDB8
#undef MM168
#undef SYNCA
#undef ENDP
#undef BAR2
#undef WAITN
#undef WAITH

  // ---- SwiGLU epilogue: exchange u2 via (dead) LDS, gate, store ----
  const int reg = wm * 2 + ((wn >= 2) ? (wn - 2) : wn);
  float* fb = (float*)((reg < 2 ? Abuf : Bbuf) + (reg & 1) * 16384);
  if (wn >= 2) {
#pragma unroll
    for (int m = 0; m < 8; m++)
#pragma unroll
      for (int n = 0; n < 4; n++)
#pragma unroll
        for (int r = 0; r < 4; r++) {
          int lrow = m * 16 + 4 * g + r;
          int pcol = (n * 16 + lq) ^ ((g & 1) << 4);
          fb[lrow * 64 + pcol] = acc[m][n][r];
        }
  }
  __syncthreads();
  if (wn < 2) {
#pragma unroll
    for (int m = 0; m < 8; m++) {
      size_t row = bm + wm * 128 + m * 16 + 4 * g;
#pragma unroll
      for (int n = 0; n < 4; n++) {
        size_t col = c0 + wn * 64 + n * 16 + lq;
#pragma unroll
        for (int r = 0; r < 4; r++) {
          int lrow = m * 16 + 4 * g + r;
          int pcol = (n * 16 + lq) ^ ((g & 1) << 4);
          float u1 = acc[m][n][r];
          float u2 = fb[lrow * 64 + pcol];
          float sil = u1 / (1.f + exp2f(-1.4426950408889634f * u1));
          Cout[(row + r) * (size_t)N + col] = f2bf(sil * u2);
        }
      }
    }
  }
}

// ----------------- causal flash attention (LDS-staged) --------------
// grid (T/128, B*H); 4 waves/block; wave owns 32 q-rows (2 rg of 16).
// Q,K from fused QK buffer [B*T][4096] (q cols 0..2047, k cols 2048+).
// Causal load-balance remap: blocks y>=16 flip qx -> 15-qx (r18 win).
__global__ __launch_bounds__(256, 2) void attn_kernel(const u16* __restrict__ QK,
                                                      const u16* __restrict__ VT,
                                                      u16* __restrict__ CTX) {
  __shared__ u16 Ks[64 * 128];
  __shared__ u16 Vs[128 * 64];
  __shared__ u16 P_all[4][32 * 72];
  const int t = threadIdx.x;
  const int w = t >> 6, l = t & 63, g = l >> 4, lq = l & 15;
  u16* P = P_all[w];
  const int qx = (blockIdx.y & 16) ? (15 - blockIdx.x) : blockIdx.x;
  const int q0blk = qx * 128;
  const int q0w = q0blk + w * 32;
  const int bh = blockIdx.y, b = bh >> 4, h = bh & 15;
  const u16* qp = QK + (size_t)b * T_SEQ * QKS + h * D_HEAD;
  const u16* kp = qp + E_DIM;
  const u16* vp = VT + ((size_t)b * E_DIM + h * D_HEAD) * T_SEQ;

  short8 qf[2][4];
#pragma unroll
  for (int rg = 0; rg < 2; rg++)
#pragma unroll
    for (int ks = 0; ks < 4; ks++)
      qf[rg][ks] =
          *(const short8*)(qp + (size_t)(q0w + rg * 16 + lq) * QKS + ks * 32 + g * 8);

  f32x4 acc[2][8] = {};
  float m2[2][4], ls[2][4];
#pragma unroll
  for (int rg = 0; rg < 2; rg++)
#pragma unroll
    for (int r = 0; r < 4; r++) { m2[rg][r] = -1e30f; ls[rg][r] = 0.f; }
  const float sc = 0.08838834764831845f * 1.4426950408889634f;

  const int kRow0 = 16 * w + (l >> 4);
  const int kChunk = l & 15;
  const int vRow0 = 32 * w + (l >> 3);
  const int vChunk = l & 7;

  for (int kv0 = 0; kv0 < q0blk + 128; kv0 += 64) {
#pragma unroll
    for (int j = 0; j < 4; j++) {
      int R = kRow0 + 4 * j;
      async16(Ks + (16 * w + 4 * j) * 128,
              kp + (size_t)(kv0 + R) * QKS + ((kChunk ^ (R & 7)) << 3));
    }
#pragma unroll
    for (int j = 0; j < 4; j++) {
      int D = vRow0 + 8 * j;
      async16(Vs + (32 * w + 8 * j) * 64,
              vp + (size_t)D * T_SEQ + kv0 + ((vChunk ^ (D & 7)) << 3));
    }
    __syncthreads();

#pragma unroll
    for (int rg = 0; rg < 2; rg++) {
      const int rb = q0w + rg * 16;
      if (kv0 > rb + 15) continue;
      f32x4 s[4];
      __builtin_amdgcn_s_setprio(1);
#pragma unroll
      for (int ct = 0; ct < 4; ct++) {
        s[ct] = f32x4{0.f, 0.f, 0.f, 0.f};
#pragma unroll
        for (int ks = 0; ks < 4; ks++) {
          short8 kf = *(const short8*)(Ks + (ct * 16 + lq) * 128 +
                                       (((ks * 4 + g) ^ (lq & 7)) << 3));
          s[ct] = __builtin_amdgcn_mfma_f32_16x16x32_bf16(qf[rg][ks], kf, s[ct], 0, 0, 0);
        }
      }
      __builtin_amdgcn_s_setprio(0);
      float sv[4][4];
#pragma unroll
      for (int ct = 0; ct < 4; ct++)
#pragma unroll
        for (int r = 0; r < 4; r++) sv[ct][r] = s[ct][r] * sc;
      if (kv0 + 64 > rb) {
#pragma unroll
        for (int ct = 0; ct < 4; ct++)
#pragma unroll
          for (int r = 0; r < 4; r++)
            if (kv0 + ct * 16 + lq > rb + 4 * g + r) sv[ct][r] = -1e30f;
      }
      float mx[4];
#pragma unroll
      for (int r = 0; r < 4; r++)
        mx[r] = fmaxf(fmaxf(sv[0][r], sv[1][r]), fmaxf(sv[2][r], sv[3][r]));
#pragma unroll
      for (int off = 1; off < 16; off <<= 1)
#pragma unroll
        for (int r = 0; r < 4; r++) mx[r] = fmaxf(mx[r], __shfl_xor(mx[r], off));
#pragma unroll
      for (int r = 0; r < 4; r++) {
        float mn = fmaxf(m2[rg][r], mx[r]);
        float sca = exp2f(m2[rg][r] - mn);
        m2[rg][r] = mn;
        float sum = 0.f;
#pragma unroll
        for (int ct = 0; ct < 4; ct++) {
          float pv = exp2f(sv[ct][r] - mn);
          sum += pv;
          P[(rg * 16 + 4 * g + r) * 72 + ct * 16 + lq] = f2bf(pv);
        }
        ls[rg][r] = ls[rg][r] * sca + sum;
#pragma unroll
        for (int n = 0; n < 8; n++) acc[rg][n][r] *= sca;
      }
      short8 pa[2];
#pragma unroll
      for (int ks2 = 0; ks2 < 2; ks2++)
        pa[ks2] = *(const short8*)(P + (rg * 16 + lq) * 72 + ks2 * 32 + g * 8);
      __builtin_amdgcn_s_setprio(1);
#pragma unroll
      for (int n = 0; n < 8; n++)
#pragma unroll
        for (int ks2 = 0; ks2 < 2; ks2++) {
          short8 vf = *(const short8*)(Vs + (n * 16 + lq) * 64 +
                                       (((ks2 * 4 + g) ^ (lq & 7)) << 3));
          acc[rg][n] = __builtin_amdgcn_mfma_f32_16x16x32_bf16(pa[ks2], vf, acc[rg][n], 0, 0, 0);
        }
      __builtin_amdgcn_s_setprio(0);
    }
    __syncthreads();
  }

#pragma unroll
  for (int rg = 0; rg < 2; rg++) {
#pragma unroll
    for (int off = 1; off < 16; off <<= 1)
#pragma unroll
      for (int r = 0; r < 4; r++) ls[rg][r] += __shfl_xor(ls[rg][r], off);
  }
  u16* cp = CTX + ((size_t)b * T_SEQ + q0w) * E_DIM + h * D_HEAD;
#pragma unroll
  for (int rg = 0; rg < 2; rg++) {
    float inv[4];
#pragma unroll
    for (int r = 0; r < 4; r++) inv[r] = 1.f / ls[rg][r];
#pragma unroll
    for (int n = 0; n < 8; n++)
#pragma unroll
      for (int r = 0; r < 4; r++)
        cp[(size_t)(rg * 16 + 4 * g + r) * E_DIM + n * 16 + lq] =
            f2bf(acc[rg][n][r] * inv[r]);
  }
}

extern "C" void kernel_launch(void* const* d_in, const int* in_sizes, int n_in,
                              void* d_out, int out_size, void* d_ws, size_t ws_size,
                              hipStream_t stream) {
  (void)in_sizes; (void)n_in; (void)out_size; (void)ws_size;
  const float* x  = (const float*)d_in[0];
  const float* g1 = (const float*)d_in[1];
  const float* b1 = (const float*)d_in[2];
  const float* wq = (const float*)d_in[3];
  const float* wk = (const float*)d_in[4];
  const float* wv = (const float*)d_in[5];
  const float* wo = (const float*)d_in[6];
  const float* g2 = (const float*)d_in[7];
  const float* b2 = (const float*)d_in[8];
  const float* w1 = (const float*)d_in[9];
  const float* w2 = (const float*)d_in[10];
  const float* w3 = (const float*)d_in[11];
  float* out = (float*)d_out;

  const size_t EE = (size_t)E_DIM * E_DIM;
  const size_t EE2 = EE * 2;
  const size_t EF2 = (size_t)E_DIM * FFN_DIM * 2;
  const size_t ME2 = (size_t)M_ROWS * E_DIM * 2;
  char* p = (char*)d_ws;
  u16* wqkT = (u16*)p; p += 2 * EE2;   // [2E][E]: rows 0..E-1 = wq^T
  u16* wvT = (u16*)p; p += EE2;
  u16* woT = (u16*)p; p += EE2;
  u16* w1T = (u16*)p; p += EF2;
  u16* w2T = (u16*)p; p += EF2;
  u16* w3T = (u16*)p; p += EF2;
  u16* Hb  = (u16*)p; p += ME2;
  u16* QKb = (u16*)p; p += (size_t)M_ROWS * QKS * 2;  // [4096][4096]
  u16* VTb = (u16*)p; p += ME2;
  u16* CTXb = (u16*)p; p += ME2;
  u16* U1b = QKb;    // gated (67MB) reuses QKb+VTb+CTXb
  u16* Pv0 = wqkT;   // V^T kz=0 partial (wqkT dead after QK GEMM)
  u16* Pv1 = CTXb;   // V^T kz=1 partial (CTXb untouched until attn)
  u16* Pwo = wqkT;   // WO split-K partials (Pv0 consumed by addv first)
  u16* Pk = wqkT;    // w3 split-K partials (wqkT dead after addwo_ln)

  dim3 blk32(32, 8);
  // ALL weights cvt+transpose AND LayerNorm1 in one dispatch
  prep_kernel<<<69632, blk32, 0, stream>>>(wq, wk, wv, wo, w1, w2, w3,
                                           wqkT, wvT, woT, w1T, w2T, w3T,
                                           x, g1, b1, Hb);

  // attention block
  // fused QK GEMM at BM256: grid (16,16) = 256 blocks; chunk 4x8
  gemm8p<0, 256><<<dim3(QKS / 256, M_ROWS / 256), 512, 0, stream>>>(
      Hb, wqkT, QKb, nullptr, QKS, E_DIM, E_DIM, E_DIM, 4, 8);
  // V^T direct: A=wvT (M=E), B=Hb (N=B*T), split-K=2:
  // grid (16,8,2) = 256 blocks; chunk 8x4; kz=0 -> Pv0, kz=1 -> Pv1
  gemm8p<4, 256><<<dim3(M_ROWS / 256, E_DIM / 256, 2), 512, 0, stream>>>(
      wvT, Hb, Pv0, Pv1, M_ROWS, E_DIM / 2, E_DIM, E_DIM, 8, 4);
  addv_kernel<<<4096, 256, 0, stream>>>(VTb, Pv0, Pv1);
  attn_kernel<<<dim3(T_SEQ / 128, 2 * N_HEAD), 256, 0, stream>>>(QKb, VTb, CTXb);
  // WO at BM256 split-K=2: grid (8,16,2) = 256 blocks; chunk 4x8
  gemm8p<3, 256><<<dim3(E_DIM / 256, M_ROWS / 256, 2), 512, 0, stream>>>(
      CTXb, woT, Pwo, nullptr, E_DIM, E_DIM / 2, E_DIM, E_DIM, 4, 8);
  // fused: out = x + Pwo0 + Pwo1;  Hb = LN(out)*g2 + b2
  addwo_ln_kernel<<<M_ROWS, 256, 0, stream>>>(out, x, Pwo, g2, b2, Hb);

  // SwiGLU MLP block
  // fused FFN1+FFN2+silu-gate: grid (64,16) = 1024 blocks; chunk 16x8
  gemm_ffn<<<dim3(FFN_DIM / 128, M_ROWS / 256), 512, 0, stream>>>(
      Hb, w1T, w2T, U1b, FFN_DIM, E_DIM, E_DIM, E_DIM, 16, 8);
  // w3: BM256 split-K=2: grid (8,16,2) = 256 blocks; chunk 4x8 per kz
  gemm8p<3, 256><<<dim3(E_DIM / 256, M_ROWS / 256, 2), 512, 0, stream>>>(
      U1b, w3T, Pk, nullptr, E_DIM, FFN_DIM / 2, FFN_DIM, FFN_DIM, 4, 8);
  add3_kernel<<<4096, 256, 0, stream>>>(out, Pk);
}